// Round 7
// baseline (3215.443 us; speedup 1.0000x reference)
//
#include <hip/hip_runtime.h>
#include <hip/hip_bf16.h>

// Problem constants
#define Bsz   16
#define Tn    2048
#define INC   80
#define Hc    512
#define Dc    512
#define NCODE 1024
#define BT    (Bsz * Tn)           // 32768
#define RECON_N (Bsz * Tn * INC)   // 2,621,440

// ---------------------------------------------------------------------------
// code_norms: CN[j] = sum_d CB[j][d]^2
// ---------------------------------------------------------------------------
__global__ __launch_bounds__(64)
void code_norms(const float* __restrict__ CB, float* __restrict__ CN) {
    int j = blockIdx.x;
    int lane = threadIdx.x;
    const float4* row = (const float4*)(CB + (size_t)j * Dc);
    float s = 0.f;
    #pragma unroll
    for (int i = 0; i < 2; ++i) {
        float4 v = row[lane + i * 64];
        s = fmaf(v.x, v.x, s);
        s = fmaf(v.y, v.y, s);
        s = fmaf(v.z, v.z, s);
        s = fmaf(v.w, v.w, s);
    }
    #pragma unroll
    for (int off = 32; off > 0; off >>= 1) s += __shfl_down(s, off, 64);
    if (lane == 0) CN[j] = s;
}

// ---------------------------------------------------------------------------
// cb_transpose: CBt[d][j] = CB[j][d].  grid (NCODE/64, Dc/64), block 256
// ---------------------------------------------------------------------------
__global__ __launch_bounds__(256)
void cb_transpose(const float* __restrict__ CB, float* __restrict__ CBt) {
    const int j0 = blockIdx.x * 64;
    const int d0 = blockIdx.y * 64;
    __shared__ float ts[64][65];
    const int tid = threadIdx.x;
    for (int i = tid; i < 4096; i += 256) {
        int r = i >> 6, c = i & 63;
        ts[r][c] = CB[(size_t)(j0 + r) * Dc + d0 + c];
    }
    __syncthreads();
    for (int i = tid; i < 4096; i += 256) {
        int r = i >> 6, c = i & 63;
        CBt[(size_t)(d0 + r) * NCODE + j0 + c] = ts[c][r];
    }
}

// ---------------------------------------------------------------------------
// mels_transpose: MT[b][c][t] = M[b][t][c].  grid (Tn/64, Bsz), block 256
// ---------------------------------------------------------------------------
__global__ __launch_bounds__(256)
void mels_transpose(const float* __restrict__ M, float* __restrict__ MT) {
    const int t0 = blockIdx.x * 64;
    const int b  = blockIdx.y;
    __shared__ float ts[64][84];
    const int tid = threadIdx.x;
    #pragma unroll
    for (int it = 0; it < 5; ++it) {
        int i = tid + it * 256;            // < 1280
        int t = i / 20, c4 = i % 20;
        *(float4*)&ts[t][c4 * 4] =
            *(const float4*)&M[((size_t)b * Tn + t0 + t) * INC + c4 * 4];
    }
    __syncthreads();
    #pragma unroll
    for (int it = 0; it < 20; ++it) {
        int i = tid + it * 256;            // < 5120
        int c = i >> 6, t = i & 63;
        MT[((size_t)b * INC + c) * Tn + t0 + t] = ts[t][c];
    }
}

// ---------------------------------------------------------------------------
// wt_transpose: Wt[(c*3+k)*Cout + o] = W[(o*Cin + c)*3 + k]
// grid (ceil(Cout/64), Cin/16), block 256
// ---------------------------------------------------------------------------
__global__ __launch_bounds__(256)
void wt_transpose(const float* __restrict__ W, float* __restrict__ Wt,
                  int Cin, int Cout) {
    const int o0 = blockIdx.x * 64;
    const int c0 = blockIdx.y * 16;
    __shared__ float ts[48][65];
    const int tid = threadIdx.x;
    for (int i = tid; i < 64 * 48; i += 256) {
        int o = i / 48, ck = i % 48;
        int oo = o0 + o;
        float v = 0.f;
        if (oo < Cout) v = W[(size_t)oo * Cin * 3 + c0 * 3 + ck];
        ts[ck][o] = v;
    }
    __syncthreads();
    for (int i = tid; i < 48 * 64; i += 256) {
        int o = i & 63, ck = i >> 6;
        int oo = o0 + o;
        if (oo < Cout) Wt[(size_t)(c0 * 3 + ck) * Cout + oo] = ts[ck][o];
    }
}

// ---------------------------------------------------------------------------
// conv_enc1: melsT [B,80,T] -> Y [B,512,T], K=3 SAME, ReLU at store.
// Tile 64 t x 128 o; per-thread 4 t x 8 o (o split {ty*4, 64+ty*4}).
// Register-prefetch pipeline: fetch chunk c0+16 during compute of c0.
// grid (T/64, 4, B), block 256
// ---------------------------------------------------------------------------
__global__ __launch_bounds__(256, 2)
void conv_enc1(const float* __restrict__ X, const float* __restrict__ Wt,
               const float* __restrict__ bias, float* __restrict__ Y) {
    const int t0 = blockIdx.x * 64;
    const int o0 = blockIdx.y * 128;
    const int b  = blockIdx.z;
    __shared__ __align__(16) float Xs[16][72];
    __shared__ __align__(16) float Ws[48][132];
    const int tid = threadIdx.x;
    const int tx = tid & 15, ty = tid >> 4;
    float acc[8][4] = {};   // [o8: og*4+oi][t4]
    const float* Xb = X + (size_t)b * INC * Tn;

    float xr[5];
    float4 wr[6];
    // prefetch chunk c0=0 (X: 16x66=1056 = 4x256 + 32; W: 1536 float4)
    #pragma unroll
    for (int it = 0; it < 5; ++it) {
        int i = tid + it * 256;
        if (it < 4 || tid < 32) {
            int cc = i / 66, tt = i - cc * 66;
            int t = t0 + tt - 1;
            xr[it] = (t >= 0 && t < Tn) ? Xb[(size_t)cc * Tn + t] : 0.f;
        }
    }
    #pragma unroll
    for (int it = 0; it < 6; ++it) {
        int i = tid + it * 256;
        int ck = i >> 5, o4 = i & 31;
        wr[it] = *(const float4*)&Wt[(size_t)ck * Hc + o0 + o4 * 4];
    }

    for (int c0 = 0; c0 < INC; c0 += 16) {
        #pragma unroll
        for (int it = 0; it < 5; ++it) {
            int i = tid + it * 256;
            if (it < 4 || tid < 32) {
                int cc = i / 66, tt = i - cc * 66;
                Xs[cc][tt] = xr[it];
            }
        }
        #pragma unroll
        for (int it = 0; it < 6; ++it) {
            int i = tid + it * 256;
            int ck = i >> 5, o4 = i & 31;
            *(float4*)&Ws[ck][o4 * 4] = wr[it];
        }
        __syncthreads();
        if (c0 + 16 < INC) {
            int c1 = c0 + 16;
            #pragma unroll
            for (int it = 0; it < 5; ++it) {
                int i = tid + it * 256;
                if (it < 4 || tid < 32) {
                    int cc = i / 66, tt = i - cc * 66;
                    int t = t0 + tt - 1;
                    xr[it] = (t >= 0 && t < Tn) ? Xb[(size_t)(c1 + cc) * Tn + t] : 0.f;
                }
            }
            #pragma unroll
            for (int it = 0; it < 6; ++it) {
                int i = tid + it * 256;
                int ck = i >> 5, o4 = i & 31;
                wr[it] = *(const float4*)&Wt[(size_t)(c1 * 3 + ck) * Hc + o0 + o4 * 4];
            }
        }
        #pragma unroll
        for (int cc = 0; cc < 16; ++cc) {
            float4 xa = *(const float4*)&Xs[cc][tx * 4];
            float2 xb2 = *(const float2*)&Xs[cc][tx * 4 + 4];
            float xv[6] = {xa.x, xa.y, xa.z, xa.w, xb2.x, xb2.y};
            #pragma unroll
            for (int k = 0; k < 3; ++k) {
                float4 wa = *(const float4*)&Ws[cc * 3 + k][ty * 4];
                float4 wb = *(const float4*)&Ws[cc * 3 + k][64 + ty * 4];
                float wv[8] = {wa.x, wa.y, wa.z, wa.w, wb.x, wb.y, wb.z, wb.w};
                #pragma unroll
                for (int i8 = 0; i8 < 8; ++i8)
                    #pragma unroll
                    for (int j = 0; j < 4; ++j)
                        acc[i8][j] = fmaf(wv[i8], xv[k + j], acc[i8][j]);
            }
        }
        __syncthreads();
    }
    float* Yb = Y + (size_t)b * Hc * Tn;
    #pragma unroll
    for (int og = 0; og < 2; ++og)
        #pragma unroll
        for (int oi = 0; oi < 4; ++oi) {
            int o = o0 + og * 64 + ty * 4 + oi;
            float bv = bias[o];
            const int i8 = og * 4 + oi;
            float4 r;
            r.x = fmaxf(acc[i8][0] + bv, 0.f);
            r.y = fmaxf(acc[i8][1] + bv, 0.f);
            r.z = fmaxf(acc[i8][2] + bv, 0.f);
            r.w = fmaxf(acc[i8][3] + bv, 0.f);
            *(float4*)&Yb[(size_t)o * Tn + t0 + tx * 4] = r;
        }
}

// ---------------------------------------------------------------------------
// conv_mid128cf: X [B,512,T] -> Y [B,512,T], K=3 SAME, no relu (encoder z).
// Tile 128 t x 128 o; per-thread 8 t x 8 o, conflict-free groups of 4.
// Register-prefetch pipeline: the r6 profile showed 38% VALU-idle from
// staging-load latency exposed at ds_write each chunk; fetch chunk c0+16
// into VGPRs right after the barrier so the ~900-cyc load latency overlaps
// the ~6000-cyc FMA block. FMA order per output unchanged -> z bit-identical.
// ---------------------------------------------------------------------------
__global__ __launch_bounds__(256, 2)
void conv_mid128cf(const float* __restrict__ X, const float* __restrict__ Wt,
                   const float* __restrict__ bias, float* __restrict__ Y) {
    const int t0 = blockIdx.x * 128;
    const int o0 = blockIdx.y * 128;
    const int b  = blockIdx.z;
    __shared__ __align__(16) float Xs[16][132];   // Xs[cc][tt] = X[t0+tt-1]
    __shared__ __align__(16) float Ws[48][132];
    const int tid = threadIdx.x;
    const int tx = tid & 15, ty = tid >> 4;
    float acc[8][8] = {};   // [t: g*4+j][o: og*4+oi]
    const float* Xb = X + (size_t)b * Hc * Tn;

    float xr[9];
    float4 wr[6];
    // prefetch chunk c0=0 (X: 16x130=2080 = 8x256 + 32; W: 1536 float4)
    #pragma unroll
    for (int it = 0; it < 9; ++it) {
        int i = tid + it * 256;
        if (it < 8 || tid < 32) {
            int cc = i / 130, tt = i - cc * 130;
            int t = t0 + tt - 1;
            xr[it] = (t >= 0 && t < Tn) ? Xb[(size_t)cc * Tn + t] : 0.f;
        }
    }
    #pragma unroll
    for (int it = 0; it < 6; ++it) {
        int i = tid + it * 256;
        int ck = i >> 5, o4 = i & 31;
        wr[it] = *(const float4*)&Wt[(size_t)ck * Hc + o0 + o4 * 4];
    }

    for (int c0 = 0; c0 < Hc; c0 += 16) {
        // write prefetched chunk to LDS
        #pragma unroll
        for (int it = 0; it < 9; ++it) {
            int i = tid + it * 256;
            if (it < 8 || tid < 32) {
                int cc = i / 130, tt = i - cc * 130;
                Xs[cc][tt] = xr[it];
            }
        }
        #pragma unroll
        for (int it = 0; it < 6; ++it) {
            int i = tid + it * 256;
            int ck = i >> 5, o4 = i & 31;
            *(float4*)&Ws[ck][o4 * 4] = wr[it];
        }
        __syncthreads();
        // prefetch next chunk (overlaps compute)
        if (c0 + 16 < Hc) {
            int c1 = c0 + 16;
            #pragma unroll
            for (int it = 0; it < 9; ++it) {
                int i = tid + it * 256;
                if (it < 8 || tid < 32) {
                    int cc = i / 130, tt = i - cc * 130;
                    int t = t0 + tt - 1;
                    xr[it] = (t >= 0 && t < Tn) ? Xb[(size_t)(c1 + cc) * Tn + t] : 0.f;
                }
            }
            #pragma unroll
            for (int it = 0; it < 6; ++it) {
                int i = tid + it * 256;
                int ck = i >> 5, o4 = i & 31;
                wr[it] = *(const float4*)&Wt[(size_t)(c1 * 3 + ck) * Hc + o0 + o4 * 4];
            }
        }
        // compute
        #pragma unroll
        for (int cc = 0; cc < 16; ++cc) {
            float xv[2][6];
            #pragma unroll
            for (int g = 0; g < 2; ++g) {
                float4 xa = *(const float4*)&Xs[cc][tx * 4 + g * 64];
                float2 xb2 = *(const float2*)&Xs[cc][tx * 4 + g * 64 + 4];
                xv[g][0] = xa.x; xv[g][1] = xa.y; xv[g][2] = xa.z;
                xv[g][3] = xa.w; xv[g][4] = xb2.x; xv[g][5] = xb2.y;
            }
            #pragma unroll
            for (int k = 0; k < 3; ++k) {
                float4 wa = *(const float4*)&Ws[cc * 3 + k][ty * 4];
                float4 wb = *(const float4*)&Ws[cc * 3 + k][64 + ty * 4];
                float wv[8] = {wa.x, wa.y, wa.z, wa.w, wb.x, wb.y, wb.z, wb.w};
                #pragma unroll
                for (int g = 0; g < 2; ++g)
                    #pragma unroll
                    for (int j = 0; j < 4; ++j) {
                        float xx = xv[g][k + j];
                        #pragma unroll
                        for (int o8 = 0; o8 < 8; ++o8)
                            acc[g * 4 + j][o8] = fmaf(wv[o8], xx, acc[g * 4 + j][o8]);
                    }
            }
        }
        __syncthreads();
    }
    float* Yb = Y + (size_t)b * Hc * Tn;
    #pragma unroll
    for (int og = 0; og < 2; ++og)
        #pragma unroll
        for (int oi = 0; oi < 4; ++oi) {
            int o = o0 + og * 64 + ty * 4 + oi;
            float bv = bias[o];
            const int o8 = og * 4 + oi;
            #pragma unroll
            for (int g = 0; g < 2; ++g) {
                float4 r;
                r.x = acc[g * 4 + 0][o8] + bv;
                r.y = acc[g * 4 + 1][o8] + bv;
                r.z = acc[g * 4 + 2][o8] + bv;
                r.w = acc[g * 4 + 3][o8] + bv;
                *(float4*)&Yb[(size_t)o * Tn + t0 + g * 64 + tx * 4] = r;
            }
        }
}

// ---------------------------------------------------------------------------
// conv_dec2p: X [B,512,T] -> partial recon (no bias), K-split over channels.
// half = blockIdx.y selects c in [half*256, half*256+256). 1024 blocks.
// Register-prefetch pipeline + wave-uniform skip: o-group1 (64..79) is owned
// entirely by wave 0 (ty<4), so waves 1-3 skip those FMAs (37.5% less work).
// ---------------------------------------------------------------------------
__global__ __launch_bounds__(256, 2)
void conv_dec2p(const float* __restrict__ X, const float* __restrict__ Wt,
                float* __restrict__ P) {
    const int t0 = blockIdx.x * 64;
    const int half = blockIdx.y;
    const int b  = blockIdx.z;
    __shared__ __align__(16) float Xs[16][72];
    __shared__ __align__(16) float Ws[48][132];
    const int tid = threadIdx.x;
    const int tx = tid & 15, ty = tid >> 4;
    float acc[8][4] = {};   // [o8: og*4+oi][t4]
    const float* Xb = X + (size_t)b * Hc * Tn;
    const int cbase = half * 256;

    float xr[5];
    float4 wr[6];
    #pragma unroll
    for (int it = 0; it < 5; ++it) {
        int i = tid + it * 256;
        if (it < 4 || tid < 32) {
            int cc = i / 66, tt = i - cc * 66;
            int t = t0 + tt - 1;
            xr[it] = (t >= 0 && t < Tn) ? Xb[(size_t)(cbase + cc) * Tn + t] : 0.f;
        }
    }
    #pragma unroll
    for (int it = 0; it < 6; ++it) {
        int i = tid + it * 256;
        int ck = i >> 5, o4 = i & 31;
        wr[it] = (o4 < 20)
            ? *(const float4*)&Wt[(size_t)(cbase * 3 + ck) * INC + o4 * 4]
            : make_float4(0.f, 0.f, 0.f, 0.f);
    }

    for (int c0 = cbase; c0 < cbase + 256; c0 += 16) {
        #pragma unroll
        for (int it = 0; it < 5; ++it) {
            int i = tid + it * 256;
            if (it < 4 || tid < 32) {
                int cc = i / 66, tt = i - cc * 66;
                Xs[cc][tt] = xr[it];
            }
        }
        #pragma unroll
        for (int it = 0; it < 6; ++it) {
            int i = tid + it * 256;
            int ck = i >> 5, o4 = i & 31;
            *(float4*)&Ws[ck][o4 * 4] = wr[it];
        }
        __syncthreads();
        if (c0 + 16 < cbase + 256) {
            int c1 = c0 + 16;
            #pragma unroll
            for (int it = 0; it < 5; ++it) {
                int i = tid + it * 256;
                if (it < 4 || tid < 32) {
                    int cc = i / 66, tt = i - cc * 66;
                    int t = t0 + tt - 1;
                    xr[it] = (t >= 0 && t < Tn) ? Xb[(size_t)(c1 + cc) * Tn + t] : 0.f;
                }
            }
            #pragma unroll
            for (int it = 0; it < 6; ++it) {
                int i = tid + it * 256;
                int ck = i >> 5, o4 = i & 31;
                wr[it] = (o4 < 20)
                    ? *(const float4*)&Wt[(size_t)(c1 * 3 + ck) * INC + o4 * 4]
                    : make_float4(0.f, 0.f, 0.f, 0.f);
            }
        }
        #pragma unroll
        for (int cc = 0; cc < 16; ++cc) {
            float4 xa = *(const float4*)&Xs[cc][tx * 4];
            float2 xb2 = *(const float2*)&Xs[cc][tx * 4 + 4];
            float xv[6] = {xa.x, xa.y, xa.z, xa.w, xb2.x, xb2.y};
            #pragma unroll
            for (int k = 0; k < 3; ++k) {
                float4 wa = *(const float4*)&Ws[cc * 3 + k][ty * 4];
                #pragma unroll
                for (int i8 = 0; i8 < 4; ++i8) {
                    float w = (i8 == 0) ? wa.x : (i8 == 1) ? wa.y : (i8 == 2) ? wa.z : wa.w;
                    #pragma unroll
                    for (int j = 0; j < 4; ++j)
                        acc[i8][j] = fmaf(w, xv[k + j], acc[i8][j]);
                }
            }
            if (ty < 4) {   // wave-uniform: only wave 0 owns o=64..79
                #pragma unroll
                for (int k = 0; k < 3; ++k) {
                    float4 wb = *(const float4*)&Ws[cc * 3 + k][64 + ty * 4];
                    #pragma unroll
                    for (int i8 = 0; i8 < 4; ++i8) {
                        float w = (i8 == 0) ? wb.x : (i8 == 1) ? wb.y : (i8 == 2) ? wb.z : wb.w;
                        #pragma unroll
                        for (int j = 0; j < 4; ++j)
                            acc[4 + i8][j] = fmaf(w, xv[k + j], acc[4 + i8][j]);
                    }
                }
            }
        }
        __syncthreads();
    }
    float* Ph = P + (size_t)half * RECON_N;
    {
        #pragma unroll
        for (int j = 0; j < 4; ++j) {
            int t = t0 + tx * 4 + j;
            float4 s;
            s.x = acc[0][j]; s.y = acc[1][j]; s.z = acc[2][j]; s.w = acc[3][j];
            *(float4*)(Ph + ((size_t)b * Tn + t) * INC + ty * 4) = s;
        }
    }
    if (ty < 4) {
        #pragma unroll
        for (int j = 0; j < 4; ++j) {
            int t = t0 + tx * 4 + j;
            float4 s;
            s.x = acc[4][j]; s.y = acc[5][j]; s.z = acc[6][j]; s.w = acc[7][j];
            *(float4*)(Ph + ((size_t)b * Tn + t) * INC + 64 + ty * 4) = s;
        }
    }
}

// ---------------------------------------------------------------------------
// dec_combine: recon = P0 + P1 + bias. grid (RECON_N/1024), block 256, f4.
// ---------------------------------------------------------------------------
__global__ __launch_bounds__(256)
void dec_combine(const float* __restrict__ P, const float* __restrict__ bias,
                 float* __restrict__ OUT) {
    int i4 = blockIdx.x * 256 + threadIdx.x;
    float4 a = ((const float4*)P)[i4];
    float4 b = ((const float4*)(P + RECON_N))[i4];
    int o = (i4 * 4) % INC;
    float4 r;
    r.x = a.x + b.x + bias[o];
    r.y = a.y + b.y + bias[o + 1];
    r.z = a.z + b.z + bias[o + 2];
    r.w = a.w + b.w + bias[o + 3];
    ((float4*)OUT)[i4] = r;
}

// ---------------------------------------------------------------------------
// vq_partial: per code-quarter partial argmin of CN[j] - 2 z.c_j.
// grid (T/64, B, 4), block 256. Register-prefetch pipeline added.
// ---------------------------------------------------------------------------
__global__ __launch_bounds__(256, 2)
void vq_partial(const float* __restrict__ Z, const float* __restrict__ CBt,
                const float* __restrict__ CN, float* __restrict__ candv,
                int* __restrict__ candi) {
    const int t0 = blockIdx.x * 64;
    const int b  = blockIdx.y;
    const int jbase = blockIdx.z * 256;
    const int tid = threadIdx.x;
    const int tx = tid & 15, ty = tid >> 4;
    __shared__ __align__(16) float Zs[16][68];
    __shared__ __align__(16) float Cs[16][260];
    __shared__ float rv[64][17];
    __shared__ int   ri[64][17];

    float acc[16][4] = {};   // [code16][pos]
    const float* Zb = Z + (size_t)b * Dc * Tn + t0;

    float zr[4];
    float4 cr[4];
    #pragma unroll
    for (int it = 0; it < 4; ++it) {
        int i = tid + it * 256;
        zr[it] = Zb[(size_t)(i >> 6) * Tn + (i & 63)];
        cr[it] = *(const float4*)&CBt[(size_t)(i >> 6) * NCODE + jbase + (i & 63) * 4];
    }

    for (int d0 = 0; d0 < Dc; d0 += 16) {
        #pragma unroll
        for (int it = 0; it < 4; ++it) {
            int i = tid + it * 256;
            Zs[i >> 6][i & 63] = zr[it];
            *(float4*)&Cs[i >> 6][(i & 63) * 4] = cr[it];
        }
        __syncthreads();
        if (d0 + 16 < Dc) {
            int d1 = d0 + 16;
            #pragma unroll
            for (int it = 0; it < 4; ++it) {
                int i = tid + it * 256;
                zr[it] = Zb[(size_t)(d1 + (i >> 6)) * Tn + (i & 63)];
                cr[it] = *(const float4*)&CBt[(size_t)(d1 + (i >> 6)) * NCODE + jbase + (i & 63) * 4];
            }
        }
        #pragma unroll
        for (int dd = 0; dd < 16; ++dd) {
            float4 z = *(const float4*)&Zs[dd][tx * 4];
            float zp[4] = {z.x, z.y, z.z, z.w};
            #pragma unroll
            for (int s = 0; s < 4; ++s) {
                float4 c = *(const float4*)&Cs[dd][s * 64 + ty * 4];
                float cp[4] = {c.x, c.y, c.z, c.w};
                #pragma unroll
                for (int q = 0; q < 4; ++q)
                    #pragma unroll
                    for (int p = 0; p < 4; ++p)
                        acc[s * 4 + q][p] = fmaf(cp[q], zp[p], acc[s * 4 + q][p]);
            }
        }
        __syncthreads();
    }
    float bestv[4];
    int   besti[4];
    #pragma unroll
    for (int p = 0; p < 4; ++p) { bestv[p] = 1e30f; besti[p] = 0; }
    #pragma unroll
    for (int s = 0; s < 4; ++s)
        #pragma unroll
        for (int q = 0; q < 4; ++q) {
            int j = jbase + s * 64 + ty * 4 + q;
            float cnv = CN[j];
            #pragma unroll
            for (int p = 0; p < 4; ++p) {
                float dist = fmaf(-2.f, acc[s * 4 + q][p], cnv);
                if (dist < bestv[p] || (dist == bestv[p] && j < besti[p])) {
                    bestv[p] = dist; besti[p] = j;
                }
            }
        }
    #pragma unroll
    for (int p = 0; p < 4; ++p) {
        rv[tx * 4 + p][ty] = bestv[p];
        ri[tx * 4 + p][ty] = besti[p];
    }
    __syncthreads();
    if (tid < 64) {
        float bv = rv[tid][0];
        int   bi = ri[tid][0];
        #pragma unroll
        for (int y = 1; y < 16; ++y) {
            float v = rv[tid][y];
            int   i2 = ri[tid][y];
            if (v < bv || (v == bv && i2 < bi)) { bv = v; bi = i2; }
        }
        int n = b * Tn + t0 + tid;
        candv[(size_t)blockIdx.z * BT + n] = bv;
        candi[(size_t)blockIdx.z * BT + n] = bi;
    }
}

// ---------------------------------------------------------------------------
// vq_reduce: merge 4 candidates per position. grid (BT/256), block 256
// ---------------------------------------------------------------------------
__global__ __launch_bounds__(256)
void vq_reduce(const float* __restrict__ candv, const int* __restrict__ candi,
               int* __restrict__ idxI, float* __restrict__ idxf) {
    int n = blockIdx.x * 256 + threadIdx.x;
    float bv = candv[n];
    int   bi = candi[n];
    #pragma unroll
    for (int jq = 1; jq < 4; ++jq) {
        float v = candv[(size_t)jq * BT + n];
        int   i2 = candi[(size_t)jq * BT + n];
        if (v < bv || (v == bv && i2 < bi)) { bv = v; bi = i2; }
    }
    idxI[n] = bi;
    idxf[n] = (float)bi;
}

// ---------------------------------------------------------------------------
// gemm_g: G[j][kk*512+o] = sum_c CB[j][c] * dec_w1[o][c][kk].
// grid (NCODE/64, 12): kk = y>>2, o0 = (y&3)*128. block 256, 4j x 8o.
// ---------------------------------------------------------------------------
__global__ __launch_bounds__(256)
void gemm_g(const float* __restrict__ CBt, const float* __restrict__ Wt,
            float* __restrict__ G) {
    const int j0 = blockIdx.x * 64;
    const int kk = blockIdx.y >> 2;
    const int o0 = (blockIdx.y & 3) * 128;
    __shared__ __align__(16) float As[16][68];    // [c][j]
    __shared__ __align__(16) float Bs[16][132];   // [c][o]
    const int tid = threadIdx.x;
    const int tx = tid & 15, ty = tid >> 4;
    float acc[4][8] = {};   // [j][o]

    for (int c0 = 0; c0 < Dc; c0 += 16) {
        {
            int cc = tid >> 4, j4 = tid & 15;
            *(float4*)&As[cc][j4 * 4] =
                *(const float4*)&CBt[(size_t)(c0 + cc) * NCODE + j0 + j4 * 4];
        }
        #pragma unroll
        for (int it = 0; it < 2; ++it) {
            int i = tid + it * 256;
            int cc = i >> 5, o4 = i & 31;
            *(float4*)&Bs[cc][o4 * 4] =
                *(const float4*)&Wt[(size_t)((c0 + cc) * 3 + kk) * Hc + o0 + o4 * 4];
        }
        __syncthreads();
        #pragma unroll
        for (int cc = 0; cc < 16; ++cc) {
            float4 a = *(const float4*)&As[cc][tx * 4];
            float av[4] = {a.x, a.y, a.z, a.w};
            float4 b0 = *(const float4*)&Bs[cc][ty * 4];
            float4 b1 = *(const float4*)&Bs[cc][64 + ty * 4];
            float bv[8] = {b0.x, b0.y, b0.z, b0.w, b1.x, b1.y, b1.z, b1.w};
            #pragma unroll
            for (int jj = 0; jj < 4; ++jj)
                #pragma unroll
                for (int oo = 0; oo < 8; ++oo)
                    acc[jj][oo] = fmaf(av[jj], bv[oo], acc[jj][oo]);
        }
        __syncthreads();
    }
    #pragma unroll
    for (int jj = 0; jj < 4; ++jj) {
        int j = j0 + tx * 4 + jj;
        float* gp = G + (size_t)j * 1536 + kk * 512 + o0;
        *(float4*)(gp + ty * 4) = *(float4*)&acc[jj][0];
        *(float4*)(gp + 64 + ty * 4) = *(float4*)&acc[jj][4];
    }
}

// ---------------------------------------------------------------------------
// dec_y3: y3[b][o][t] = relu(b1[o] + sum_kk G[idx[b][t+kk-1]][kk*512+o]).
// grid (T/64, 4 o-tiles, B), block 256.
// ---------------------------------------------------------------------------
__global__ __launch_bounds__(256)
void dec_y3(const int* __restrict__ idx, const float* __restrict__ G,
            const float* __restrict__ bias, float* __restrict__ Y) {
    const int t0 = blockIdx.x * 64;
    const int o0 = blockIdx.y * 128;
    const int b  = blockIdx.z;
    const int tid = threadIdx.x;
    __shared__ int sidx[66];
    __shared__ __align__(16) float Ys[128][68];

    if (tid < 66) {
        int t = t0 + tid - 1;
        sidx[tid] = (t >= 0 && t < Tn) ? idx[b * Tn + t] : -1;
    }
    __syncthreads();

    const int o = tid & 127;
    const int half = tid >> 7;
    float acc[32] = {};
    #pragma unroll
    for (int kk = 0; kk < 3; ++kk) {
        const float* Gk = G + (size_t)kk * 512 + o0 + o;
        #pragma unroll
        for (int k = 0; k < 32; ++k) {
            int j = sidx[half + 2 * k + kk];
            if (j >= 0) acc[k] += Gk[(size_t)j * 1536];
        }
    }
    float bv = bias[o0 + o];
    #pragma unroll
    for (int k = 0; k < 32; ++k)
        Ys[o][half + 2 * k] = fmaxf(acc[k] + bv, 0.f);
    __syncthreads();

    float* Yb = Y + (size_t)b * Hc * Tn + t0;
    #pragma unroll
    for (int it = 0; it < 8; ++it) {
        int i = tid + it * 256;
        int t4 = i & 15, oo = i >> 4;
        *(float4*)&Yb[(size_t)(o0 + oo) * Tn + t4 * 4] =
            *(const float4*)&Ys[oo][t4 * 4];
    }
}

// ---------------------------------------------------------------------------
extern "C" void kernel_launch(void* const* d_in, const int* in_sizes, int n_in,
                              void* d_out, int out_size, void* d_ws, size_t ws_size,
                              hipStream_t stream) {
    const float* mels    = (const float*)d_in[0];
    const float* enc_w1  = (const float*)d_in[1];
    const float* enc_b1  = (const float*)d_in[2];
    const float* enc_w2  = (const float*)d_in[3];
    const float* enc_b2  = (const float*)d_in[4];
    const float* codebook= (const float*)d_in[5];
    const float* dec_w1  = (const float*)d_in[6];
    const float* dec_b1  = (const float*)d_in[7];
    const float* dec_w2  = (const float*)d_in[8];
    const float* dec_b2  = (const float*)d_in[9];

    float* out = (float*)d_out;
    float* recon = out;                 // [B,T,80]
    float* idxf  = out + RECON_N;       // [B,T] as float

    const size_t ACT = (size_t)Bsz * Hc * Tn;   // 16,777,216 floats (64 MB)
    float* bufA = (float*)d_ws;                 // y1, later y3
    float* bufB = bufA + ACT;                   // melsT, then z, then dec partials
    int*   idxI = (int*)(bufB + ACT);           // [B*T]
    float* cn   = (float*)(idxI + BT);          // [NCODE]
    float* cbt  = cn + NCODE;                   // [512*1024]
    float* wt1  = cbt + (size_t)Dc * NCODE;     // enc_w1t: 80*3*512
    float* wt2  = wt1 + (size_t)INC * 3 * Hc;   // enc_w2t: 512*3*512
    float* wt3  = wt2 + (size_t)Hc * 3 * Dc;    // dec_w1t: 512*3*512
    float* wt4  = wt3 + (size_t)Dc * 3 * Hc;    // dec_w2t: 512*3*80
    float* candv = wt4 + (size_t)Hc * 3 * INC;  // [4*BT]
    int*   candi = (int*)(candv + 4 * BT);      // [4*BT]
    float* G    = (float*)(candi + 4 * BT);     // [1024*1536]
    float* melsT = bufB;                        // [B,80,T] (dead after enc1)
    float* Pdec  = bufB;                        // 2 partials (z dead by then)

    dim3 blk(256);
    // prep: norms + transposes (cheap, every call — graph-capture safe)
    code_norms<<<dim3(NCODE), dim3(64), 0, stream>>>(codebook, cn);
    cb_transpose<<<dim3(NCODE / 64, Dc / 64), blk, 0, stream>>>(codebook, cbt);
    mels_transpose<<<dim3(Tn / 64, Bsz), blk, 0, stream>>>(mels, melsT);
    wt_transpose<<<dim3(Hc / 64, INC / 16), blk, 0, stream>>>(enc_w1, wt1, INC, Hc);
    wt_transpose<<<dim3(Dc / 64, Hc / 16), blk, 0, stream>>>(enc_w2, wt2, Hc, Dc);
    wt_transpose<<<dim3(Hc / 64, Dc / 16), blk, 0, stream>>>(dec_w1, wt3, Dc, Hc);
    wt_transpose<<<dim3(2, Hc / 16), blk, 0, stream>>>(dec_w2, wt4, Hc, INC);
    // decoder conv1 folded matrix (independent of activations)
    gemm_g<<<dim3(NCODE / 64, 12), blk, 0, stream>>>(cbt, wt3, G);
    // encoder
    conv_enc1<<<dim3(Tn / 64, Hc / 128, Bsz), blk, 0, stream>>>(melsT, wt1, enc_b1, bufA);
    conv_mid128cf<<<dim3(Tn / 128, Dc / 128, Bsz), blk, 0, stream>>>(bufA, wt2, enc_b2, bufB);
    // vector quantization
    vq_partial<<<dim3(Tn / 64, Bsz, 4), blk, 0, stream>>>(bufB, cbt, cn, candv, candi);
    vq_reduce<<<dim3(BT / 256), blk, 0, stream>>>(candv, candi, idxI, idxf);
    // decoder: conv1 via gather of G rows, then conv2 (K-split) + combine
    dec_y3<<<dim3(Tn / 64, 4, Bsz), blk, 0, stream>>>(idxI, G, dec_b1, bufA);
    conv_dec2p<<<dim3(Tn / 64, 2, Bsz), blk, 0, stream>>>(bufA, wt4, Pdec);
    dec_combine<<<dim3(RECON_N / 1024), blk, 0, stream>>>(Pdec, dec_b2, recon);
}

// Round 8
// 1715.232 us; speedup vs baseline: 1.8746x; 1.8746x over previous
//
#include <hip/hip_runtime.h>
#include <hip/hip_bf16.h>

// Problem constants
#define Bsz   16
#define Tn    2048
#define INC   80
#define Hc    512
#define Dc    512
#define NCODE 1024
#define BT    (Bsz * Tn)           // 32768
#define RECON_N (Bsz * Tn * INC)   // 2,621,440

#define AS1 __attribute__((address_space(1)))
#define AS3 __attribute__((address_space(3)))

// ---------------------------------------------------------------------------
// code_norms: CN[j] = sum_d CB[j][d]^2
// ---------------------------------------------------------------------------
__global__ __launch_bounds__(64)
void code_norms(const float* __restrict__ CB, float* __restrict__ CN) {
    int j = blockIdx.x;
    int lane = threadIdx.x;
    const float4* row = (const float4*)(CB + (size_t)j * Dc);
    float s = 0.f;
    #pragma unroll
    for (int i = 0; i < 2; ++i) {
        float4 v = row[lane + i * 64];
        s = fmaf(v.x, v.x, s);
        s = fmaf(v.y, v.y, s);
        s = fmaf(v.z, v.z, s);
        s = fmaf(v.w, v.w, s);
    }
    #pragma unroll
    for (int off = 32; off > 0; off >>= 1) s += __shfl_down(s, off, 64);
    if (lane == 0) CN[j] = s;
}

// ---------------------------------------------------------------------------
// cb_transpose: CBt[d][j] = CB[j][d].  grid (NCODE/64, Dc/64), block 256
// ---------------------------------------------------------------------------
__global__ __launch_bounds__(256)
void cb_transpose(const float* __restrict__ CB, float* __restrict__ CBt) {
    const int j0 = blockIdx.x * 64;
    const int d0 = blockIdx.y * 64;
    __shared__ float ts[64][65];
    const int tid = threadIdx.x;
    for (int i = tid; i < 4096; i += 256) {
        int r = i >> 6, c = i & 63;
        ts[r][c] = CB[(size_t)(j0 + r) * Dc + d0 + c];
    }
    __syncthreads();
    for (int i = tid; i < 4096; i += 256) {
        int r = i >> 6, c = i & 63;
        CBt[(size_t)(d0 + r) * NCODE + j0 + c] = ts[c][r];
    }
}

// ---------------------------------------------------------------------------
// mels_transpose: MT[b][c][t] = M[b][t][c].  grid (Tn/64, Bsz), block 256
// ---------------------------------------------------------------------------
__global__ __launch_bounds__(256)
void mels_transpose(const float* __restrict__ M, float* __restrict__ MT) {
    const int t0 = blockIdx.x * 64;
    const int b  = blockIdx.y;
    __shared__ float ts[64][84];
    const int tid = threadIdx.x;
    #pragma unroll
    for (int it = 0; it < 5; ++it) {
        int i = tid + it * 256;            // < 1280
        int t = i / 20, c4 = i % 20;
        *(float4*)&ts[t][c4 * 4] =
            *(const float4*)&M[((size_t)b * Tn + t0 + t) * INC + c4 * 4];
    }
    __syncthreads();
    #pragma unroll
    for (int it = 0; it < 20; ++it) {
        int i = tid + it * 256;            // < 5120
        int c = i >> 6, t = i & 63;
        MT[((size_t)b * INC + c) * Tn + t0 + t] = ts[t][c];
    }
}

// ---------------------------------------------------------------------------
// wt_transpose: Wt[(c*3+k)*Cout + o] = W[(o*Cin + c)*3 + k]
// grid (ceil(Cout/64), Cin/16), block 256
// ---------------------------------------------------------------------------
__global__ __launch_bounds__(256)
void wt_transpose(const float* __restrict__ W, float* __restrict__ Wt,
                  int Cin, int Cout) {
    const int o0 = blockIdx.x * 64;
    const int c0 = blockIdx.y * 16;
    __shared__ float ts[48][65];
    const int tid = threadIdx.x;
    for (int i = tid; i < 64 * 48; i += 256) {
        int o = i / 48, ck = i % 48;
        int oo = o0 + o;
        float v = 0.f;
        if (oo < Cout) v = W[(size_t)oo * Cin * 3 + c0 * 3 + ck];
        ts[ck][o] = v;
    }
    __syncthreads();
    for (int i = tid; i < 48 * 64; i += 256) {
        int o = i & 63, ck = i >> 6;
        int oo = o0 + o;
        if (oo < Cout) Wt[(size_t)(c0 * 3 + ck) * Cout + oo] = ts[ck][o];
    }
}

// ---------------------------------------------------------------------------
// conv_enc1 (r6 version): melsT [B,80,T] -> Y [B,512,T], K=3 SAME, ReLU.
// Tile 64 t x 128 o; per-thread 4 t x 8 o (o split {ty*4, 64+ty*4}).
// ---------------------------------------------------------------------------
__global__ __launch_bounds__(256)
void conv_enc1(const float* __restrict__ X, const float* __restrict__ Wt,
               const float* __restrict__ bias, float* __restrict__ Y) {
    const int t0 = blockIdx.x * 64;
    const int o0 = blockIdx.y * 128;
    const int b  = blockIdx.z;
    __shared__ __align__(16) float Xs[16][72];
    __shared__ __align__(16) float Ws[48][132];
    const int tid = threadIdx.x;
    const int tx = tid & 15, ty = tid >> 4;
    float acc[8][4] = {};   // [o8: og*4+oi][t4]
    const float* Xb = X + (size_t)b * INC * Tn;

    for (int c0 = 0; c0 < INC; c0 += 16) {
        for (int i = tid; i < 16 * 66; i += 256) {
            int cc = i / 66, tt = i % 66;
            int t = t0 + tt - 1;
            float v = 0.f;
            if (t >= 0 && t < Tn) v = Xb[(size_t)(c0 + cc) * Tn + t];
            Xs[cc][tt] = v;
        }
        for (int i = tid; i < 48 * 128; i += 256) {
            int o = i & 127, ck = i >> 7;
            Ws[ck][o] = Wt[(size_t)(c0 * 3 + ck) * Hc + o0 + o];
        }
        __syncthreads();
        #pragma unroll
        for (int cc = 0; cc < 16; ++cc) {
            float4 xa = *(const float4*)&Xs[cc][tx * 4];
            float2 xb2 = *(const float2*)&Xs[cc][tx * 4 + 4];
            float xv[6] = {xa.x, xa.y, xa.z, xa.w, xb2.x, xb2.y};
            #pragma unroll
            for (int k = 0; k < 3; ++k) {
                float4 wa = *(const float4*)&Ws[cc * 3 + k][ty * 4];
                float4 wb = *(const float4*)&Ws[cc * 3 + k][64 + ty * 4];
                float wv[8] = {wa.x, wa.y, wa.z, wa.w, wb.x, wb.y, wb.z, wb.w};
                #pragma unroll
                for (int i8 = 0; i8 < 8; ++i8)
                    #pragma unroll
                    for (int j = 0; j < 4; ++j)
                        acc[i8][j] = fmaf(wv[i8], xv[k + j], acc[i8][j]);
            }
        }
        __syncthreads();
    }
    float* Yb = Y + (size_t)b * Hc * Tn;
    #pragma unroll
    for (int og = 0; og < 2; ++og)
        #pragma unroll
        for (int oi = 0; oi < 4; ++oi) {
            int o = o0 + og * 64 + ty * 4 + oi;
            float bv = bias[o];
            const int i8 = og * 4 + oi;
            float4 r;
            r.x = fmaxf(acc[i8][0] + bv, 0.f);
            r.y = fmaxf(acc[i8][1] + bv, 0.f);
            r.z = fmaxf(acc[i8][2] + bv, 0.f);
            r.w = fmaxf(acc[i8][3] + bv, 0.f);
            *(float4*)&Yb[(size_t)o * Tn + t0 + tx * 4] = r;
        }
}

// ---------------------------------------------------------------------------
// conv_mid_async: X [B,512,T] -> Y [B,512,T], K=3 SAME, no relu (encoder z).
// Tile 128 t x 128 o, per-thread 8t x 8o conflict-free. Global->LDS staging
// via __builtin_amdgcn_global_load_lds into DOUBLE-BUFFERED LDS: per chunk,
// barrier (drains the loads issued a full compute-phase ago -> free), issue
// next chunk's async loads, compute current. Zero VGPR prefetch cost (r7's
// register pipeline spilled). X staged size-4 (handles the -1 halo shift);
// W staged size-16 into unpadded [48][128] (lane-contiguous; reads are
// 16-way broadcasts -> conflict-free). LDS 66 KB -> 2 blocks/CU; the async
// pipeline, not TLP, hides latency. FMA order unchanged -> z bit-identical.
// ---------------------------------------------------------------------------
__global__ __launch_bounds__(256)
void conv_mid_async(const float* __restrict__ X, const float* __restrict__ Wt,
                    const float* __restrict__ bias, float* __restrict__ Y) {
    const int t0 = blockIdx.x * 128;
    const int o0 = blockIdx.y * 128;
    const int b  = blockIdx.z;
    __shared__ __align__(16) float Xs[2][16][132];   // [buf][c][tt], tt=t-t0+1, pads 130..131
    __shared__ __align__(16) float Ws[2][48][128];   // [buf][ck][o], unpadded
    const int tid = threadIdx.x;
    const int tx = tid & 15, ty = tid >> 4;
    float acc[8][8] = {};   // [t: g*4+j][o: og*4+oi]
    const float* Xb = X + (size_t)b * Hc * Tn;
    const bool edgeL = (blockIdx.x == 0);
    const bool edgeR = (blockIdx.x == Tn / 128 - 1);

    // Per-thread staging offsets (constant across chunks).
    // X flat f = tid + it*256 over [16][132]; global col clamped (edge blocks
    // zero-fix the halo slot after the load lands).
    int xoff[9];
    #pragma unroll
    for (int it = 0; it < 9; ++it) {
        int f = tid + it * 256;
        int cc = f / 132, tt = f - cc * 132;
        int t = t0 + tt - 1;
        t = t < 0 ? 0 : (t > Tn - 1 ? Tn - 1 : t);
        xoff[it] = cc * Tn + t;
    }
    // W float4 index f4 = tid + it*256 over [48][32 float4s]
    int woff[6];
    #pragma unroll
    for (int it = 0; it < 6; ++it) {
        int f4 = tid + it * 256;
        int ck = f4 >> 5, o4 = f4 & 31;
        woff[it] = ck * Hc + o0 + o4 * 4;
    }

    // issue chunk 0 into buffer 0
    {
        #pragma unroll
        for (int it = 0; it < 9; ++it) {
            if (it < 8 || tid < 64) {   // wave-uniform tail
                const float* gp = Xb + xoff[it];
                float* lp = &Xs[0][0][0] + tid + it * 256;
                __builtin_amdgcn_global_load_lds(
                    (const AS1 void*)gp, (AS3 void*)lp, 4, 0, 0);
            }
        }
        #pragma unroll
        for (int it = 0; it < 6; ++it) {
            const float* gp = Wt + woff[it];
            float* lp = &Ws[0][0][0] + (tid + it * 256) * 4;
            __builtin_amdgcn_global_load_lds(
                (const AS1 void*)gp, (AS3 void*)lp, 16, 0, 0);
        }
    }

    int cur = 0;
    for (int c0 = 0; c0 < Hc; c0 += 16) {
        __syncthreads();   // vmcnt(0) drain: cur-buffer loads had a full compute phase
        if (edgeL || edgeR) {
            if (tid < 16) {
                if (edgeL) Xs[cur][tid][0]   = 0.f;   // t = -1
                if (edgeR) Xs[cur][tid][129] = 0.f;   // t = Tn
            }
            __syncthreads();
        }
        // issue next chunk into the other buffer (overlaps compute below)
        if (c0 + 16 < Hc) {
            const float* Xc = Xb + (size_t)(c0 + 16) * Tn;
            const float* Wc = Wt + (size_t)(c0 + 16) * 3 * Hc;
            int nxt = cur ^ 1;
            #pragma unroll
            for (int it = 0; it < 9; ++it) {
                if (it < 8 || tid < 64) {
                    const float* gp = Xc + xoff[it];
                    float* lp = &Xs[nxt][0][0] + tid + it * 256;
                    __builtin_amdgcn_global_load_lds(
                        (const AS1 void*)gp, (AS3 void*)lp, 4, 0, 0);
                }
            }
            #pragma unroll
            for (int it = 0; it < 6; ++it) {
                const float* gp = Wc + woff[it];
                float* lp = &Ws[nxt][0][0] + (tid + it * 256) * 4;
                __builtin_amdgcn_global_load_lds(
                    (const AS1 void*)gp, (AS3 void*)lp, 16, 0, 0);
            }
        }
        // compute chunk c0 from buffer cur
        #pragma unroll
        for (int cc = 0; cc < 16; ++cc) {
            float xv[2][6];
            #pragma unroll
            for (int g = 0; g < 2; ++g) {
                float4 xa = *(const float4*)&Xs[cur][cc][tx * 4 + g * 64];
                float2 xb2 = *(const float2*)&Xs[cur][cc][tx * 4 + g * 64 + 4];
                xv[g][0] = xa.x; xv[g][1] = xa.y; xv[g][2] = xa.z;
                xv[g][3] = xa.w; xv[g][4] = xb2.x; xv[g][5] = xb2.y;
            }
            #pragma unroll
            for (int k = 0; k < 3; ++k) {
                float4 wa = *(const float4*)&Ws[cur][cc * 3 + k][ty * 4];
                float4 wb = *(const float4*)&Ws[cur][cc * 3 + k][64 + ty * 4];
                float wv[8] = {wa.x, wa.y, wa.z, wa.w, wb.x, wb.y, wb.z, wb.w};
                #pragma unroll
                for (int g = 0; g < 2; ++g)
                    #pragma unroll
                    for (int j = 0; j < 4; ++j) {
                        float xx = xv[g][k + j];
                        #pragma unroll
                        for (int o8 = 0; o8 < 8; ++o8)
                            acc[g * 4 + j][o8] = fmaf(wv[o8], xx, acc[g * 4 + j][o8]);
                    }
            }
        }
        cur ^= 1;
    }
    float* Yb = Y + (size_t)b * Hc * Tn;
    #pragma unroll
    for (int og = 0; og < 2; ++og)
        #pragma unroll
        for (int oi = 0; oi < 4; ++oi) {
            int o = o0 + og * 64 + ty * 4 + oi;
            float bv = bias[o];
            const int o8 = og * 4 + oi;
            #pragma unroll
            for (int g = 0; g < 2; ++g) {
                float4 r;
                r.x = acc[g * 4 + 0][o8] + bv;
                r.y = acc[g * 4 + 1][o8] + bv;
                r.z = acc[g * 4 + 2][o8] + bv;
                r.w = acc[g * 4 + 3][o8] + bv;
                *(float4*)&Yb[(size_t)o * Tn + t0 + g * 64 + tx * 4] = r;
            }
        }
}

// ---------------------------------------------------------------------------
// conv_dec2p (r6 version): X [B,512,T] -> partial recon, K-split over c.
// half = blockIdx.y selects c in [half*256, half*256+256). 1024 blocks.
// ---------------------------------------------------------------------------
__global__ __launch_bounds__(256)
void conv_dec2p(const float* __restrict__ X, const float* __restrict__ Wt,
                float* __restrict__ P) {
    const int t0 = blockIdx.x * 64;
    const int half = blockIdx.y;
    const int b  = blockIdx.z;
    __shared__ __align__(16) float Xs[16][72];
    __shared__ __align__(16) float Ws[48][132];
    const int tid = threadIdx.x;
    const int tx = tid & 15, ty = tid >> 4;
    float acc[8][4] = {};   // [o8: og*4+oi][t4]
    const float* Xb = X + (size_t)b * Hc * Tn;
    const int cbase = half * 256;

    for (int c0 = cbase; c0 < cbase + 256; c0 += 16) {
        for (int i = tid; i < 16 * 66; i += 256) {
            int cc = i / 66, tt = i % 66;
            int t = t0 + tt - 1;
            float v = 0.f;
            if (t >= 0 && t < Tn) v = Xb[(size_t)(c0 + cc) * Tn + t];
            Xs[cc][tt] = v;
        }
        for (int i = tid; i < 48 * 128; i += 256) {
            int o = i & 127, ck = i >> 7;
            Ws[ck][o] = (o < INC) ? Wt[(size_t)(c0 * 3 + ck) * INC + o] : 0.f;
        }
        __syncthreads();
        #pragma unroll
        for (int cc = 0; cc < 16; ++cc) {
            float4 xa = *(const float4*)&Xs[cc][tx * 4];
            float2 xb2 = *(const float2*)&Xs[cc][tx * 4 + 4];
            float xv[6] = {xa.x, xa.y, xa.z, xa.w, xb2.x, xb2.y};
            #pragma unroll
            for (int k = 0; k < 3; ++k) {
                float4 wa = *(const float4*)&Ws[cc * 3 + k][ty * 4];
                float4 wb = *(const float4*)&Ws[cc * 3 + k][64 + ty * 4];
                float wv[8] = {wa.x, wa.y, wa.z, wa.w, wb.x, wb.y, wb.z, wb.w};
                #pragma unroll
                for (int i8 = 0; i8 < 8; ++i8)
                    #pragma unroll
                    for (int j = 0; j < 4; ++j)
                        acc[i8][j] = fmaf(wv[i8], xv[k + j], acc[i8][j]);
            }
        }
        __syncthreads();
    }
    float* Ph = P + (size_t)half * RECON_N;
    {
        #pragma unroll
        for (int j = 0; j < 4; ++j) {
            int t = t0 + tx * 4 + j;
            float4 s;
            s.x = acc[0][j]; s.y = acc[1][j]; s.z = acc[2][j]; s.w = acc[3][j];
            *(float4*)(Ph + ((size_t)b * Tn + t) * INC + ty * 4) = s;
        }
    }
    if (ty < 4) {
        #pragma unroll
        for (int j = 0; j < 4; ++j) {
            int t = t0 + tx * 4 + j;
            float4 s;
            s.x = acc[4][j]; s.y = acc[5][j]; s.z = acc[6][j]; s.w = acc[7][j];
            *(float4*)(Ph + ((size_t)b * Tn + t) * INC + 64 + ty * 4) = s;
        }
    }
}

// ---------------------------------------------------------------------------
// dec_combine: recon = P0 + P1 + bias. grid (RECON_N/1024), block 256, f4.
// ---------------------------------------------------------------------------
__global__ __launch_bounds__(256)
void dec_combine(const float* __restrict__ P, const float* __restrict__ bias,
                 float* __restrict__ OUT) {
    int i4 = blockIdx.x * 256 + threadIdx.x;
    float4 a = ((const float4*)P)[i4];
    float4 b = ((const float4*)(P + RECON_N))[i4];
    int o = (i4 * 4) % INC;
    float4 r;
    r.x = a.x + b.x + bias[o];
    r.y = a.y + b.y + bias[o + 1];
    r.z = a.z + b.z + bias[o + 2];
    r.w = a.w + b.w + bias[o + 3];
    ((float4*)OUT)[i4] = r;
}

// ---------------------------------------------------------------------------
// vq_partial (r6 version): per code-quarter partial argmin of CN[j]-2 z.c_j.
// grid (T/64, B, 4), block 256. Per thread: 4 positions x 16 codes.
// ---------------------------------------------------------------------------
__global__ __launch_bounds__(256)
void vq_partial(const float* __restrict__ Z, const float* __restrict__ CBt,
                const float* __restrict__ CN, float* __restrict__ candv,
                int* __restrict__ candi) {
    const int t0 = blockIdx.x * 64;
    const int b  = blockIdx.y;
    const int jbase = blockIdx.z * 256;
    const int tid = threadIdx.x;
    const int tx = tid & 15, ty = tid >> 4;
    __shared__ __align__(16) float Zs[16][68];
    __shared__ __align__(16) float Cs[16][260];
    __shared__ float rv[64][17];
    __shared__ int   ri[64][17];

    float acc[16][4] = {};   // [code16][pos]
    const float* Zb = Z + (size_t)b * Dc * Tn + t0;

    for (int d0 = 0; d0 < Dc; d0 += 16) {
        for (int i = tid; i < 1024; i += 256) {
            int dd = i >> 6, tt = i & 63;
            Zs[dd][tt] = Zb[(size_t)(d0 + dd) * Tn + tt];
        }
        for (int i = tid; i < 1024; i += 256) {
            int dd = i >> 6, j4 = i & 63;
            *(float4*)&Cs[dd][j4 * 4] =
                *(const float4*)&CBt[(size_t)(d0 + dd) * NCODE + jbase + j4 * 4];
        }
        __syncthreads();
        #pragma unroll
        for (int dd = 0; dd < 16; ++dd) {
            float4 z = *(const float4*)&Zs[dd][tx * 4];
            float zp[4] = {z.x, z.y, z.z, z.w};
            #pragma unroll
            for (int s = 0; s < 4; ++s) {
                float4 c = *(const float4*)&Cs[dd][s * 64 + ty * 4];
                float cp[4] = {c.x, c.y, c.z, c.w};
                #pragma unroll
                for (int q = 0; q < 4; ++q)
                    #pragma unroll
                    for (int p = 0; p < 4; ++p)
                        acc[s * 4 + q][p] = fmaf(cp[q], zp[p], acc[s * 4 + q][p]);
            }
        }
        __syncthreads();
    }
    float bestv[4];
    int   besti[4];
    #pragma unroll
    for (int p = 0; p < 4; ++p) { bestv[p] = 1e30f; besti[p] = 0; }
    #pragma unroll
    for (int s = 0; s < 4; ++s)
        #pragma unroll
        for (int q = 0; q < 4; ++q) {
            int j = jbase + s * 64 + ty * 4 + q;
            float cnv = CN[j];
            #pragma unroll
            for (int p = 0; p < 4; ++p) {
                float dist = fmaf(-2.f, acc[s * 4 + q][p], cnv);
                if (dist < bestv[p] || (dist == bestv[p] && j < besti[p])) {
                    bestv[p] = dist; besti[p] = j;
                }
            }
        }
    #pragma unroll
    for (int p = 0; p < 4; ++p) {
        rv[tx * 4 + p][ty] = bestv[p];
        ri[tx * 4 + p][ty] = besti[p];
    }
    __syncthreads();
    if (tid < 64) {
        float bv = rv[tid][0];
        int   bi = ri[tid][0];
        #pragma unroll
        for (int y = 1; y < 16; ++y) {
            float v = rv[tid][y];
            int   i2 = ri[tid][y];
            if (v < bv || (v == bv && i2 < bi)) { bv = v; bi = i2; }
        }
        int n = b * Tn + t0 + tid;
        candv[(size_t)blockIdx.z * BT + n] = bv;
        candi[(size_t)blockIdx.z * BT + n] = bi;
    }
}

// ---------------------------------------------------------------------------
// vq_reduce: merge 4 candidates per position. grid (BT/256), block 256
// ---------------------------------------------------------------------------
__global__ __launch_bounds__(256)
void vq_reduce(const float* __restrict__ candv, const int* __restrict__ candi,
               int* __restrict__ idxI, float* __restrict__ idxf) {
    int n = blockIdx.x * 256 + threadIdx.x;
    float bv = candv[n];
    int   bi = candi[n];
    #pragma unroll
    for (int jq = 1; jq < 4; ++jq) {
        float v = candv[(size_t)jq * BT + n];
        int   i2 = candi[(size_t)jq * BT + n];
        if (v < bv || (v == bv && i2 < bi)) { bv = v; bi = i2; }
    }
    idxI[n] = bi;
    idxf[n] = (float)bi;
}

// ---------------------------------------------------------------------------
// gemm_g: G[j][kk*512+o] = sum_c CB[j][c] * dec_w1[o][c][kk].
// grid (NCODE/64, 12): kk = y>>2, o0 = (y&3)*128. block 256, 4j x 8o.
// ---------------------------------------------------------------------------
__global__ __launch_bounds__(256)
void gemm_g(const float* __restrict__ CBt, const float* __restrict__ Wt,
            float* __restrict__ G) {
    const int j0 = blockIdx.x * 64;
    const int kk = blockIdx.y >> 2;
    const int o0 = (blockIdx.y & 3) * 128;
    __shared__ __align__(16) float As[16][68];    // [c][j]
    __shared__ __align__(16) float Bs[16][132];   // [c][o]
    const int tid = threadIdx.x;
    const int tx = tid & 15, ty = tid >> 4;
    float acc[4][8] = {};   // [j][o]

    for (int c0 = 0; c0 < Dc; c0 += 16) {
        {
            int cc = tid >> 4, j4 = tid & 15;
            *(float4*)&As[cc][j4 * 4] =
                *(const float4*)&CBt[(size_t)(c0 + cc) * NCODE + j0 + j4 * 4];
        }
        #pragma unroll
        for (int it = 0; it < 2; ++it) {
            int i = tid + it * 256;
            int cc = i >> 5, o4 = i & 31;
            *(float4*)&Bs[cc][o4 * 4] =
                *(const float4*)&Wt[(size_t)((c0 + cc) * 3 + kk) * Hc + o0 + o4 * 4];
        }
        __syncthreads();
        #pragma unroll
        for (int cc = 0; cc < 16; ++cc) {
            float4 a = *(const float4*)&As[cc][tx * 4];
            float av[4] = {a.x, a.y, a.z, a.w};
            float4 b0 = *(const float4*)&Bs[cc][ty * 4];
            float4 b1 = *(const float4*)&Bs[cc][64 + ty * 4];
            float bv[8] = {b0.x, b0.y, b0.z, b0.w, b1.x, b1.y, b1.z, b1.w};
            #pragma unroll
            for (int jj = 0; jj < 4; ++jj)
                #pragma unroll
                for (int oo = 0; oo < 8; ++oo)
                    acc[jj][oo] = fmaf(av[jj], bv[oo], acc[jj][oo]);
        }
        __syncthreads();
    }
    #pragma unroll
    for (int jj = 0; jj < 4; ++jj) {
        int j = j0 + tx * 4 + jj;
        float* gp = G + (size_t)j * 1536 + kk * 512 + o0;
        *(float4*)(gp + ty * 4) = *(float4*)&acc[jj][0];
        *(float4*)(gp + 64 + ty * 4) = *(float4*)&acc[jj][4];
    }
}

// ---------------------------------------------------------------------------
// dec_y3: y3[b][o][t] = relu(b1[o] + sum_kk G[idx[b][t+kk-1]][kk*512+o]).
// grid (T/64, 4 o-tiles, B), block 256.
// ---------------------------------------------------------------------------
__global__ __launch_bounds__(256)
void dec_y3(const int* __restrict__ idx, const float* __restrict__ G,
            const float* __restrict__ bias, float* __restrict__ Y) {
    const int t0 = blockIdx.x * 64;
    const int o0 = blockIdx.y * 128;
    const int b  = blockIdx.z;
    const int tid = threadIdx.x;
    __shared__ int sidx[66];
    __shared__ __align__(16) float Ys[128][68];

    if (tid < 66) {
        int t = t0 + tid - 1;
        sidx[tid] = (t >= 0 && t < Tn) ? idx[b * Tn + t] : -1;
    }
    __syncthreads();

    const int o = tid & 127;
    const int half = tid >> 7;
    float acc[32] = {};
    #pragma unroll
    for (int kk = 0; kk < 3; ++kk) {
        const float* Gk = G + (size_t)kk * 512 + o0 + o;
        #pragma unroll
        for (int k = 0; k < 32; ++k) {
            int j = sidx[half + 2 * k + kk];
            if (j >= 0) acc[k] += Gk[(size_t)j * 1536];
        }
    }
    float bv = bias[o0 + o];
    #pragma unroll
    for (int k = 0; k < 32; ++k)
        Ys[o][half + 2 * k] = fmaxf(acc[k] + bv, 0.f);
    __syncthreads();

    float* Yb = Y + (size_t)b * Hc * Tn + t0;
    #pragma unroll
    for (int it = 0; it < 8; ++it) {
        int i = tid + it * 256;
        int t4 = i & 15, oo = i >> 4;
        *(float4*)&Yb[(size_t)(o0 + oo) * Tn + t4 * 4] =
            *(const float4*)&Ys[oo][t4 * 4];
    }
}

// ---------------------------------------------------------------------------
extern "C" void kernel_launch(void* const* d_in, const int* in_sizes, int n_in,
                              void* d_out, int out_size, void* d_ws, size_t ws_size,
                              hipStream_t stream) {
    const float* mels    = (const float*)d_in[0];
    const float* enc_w1  = (const float*)d_in[1];
    const float* enc_b1  = (const float*)d_in[2];
    const float* enc_w2  = (const float*)d_in[3];
    const float* enc_b2  = (const float*)d_in[4];
    const float* codebook= (const float*)d_in[5];
    const float* dec_w1  = (const float*)d_in[6];
    const float* dec_b1  = (const float*)d_in[7];
    const float* dec_w2  = (const float*)d_in[8];
    const float* dec_b2  = (const float*)d_in[9];

    float* out = (float*)d_out;
    float* recon = out;                 // [B,T,80]
    float* idxf  = out + RECON_N;       // [B,T] as float

    const size_t ACT = (size_t)Bsz * Hc * Tn;   // 16,777,216 floats (64 MB)
    float* bufA = (float*)d_ws;                 // y1, later y3
    float* bufB = bufA + ACT;                   // melsT, then z, then dec partials
    int*   idxI = (int*)(bufB + ACT);           // [B*T]
    float* cn   = (float*)(idxI + BT);          // [NCODE]
    float* cbt  = cn + NCODE;                   // [512*1024]
    float* wt1  = cbt + (size_t)Dc * NCODE;     // enc_w1t: 80*3*512
    float* wt2  = wt1 + (size_t)INC * 3 * Hc;   // enc_w2t: 512*3*512
    float* wt3  = wt2 + (size_t)Hc * 3 * Dc;    // dec_w1t: 512*3*512
    float* wt4  = wt3 + (size_t)Dc * 3 * Hc;    // dec_w2t: 512*3*80
    float* candv = wt4 + (size_t)Hc * 3 * INC;  // [4*BT]
    int*   candi = (int*)(candv + 4 * BT);      // [4*BT]
    float* G    = (float*)(candi + 4 * BT);     // [1024*1536]
    float* melsT = bufB;                        // [B,80,T] (dead after enc1)
    float* Pdec  = bufB;                        // 2 partials (z dead by then)

    dim3 blk(256);
    // prep: norms + transposes (cheap, every call — graph-capture safe)
    code_norms<<<dim3(NCODE), dim3(64), 0, stream>>>(codebook, cn);
    cb_transpose<<<dim3(NCODE / 64, Dc / 64), blk, 0, stream>>>(codebook, cbt);
    mels_transpose<<<dim3(Tn / 64, Bsz), blk, 0, stream>>>(mels, melsT);
    wt_transpose<<<dim3(Hc / 64, INC / 16), blk, 0, stream>>>(enc_w1, wt1, INC, Hc);
    wt_transpose<<<dim3(Dc / 64, Hc / 16), blk, 0, stream>>>(enc_w2, wt2, Hc, Dc);
    wt_transpose<<<dim3(Hc / 64, Dc / 16), blk, 0, stream>>>(dec_w1, wt3, Dc, Hc);
    wt_transpose<<<dim3(2, Hc / 16), blk, 0, stream>>>(dec_w2, wt4, Hc, INC);
    // decoder conv1 folded matrix (independent of activations)
    gemm_g<<<dim3(NCODE / 64, 12), blk, 0, stream>>>(cbt, wt3, G);
    // encoder
    conv_enc1<<<dim3(Tn / 64, Hc / 128, Bsz), blk, 0, stream>>>(melsT, wt1, enc_b1, bufA);
    conv_mid_async<<<dim3(Tn / 128, Dc / 128, Bsz), blk, 0, stream>>>(bufA, wt2, enc_b2, bufB);
    // vector quantization
    vq_partial<<<dim3(Tn / 64, Bsz, 4), blk, 0, stream>>>(bufB, cbt, cn, candv, candi);
    vq_reduce<<<dim3(BT / 256), blk, 0, stream>>>(candv, candi, idxI, idxf);
    // decoder: conv1 via gather of G rows, then conv2 (K-split) + combine
    dec_y3<<<dim3(Tn / 64, 4, Bsz), blk, 0, stream>>>(idxI, G, dec_b1, bufA);
    conv_dec2p<<<dim3(Tn / 64, 2, Bsz), blk, 0, stream>>>(bufA, wt4, Pdec);
    dec_combine<<<dim3(RECON_N / 1024), blk, 0, stream>>>(Pdec, dec_b2, recon);
}

// Round 9
// 1517.652 us; speedup vs baseline: 2.1187x; 1.1302x over previous
//
#include <hip/hip_runtime.h>
#include <hip/hip_bf16.h>

// Problem constants
#define Bsz   16
#define Tn    2048
#define INC   80
#define Hc    512
#define Dc    512
#define NCODE 1024
#define BT    (Bsz * Tn)           // 32768
#define RECON_N (Bsz * Tn * INC)   // 2,621,440

typedef __attribute__((ext_vector_type(8))) short bf16x8;
typedef __attribute__((ext_vector_type(4))) float f32x4;

// float -> bf16 (round-to-nearest-even), and back
static __device__ __forceinline__ unsigned short f2bf(float x) {
    unsigned u = __float_as_uint(x);
    u += 0x7FFF + ((u >> 16) & 1);
    return (unsigned short)(u >> 16);
}
static __device__ __forceinline__ float bf2f(unsigned short h) {
    return __uint_as_float((unsigned)h << 16);
}

// ---------------------------------------------------------------------------
// code_norms: CN[j] = sum_d CB[j][d]^2
// ---------------------------------------------------------------------------
__global__ __launch_bounds__(64)
void code_norms(const float* __restrict__ CB, float* __restrict__ CN) {
    int j = blockIdx.x;
    int lane = threadIdx.x;
    const float4* row = (const float4*)(CB + (size_t)j * Dc);
    float s = 0.f;
    #pragma unroll
    for (int i = 0; i < 2; ++i) {
        float4 v = row[lane + i * 64];
        s = fmaf(v.x, v.x, s);
        s = fmaf(v.y, v.y, s);
        s = fmaf(v.z, v.z, s);
        s = fmaf(v.w, v.w, s);
    }
    #pragma unroll
    for (int off = 32; off > 0; off >>= 1) s += __shfl_down(s, off, 64);
    if (lane == 0) CN[j] = s;
}

// ---------------------------------------------------------------------------
// cb_transpose: CBt[d][j] = CB[j][d].  grid (NCODE/64, Dc/64), block 256
// ---------------------------------------------------------------------------
__global__ __launch_bounds__(256)
void cb_transpose(const float* __restrict__ CB, float* __restrict__ CBt) {
    const int j0 = blockIdx.x * 64;
    const int d0 = blockIdx.y * 64;
    __shared__ float ts[64][65];
    const int tid = threadIdx.x;
    for (int i = tid; i < 4096; i += 256) {
        int r = i >> 6, c = i & 63;
        ts[r][c] = CB[(size_t)(j0 + r) * Dc + d0 + c];
    }
    __syncthreads();
    for (int i = tid; i < 4096; i += 256) {
        int r = i >> 6, c = i & 63;
        CBt[(size_t)(d0 + r) * NCODE + j0 + c] = ts[c][r];
    }
}

// ---------------------------------------------------------------------------
// mels_transpose: MT[b][c][t] = M[b][t][c].  grid (Tn/64, Bsz), block 256
// ---------------------------------------------------------------------------
__global__ __launch_bounds__(256)
void mels_transpose(const float* __restrict__ M, float* __restrict__ MT) {
    const int t0 = blockIdx.x * 64;
    const int b  = blockIdx.y;
    __shared__ float ts[64][84];
    const int tid = threadIdx.x;
    #pragma unroll
    for (int it = 0; it < 5; ++it) {
        int i = tid + it * 256;            // < 1280
        int t = i / 20, c4 = i % 20;
        *(float4*)&ts[t][c4 * 4] =
            *(const float4*)&M[((size_t)b * Tn + t0 + t) * INC + c4 * 4];
    }
    __syncthreads();
    #pragma unroll
    for (int it = 0; it < 20; ++it) {
        int i = tid + it * 256;            // < 5120
        int c = i >> 6, t = i & 63;
        MT[((size_t)b * INC + c) * Tn + t0 + t] = ts[t][c];
    }
}

// ---------------------------------------------------------------------------
// wt_transpose: Wt[(c*3+k)*Cout + o] = W[(o*Cin + c)*3 + k]
// grid (ceil(Cout/64), Cin/16), block 256
// ---------------------------------------------------------------------------
__global__ __launch_bounds__(256)
void wt_transpose(const float* __restrict__ W, float* __restrict__ Wt,
                  int Cin, int Cout) {
    const int o0 = blockIdx.x * 64;
    const int c0 = blockIdx.y * 16;
    __shared__ float ts[48][65];
    const int tid = threadIdx.x;
    for (int i = tid; i < 64 * 48; i += 256) {
        int o = i / 48, ck = i % 48;
        int oo = o0 + o;
        float v = 0.f;
        if (oo < Cout) v = W[(size_t)oo * Cin * 3 + c0 * 3 + ck];
        ts[ck][o] = v;
    }
    __syncthreads();
    for (int i = tid; i < 48 * 64; i += 256) {
        int o = i & 63, ck = i >> 6;
        int oo = o0 + o;
        if (oo < Cout) Wt[(size_t)(c0 * 3 + ck) * Cout + oo] = ts[ck][o];
    }
}

// ---------------------------------------------------------------------------
// wsplit: enc_w2 [o][c][k] fp32 -> Whi/Wlo [k][o][c] bf16 (hi + residual-lo).
// grid (Hc, 3), block 256.
// ---------------------------------------------------------------------------
__global__ __launch_bounds__(256)
void wsplit(const float* __restrict__ W, unsigned short* __restrict__ Whi,
            unsigned short* __restrict__ Wlo) {
    int o = blockIdx.x, k = blockIdx.y;
    #pragma unroll
    for (int it = 0; it < 2; ++it) {
        int c = threadIdx.x + it * 256;
        float v = W[((size_t)o * Hc + c) * 3 + k];
        unsigned short h = f2bf(v);
        Whi[((size_t)k * Hc + o) * Hc + c] = h;
        Wlo[((size_t)k * Hc + o) * Hc + c] = f2bf(v - bf2f(h));
    }
}

// ---------------------------------------------------------------------------
// conv_enc1 (r6 known-good): melsT [B,80,T] -> Y [B,512,T], K=3, ReLU.
// ---------------------------------------------------------------------------
__global__ __launch_bounds__(256)
void conv_enc1(const float* __restrict__ X, const float* __restrict__ Wt,
               const float* __restrict__ bias, float* __restrict__ Y) {
    const int t0 = blockIdx.x * 64;
    const int o0 = blockIdx.y * 128;
    const int b  = blockIdx.z;
    __shared__ __align__(16) float Xs[16][72];
    __shared__ __align__(16) float Ws[48][132];
    const int tid = threadIdx.x;
    const int tx = tid & 15, ty = tid >> 4;
    float acc[8][4] = {};   // [o8: og*4+oi][t4]
    const float* Xb = X + (size_t)b * INC * Tn;

    for (int c0 = 0; c0 < INC; c0 += 16) {
        for (int i = tid; i < 16 * 66; i += 256) {
            int cc = i / 66, tt = i % 66;
            int t = t0 + tt - 1;
            float v = 0.f;
            if (t >= 0 && t < Tn) v = Xb[(size_t)(c0 + cc) * Tn + t];
            Xs[cc][tt] = v;
        }
        for (int i = tid; i < 48 * 128; i += 256) {
            int o = i & 127, ck = i >> 7;
            Ws[ck][o] = Wt[(size_t)(c0 * 3 + ck) * Hc + o0 + o];
        }
        __syncthreads();
        #pragma unroll
        for (int cc = 0; cc < 16; ++cc) {
            float4 xa = *(const float4*)&Xs[cc][tx * 4];
            float2 xb2 = *(const float2*)&Xs[cc][tx * 4 + 4];
            float xv[6] = {xa.x, xa.y, xa.z, xa.w, xb2.x, xb2.y};
            #pragma unroll
            for (int k = 0; k < 3; ++k) {
                float4 wa = *(const float4*)&Ws[cc * 3 + k][ty * 4];
                float4 wb = *(const float4*)&Ws[cc * 3 + k][64 + ty * 4];
                float wv[8] = {wa.x, wa.y, wa.z, wa.w, wb.x, wb.y, wb.z, wb.w};
                #pragma unroll
                for (int i8 = 0; i8 < 8; ++i8)
                    #pragma unroll
                    for (int j = 0; j < 4; ++j)
                        acc[i8][j] = fmaf(wv[i8], xv[k + j], acc[i8][j]);
            }
        }
        __syncthreads();
    }
    float* Yb = Y + (size_t)b * Hc * Tn;
    #pragma unroll
    for (int og = 0; og < 2; ++og)
        #pragma unroll
        for (int oi = 0; oi < 4; ++oi) {
            int o = o0 + og * 64 + ty * 4 + oi;
            float bv = bias[o];
            const int i8 = og * 4 + oi;
            float4 r;
            r.x = fmaxf(acc[i8][0] + bv, 0.f);
            r.y = fmaxf(acc[i8][1] + bv, 0.f);
            r.z = fmaxf(acc[i8][2] + bv, 0.f);
            r.w = fmaxf(acc[i8][3] + bv, 0.f);
            *(float4*)&Yb[(size_t)o * Tn + t0 + tx * 4] = r;
        }
}

// ---------------------------------------------------------------------------
// conv_mid_mfma: z = conv(y1, enc_w2) as implicit GEMM on matrix cores,
// 3xbf16 emulation (hi*hi + lo*hi + hi*lo; error ~2^-16 rel — same scale as
// the fp32 summation-order noise idx already survives vs the np reference).
// Block 128o x 128t, 4 waves in 2x2 quadrants, wave = 4x4 tiles of 16x16.
// A = W from global bf16 [k][o][c] (L2-hot, no LDS); B = X hi/lo staged to
// LDS [tt][36] (b64-aligned frag reads, conflict-free row stride 18 dwords).
// Layouts (verified m89/m120): A[m=lane&15][k=q*8+j]; B[k=q*8+j][n=lane&15];
// D col=lane&15, row=q*4+reg.
// grid (Tn/128, Hc/128, B) = 1024 blocks, block 256.
// ---------------------------------------------------------------------------
__global__ __launch_bounds__(256)
void conv_mid_mfma(const float* __restrict__ X,
                   const unsigned short* __restrict__ Whi,
                   const unsigned short* __restrict__ Wlo,
                   const float* __restrict__ bias, float* __restrict__ Y) {
    const int t0 = blockIdx.x * 128;
    const int o0 = blockIdx.y * 128;
    const int b  = blockIdx.z;
    __shared__ unsigned short XhL[130 * 36];
    __shared__ unsigned short XlL[130 * 36];
    const int tid = threadIdx.x;
    const int lane = tid & 63;
    const int wave = tid >> 6;
    const int wm = wave >> 1, wn = wave & 1;
    const int m16 = lane & 15;
    const int q = lane >> 4;
    const float* Xb = X + (size_t)b * Hc * Tn;

    f32x4 acc[4][4];
    #pragma unroll
    for (int mt = 0; mt < 4; ++mt)
        #pragma unroll
        for (int nt = 0; nt < 4; ++nt)
            acc[mt][nt] = (f32x4){0.f, 0.f, 0.f, 0.f};

    for (int c0 = 0; c0 < Hc; c0 += 32) {
        __syncthreads();   // protect LDS from overwrite while prior chunk in use
        // stage X chunk: 32 c x 130 t -> bf16 hi/lo, layout [tt][cc] pitch 36
        #pragma unroll
        for (int it = 0; it < 17; ++it) {
            int f = tid + it * 256;
            if (it < 16 || tid < 64) {     // 4160 = 16*256 + 64 (wave-uniform tail)
                int cc = f / 130, tt = f - cc * 130;
                int t = t0 + tt - 1;
                float v = (t >= 0 && t < Tn) ? Xb[(size_t)(c0 + cc) * Tn + t] : 0.f;
                unsigned short h = f2bf(v);
                XhL[tt * 36 + cc] = h;
                XlL[tt * 36 + cc] = f2bf(v - bf2f(h));
            }
        }
        __syncthreads();
        #pragma unroll
        for (int k = 0; k < 3; ++k) {
            bf16x8 Ah[4], Al[4];
            #pragma unroll
            for (int mt = 0; mt < 4; ++mt) {
                int o = o0 + wm * 64 + mt * 16 + m16;
                size_t base = (size_t)(k * Hc + o) * Hc + c0 + q * 8;
                Ah[mt] = *(const bf16x8*)(Whi + base);
                Al[mt] = *(const bf16x8*)(Wlo + base);
            }
            #pragma unroll
            for (int nt = 0; nt < 4; ++nt) {
                int tt = wn * 64 + nt * 16 + m16 + k;
                union { bf16x8 v; uint2 h[2]; } bh, bl;
                const unsigned short* ph = XhL + tt * 36 + q * 8;
                const unsigned short* pl = XlL + tt * 36 + q * 8;
                bh.h[0] = *(const uint2*)ph; bh.h[1] = *(const uint2*)(ph + 4);
                bl.h[0] = *(const uint2*)pl; bl.h[1] = *(const uint2*)(pl + 4);
                #pragma unroll
                for (int mt = 0; mt < 4; ++mt)
                    acc[mt][nt] = __builtin_amdgcn_mfma_f32_16x16x32_bf16(
                        Ah[mt], bh.v, acc[mt][nt], 0, 0, 0);
                #pragma unroll
                for (int mt = 0; mt < 4; ++mt)
                    acc[mt][nt] = __builtin_amdgcn_mfma_f32_16x16x32_bf16(
                        Al[mt], bh.v, acc[mt][nt], 0, 0, 0);
                #pragma unroll
                for (int mt = 0; mt < 4; ++mt)
                    acc[mt][nt] = __builtin_amdgcn_mfma_f32_16x16x32_bf16(
                        Ah[mt], bl.v, acc[mt][nt], 0, 0, 0);
            }
        }
    }
    float* Yb = Y + (size_t)b * Hc * Tn;
    #pragma unroll
    for (int mt = 0; mt < 4; ++mt) {
        int ob = o0 + wm * 64 + mt * 16 + q * 4;
        float4 bq = *(const float4*)&bias[ob];
        float bqa[4] = {bq.x, bq.y, bq.z, bq.w};
        #pragma unroll
        for (int nt = 0; nt < 4; ++nt) {
            int t = t0 + wn * 64 + nt * 16 + m16;
            #pragma unroll
            for (int r = 0; r < 4; ++r)
                Yb[(size_t)(ob + r) * Tn + t] = acc[mt][nt][r] + bqa[r];
        }
    }
}

// ---------------------------------------------------------------------------
// conv_dec2p (r6 known-good): X [B,512,T] -> partial recon, K-split over c.
// ---------------------------------------------------------------------------
__global__ __launch_bounds__(256)
void conv_dec2p(const float* __restrict__ X, const float* __restrict__ Wt,
                float* __restrict__ P) {
    const int t0 = blockIdx.x * 64;
    const int half = blockIdx.y;
    const int b  = blockIdx.z;
    __shared__ __align__(16) float Xs[16][72];
    __shared__ __align__(16) float Ws[48][132];
    const int tid = threadIdx.x;
    const int tx = tid & 15, ty = tid >> 4;
    float acc[8][4] = {};   // [o8: og*4+oi][t4]
    const float* Xb = X + (size_t)b * Hc * Tn;
    const int cbase = half * 256;

    for (int c0 = cbase; c0 < cbase + 256; c0 += 16) {
        for (int i = tid; i < 16 * 66; i += 256) {
            int cc = i / 66, tt = i % 66;
            int t = t0 + tt - 1;
            float v = 0.f;
            if (t >= 0 && t < Tn) v = Xb[(size_t)(c0 + cc) * Tn + t];
            Xs[cc][tt] = v;
        }
        for (int i = tid; i < 48 * 128; i += 256) {
            int o = i & 127, ck = i >> 7;
            Ws[ck][o] = (o < INC) ? Wt[(size_t)(c0 * 3 + ck) * INC + o] : 0.f;
        }
        __syncthreads();
        #pragma unroll
        for (int cc = 0; cc < 16; ++cc) {
            float4 xa = *(const float4*)&Xs[cc][tx * 4];
            float2 xb2 = *(const float2*)&Xs[cc][tx * 4 + 4];
            float xv[6] = {xa.x, xa.y, xa.z, xa.w, xb2.x, xb2.y};
            #pragma unroll
            for (int k = 0; k < 3; ++k) {
                float4 wa = *(const float4*)&Ws[cc * 3 + k][ty * 4];
                float4 wb = *(const float4*)&Ws[cc * 3 + k][64 + ty * 4];
                float wv[8] = {wa.x, wa.y, wa.z, wa.w, wb.x, wb.y, wb.z, wb.w};
                #pragma unroll
                for (int i8 = 0; i8 < 8; ++i8)
                    #pragma unroll
                    for (int j = 0; j < 4; ++j)
                        acc[i8][j] = fmaf(wv[i8], xv[k + j], acc[i8][j]);
            }
        }
        __syncthreads();
    }
    float* Ph = P + (size_t)half * RECON_N;
    {
        #pragma unroll
        for (int j = 0; j < 4; ++j) {
            int t = t0 + tx * 4 + j;
            float4 s;
            s.x = acc[0][j]; s.y = acc[1][j]; s.z = acc[2][j]; s.w = acc[3][j];
            *(float4*)(Ph + ((size_t)b * Tn + t) * INC + ty * 4) = s;
        }
    }
    if (ty < 4) {
        #pragma unroll
        for (int j = 0; j < 4; ++j) {
            int t = t0 + tx * 4 + j;
            float4 s;
            s.x = acc[4][j]; s.y = acc[5][j]; s.z = acc[6][j]; s.w = acc[7][j];
            *(float4*)(Ph + ((size_t)b * Tn + t) * INC + 64 + ty * 4) = s;
        }
    }
}

// ---------------------------------------------------------------------------
// dec_combine: recon = P0 + P1 + bias. grid (RECON_N/1024), block 256, f4.
// ---------------------------------------------------------------------------
__global__ __launch_bounds__(256)
void dec_combine(const float* __restrict__ P, const float* __restrict__ bias,
                 float* __restrict__ OUT) {
    int i4 = blockIdx.x * 256 + threadIdx.x;
    float4 a = ((const float4*)P)[i4];
    float4 b = ((const float4*)(P + RECON_N))[i4];
    int o = (i4 * 4) % INC;
    float4 r;
    r.x = a.x + b.x + bias[o];
    r.y = a.y + b.y + bias[o + 1];
    r.z = a.z + b.z + bias[o + 2];
    r.w = a.w + b.w + bias[o + 3];
    ((float4*)OUT)[i4] = r;
}

// ---------------------------------------------------------------------------
// vq_partial (r6 known-good): per code-quarter partial argmin.
// ---------------------------------------------------------------------------
__global__ __launch_bounds__(256)
void vq_partial(const float* __restrict__ Z, const float* __restrict__ CBt,
                const float* __restrict__ CN, float* __restrict__ candv,
                int* __restrict__ candi) {
    const int t0 = blockIdx.x * 64;
    const int b  = blockIdx.y;
    const int jbase = blockIdx.z * 256;
    const int tid = threadIdx.x;
    const int tx = tid & 15, ty = tid >> 4;
    __shared__ __align__(16) float Zs[16][68];
    __shared__ __align__(16) float Cs[16][260];
    __shared__ float rv[64][17];
    __shared__ int   ri[64][17];

    float acc[16][4] = {};   // [code16][pos]
    const float* Zb = Z + (size_t)b * Dc * Tn + t0;

    for (int d0 = 0; d0 < Dc; d0 += 16) {
        for (int i = tid; i < 1024; i += 256) {
            int dd = i >> 6, tt = i & 63;
            Zs[dd][tt] = Zb[(size_t)(d0 + dd) * Tn + tt];
        }
        for (int i = tid; i < 1024; i += 256) {
            int dd = i >> 6, j4 = i & 63;
            *(float4*)&Cs[dd][j4 * 4] =
                *(const float4*)&CBt[(size_t)(d0 + dd) * NCODE + jbase + j4 * 4];
        }
        __syncthreads();
        #pragma unroll
        for (int dd = 0; dd < 16; ++dd) {
            float4 z = *(const float4*)&Zs[dd][tx * 4];
            float zp[4] = {z.x, z.y, z.z, z.w};
            #pragma unroll
            for (int s = 0; s < 4; ++s) {
                float4 c = *(const float4*)&Cs[dd][s * 64 + ty * 4];
                float cp[4] = {c.x, c.y, c.z, c.w};
                #pragma unroll
                for (int qq = 0; qq < 4; ++qq)
                    #pragma unroll
                    for (int p = 0; p < 4; ++p)
                        acc[s * 4 + qq][p] = fmaf(cp[qq], zp[p], acc[s * 4 + qq][p]);
            }
        }
        __syncthreads();
    }
    float bestv[4];
    int   besti[4];
    #pragma unroll
    for (int p = 0; p < 4; ++p) { bestv[p] = 1e30f; besti[p] = 0; }
    #pragma unroll
    for (int s = 0; s < 4; ++s)
        #pragma unroll
        for (int qq = 0; qq < 4; ++qq) {
            int j = jbase + s * 64 + ty * 4 + qq;
            float cnv = CN[j];
            #pragma unroll
            for (int p = 0; p < 4; ++p) {
                float dist = fmaf(-2.f, acc[s * 4 + qq][p], cnv);
                if (dist < bestv[p] || (dist == bestv[p] && j < besti[p])) {
                    bestv[p] = dist; besti[p] = j;
                }
            }
        }
    #pragma unroll
    for (int p = 0; p < 4; ++p) {
        rv[tx * 4 + p][ty] = bestv[p];
        ri[tx * 4 + p][ty] = besti[p];
    }
    __syncthreads();
    if (tid < 64) {
        float bv = rv[tid][0];
        int   bi = ri[tid][0];
        #pragma unroll
        for (int y = 1; y < 16; ++y) {
            float v = rv[tid][y];
            int   i2 = ri[tid][y];
            if (v < bv || (v == bv && i2 < bi)) { bv = v; bi = i2; }
        }
        int n = b * Tn + t0 + tid;
        candv[(size_t)blockIdx.z * BT + n] = bv;
        candi[(size_t)blockIdx.z * BT + n] = bi;
    }
}

// ---------------------------------------------------------------------------
// vq_reduce: merge 4 candidates per position. grid (BT/256), block 256
// ---------------------------------------------------------------------------
__global__ __launch_bounds__(256)
void vq_reduce(const float* __restrict__ candv, const int* __restrict__ candi,
               int* __restrict__ idxI, float* __restrict__ idxf) {
    int n = blockIdx.x * 256 + threadIdx.x;
    float bv = candv[n];
    int   bi = candi[n];
    #pragma unroll
    for (int jq = 1; jq < 4; ++jq) {
        float v = candv[(size_t)jq * BT + n];
        int   i2 = candi[(size_t)jq * BT + n];
        if (v < bv || (v == bv && i2 < bi)) { bv = v; bi = i2; }
    }
    idxI[n] = bi;
    idxf[n] = (float)bi;
}

// ---------------------------------------------------------------------------
// gemm_g: G[j][kk*512+o] = sum_c CB[j][c] * dec_w1[o][c][kk].
// ---------------------------------------------------------------------------
__global__ __launch_bounds__(256)
void gemm_g(const float* __restrict__ CBt, const float* __restrict__ Wt,
            float* __restrict__ G) {
    const int j0 = blockIdx.x * 64;
    const int kk = blockIdx.y >> 2;
    const int o0 = (blockIdx.y & 3) * 128;
    __shared__ __align__(16) float As[16][68];    // [c][j]
    __shared__ __align__(16) float Bs[16][132];   // [c][o]
    const int tid = threadIdx.x;
    const int tx = tid & 15, ty = tid >> 4;
    float acc[4][8] = {};   // [j][o]

    for (int c0 = 0; c0 < Dc; c0 += 16) {
        {
            int cc = tid >> 4, j4 = tid & 15;
            *(float4*)&As[cc][j4 * 4] =
                *(const float4*)&CBt[(size_t)(c0 + cc) * NCODE + j0 + j4 * 4];
        }
        #pragma unroll
        for (int it = 0; it < 2; ++it) {
            int i = tid + it * 256;
            int cc = i >> 5, o4 = i & 31;
            *(float4*)&Bs[cc][o4 * 4] =
                *(const float4*)&Wt[(size_t)((c0 + cc) * 3 + kk) * Hc + o0 + o4 * 4];
        }
        __syncthreads();
        #pragma unroll
        for (int cc = 0; cc < 16; ++cc) {
            float4 a = *(const float4*)&As[cc][tx * 4];
            float av[4] = {a.x, a.y, a.z, a.w};
            float4 b0 = *(const float4*)&Bs[cc][ty * 4];
            float4 b1 = *(const float4*)&Bs[cc][64 + ty * 4];
            float bv[8] = {b0.x, b0.y, b0.z, b0.w, b1.x, b1.y, b1.z, b1.w};
            #pragma unroll
            for (int jj = 0; jj < 4; ++jj)
                #pragma unroll
                for (int oo = 0; oo < 8; ++oo)
                    acc[jj][oo] = fmaf(av[jj], bv[oo], acc[jj][oo]);
        }
        __syncthreads();
    }
    #pragma unroll
    for (int jj = 0; jj < 4; ++jj) {
        int j = j0 + tx * 4 + jj;
        float* gp = G + (size_t)j * 1536 + kk * 512 + o0;
        *(float4*)(gp + ty * 4) = *(float4*)&acc[jj][0];
        *(float4*)(gp + 64 + ty * 4) = *(float4*)&acc[jj][4];
    }
}

// ---------------------------------------------------------------------------
// dec_y3: y3[b][o][t] = relu(b1[o] + sum_kk G[idx[b][t+kk-1]][kk*512+o]).
// ---------------------------------------------------------------------------
__global__ __launch_bounds__(256)
void dec_y3(const int* __restrict__ idx, const float* __restrict__ G,
            const float* __restrict__ bias, float* __restrict__ Y) {
    const int t0 = blockIdx.x * 64;
    const int o0 = blockIdx.y * 128;
    const int b  = blockIdx.z;
    const int tid = threadIdx.x;
    __shared__ int sidx[66];
    __shared__ __align__(16) float Ys[128][68];

    if (tid < 66) {
        int t = t0 + tid - 1;
        sidx[tid] = (t >= 0 && t < Tn) ? idx[b * Tn + t] : -1;
    }
    __syncthreads();

    const int o = tid & 127;
    const int half = tid >> 7;
    float acc[32] = {};
    #pragma unroll
    for (int kk = 0; kk < 3; ++kk) {
        const float* Gk = G + (size_t)kk * 512 + o0 + o;
        #pragma unroll
        for (int k = 0; k < 32; ++k) {
            int j = sidx[half + 2 * k + kk];
            if (j >= 0) acc[k] += Gk[(size_t)j * 1536];
        }
    }
    float bv = bias[o0 + o];
    #pragma unroll
    for (int k = 0; k < 32; ++k)
        Ys[o][half + 2 * k] = fmaxf(acc[k] + bv, 0.f);
    __syncthreads();

    float* Yb = Y + (size_t)b * Hc * Tn + t0;
    #pragma unroll
    for (int it = 0; it < 8; ++it) {
        int i = tid + it * 256;
        int t4 = i & 15, oo = i >> 4;
        *(float4*)&Yb[(size_t)(o0 + oo) * Tn + t4 * 4] =
            *(const float4*)&Ys[oo][t4 * 4];
    }
}

// ---------------------------------------------------------------------------
extern "C" void kernel_launch(void* const* d_in, const int* in_sizes, int n_in,
                              void* d_out, int out_size, void* d_ws, size_t ws_size,
                              hipStream_t stream) {
    const float* mels    = (const float*)d_in[0];
    const float* enc_w1  = (const float*)d_in[1];
    const float* enc_b1  = (const float*)d_in[2];
    const float* enc_w2  = (const float*)d_in[3];
    const float* enc_b2  = (const float*)d_in[4];
    const float* codebook= (const float*)d_in[5];
    const float* dec_w1  = (const float*)d_in[6];
    const float* dec_b1  = (const float*)d_in[7];
    const float* dec_w2  = (const float*)d_in[8];
    const float* dec_b2  = (const float*)d_in[9];

    float* out = (float*)d_out;
    float* recon = out;                 // [B,T,80]
    float* idxf  = out + RECON_N;       // [B,T] as float

    const size_t ACT = (size_t)Bsz * Hc * Tn;   // 16,777,216 floats (64 MB)
    float* bufA = (float*)d_ws;                 // y1, later y3
    float* bufB = bufA + ACT;                   // melsT, then z, then dec partials
    int*   idxI = (int*)(bufB + ACT);           // [B*T]
    float* cn   = (float*)(idxI + BT);          // [NCODE]
    float* cbt  = cn + NCODE;                   // [512*1024]
    float* wt1  = cbt + (size_t)Dc * NCODE;     // enc_w1t: 80*3*512
    float* wt2  = wt1 + (size_t)INC * 3 * Hc;   // (slot kept; unused now)
    float* wt3  = wt2 + (size_t)Hc * 3 * Dc;    // dec_w1t: 512*3*512
    float* wt4  = wt3 + (size_t)Dc * 3 * Hc;    // dec_w2t: 512*3*80
    float* candv = wt4 + (size_t)Hc * 3 * INC;  // [4*BT]
    int*   candi = (int*)(candv + 4 * BT);      // [4*BT]
    float* G    = (float*)(candi + 4 * BT);     // [1024*1536]
    unsigned short* whi = (unsigned short*)(G + (size_t)NCODE * 1536); // [3*512*512]
    unsigned short* wlo = whi + (size_t)3 * Hc * Dc;                   // [3*512*512]
    float* melsT = bufB;                        // [B,80,T] (dead after enc1)
    float* Pdec  = bufB;                        // 2 partials (z dead by then)

    dim3 blk(256);
    // prep: norms + transposes + bf16 weight split (cheap, graph-capture safe)
    code_norms<<<dim3(NCODE), dim3(64), 0, stream>>>(codebook, cn);
    cb_transpose<<<dim3(NCODE / 64, Dc / 64), blk, 0, stream>>>(codebook, cbt);
    mels_transpose<<<dim3(Tn / 64, Bsz), blk, 0, stream>>>(mels, melsT);
    wt_transpose<<<dim3(Hc / 64, INC / 16), blk, 0, stream>>>(enc_w1, wt1, INC, Hc);
    wsplit<<<dim3(Hc, 3), blk, 0, stream>>>(enc_w2, whi, wlo);
    wt_transpose<<<dim3(Hc / 64, Dc / 16), blk, 0, stream>>>(dec_w1, wt3, Dc, Hc);
    wt_transpose<<<dim3(2, Hc / 16), blk, 0, stream>>>(dec_w2, wt4, Hc, INC);
    // decoder conv1 folded matrix (independent of activations)
    gemm_g<<<dim3(NCODE / 64, 12), blk, 0, stream>>>(cbt, wt3, G);
    // encoder
    conv_enc1<<<dim3(Tn / 64, Hc / 128, Bsz), blk, 0, stream>>>(melsT, wt1, enc_b1, bufA);
    conv_mid_mfma<<<dim3(Tn / 128, Hc / 128, Bsz), blk, 0, stream>>>(bufA, whi, wlo, enc_b2, bufB);
    // vector quantization
    vq_partial<<<dim3(Tn / 64, Bsz, 4), blk, 0, stream>>>(bufB, cbt, cn, candv, candi);
    vq_reduce<<<dim3(BT / 256), blk, 0, stream>>>(candv, candi, idxI, idxf);
    // decoder: conv1 via gather of G rows, then conv2 (K-split) + combine
    dec_y3<<<dim3(Tn / 64, 4, Bsz), blk, 0, stream>>>(idxI, G, dec_b1, bufA);
    conv_dec2p<<<dim3(Tn / 64, 2, Bsz), blk, 0, stream>>>(bufA, wt4, Pdec);
    dec_combine<<<dim3(RECON_N / 1024), blk, 0, stream>>>(Pdec, dec_b2, recon);
}

// Round 10
// 1240.971 us; speedup vs baseline: 2.5911x; 1.2230x over previous
//
#include <hip/hip_runtime.h>
#include <hip/hip_bf16.h>

// Problem constants
#define Bsz   16
#define Tn    2048
#define INC   80
#define Hc    512
#define Dc    512
#define NCODE 1024
#define BT    (Bsz * Tn)           // 32768
#define RECON_N (Bsz * Tn * INC)   // 2,621,440

typedef __attribute__((ext_vector_type(8))) short bf16x8;
typedef __attribute__((ext_vector_type(4))) float f32x4;

// float -> bf16 (round-to-nearest-even), and back
static __device__ __forceinline__ unsigned short f2bf(float x) {
    unsigned u = __float_as_uint(x);
    u += 0x7FFF + ((u >> 16) & 1);
    return (unsigned short)(u >> 16);
}
static __device__ __forceinline__ float bf2f(unsigned short h) {
    return __uint_as_float((unsigned)h << 16);
}

// ---------------------------------------------------------------------------
// code_norms: CN[j] = sum_d CB[j][d]^2
// ---------------------------------------------------------------------------
__global__ __launch_bounds__(64)
void code_norms(const float* __restrict__ CB, float* __restrict__ CN) {
    int j = blockIdx.x;
    int lane = threadIdx.x;
    const float4* row = (const float4*)(CB + (size_t)j * Dc);
    float s = 0.f;
    #pragma unroll
    for (int i = 0; i < 2; ++i) {
        float4 v = row[lane + i * 64];
        s = fmaf(v.x, v.x, s);
        s = fmaf(v.y, v.y, s);
        s = fmaf(v.z, v.z, s);
        s = fmaf(v.w, v.w, s);
    }
    #pragma unroll
    for (int off = 32; off > 0; off >>= 1) s += __shfl_down(s, off, 64);
    if (lane == 0) CN[j] = s;
}

// ---------------------------------------------------------------------------
// cb_transpose: CBt[d][j] = CB[j][d].  grid (NCODE/64, Dc/64), block 256
// ---------------------------------------------------------------------------
__global__ __launch_bounds__(256)
void cb_transpose(const float* __restrict__ CB, float* __restrict__ CBt) {
    const int j0 = blockIdx.x * 64;
    const int d0 = blockIdx.y * 64;
    __shared__ float ts[64][65];
    const int tid = threadIdx.x;
    for (int i = tid; i < 4096; i += 256) {
        int r = i >> 6, c = i & 63;
        ts[r][c] = CB[(size_t)(j0 + r) * Dc + d0 + c];
    }
    __syncthreads();
    for (int i = tid; i < 4096; i += 256) {
        int r = i >> 6, c = i & 63;
        CBt[(size_t)(d0 + r) * NCODE + j0 + c] = ts[c][r];
    }
}

// ---------------------------------------------------------------------------
// mels_transpose: MT[b][c][t] = M[b][t][c].  grid (Tn/64, Bsz), block 256
// ---------------------------------------------------------------------------
__global__ __launch_bounds__(256)
void mels_transpose(const float* __restrict__ M, float* __restrict__ MT) {
    const int t0 = blockIdx.x * 64;
    const int b  = blockIdx.y;
    __shared__ float ts[64][84];
    const int tid = threadIdx.x;
    #pragma unroll
    for (int it = 0; it < 5; ++it) {
        int i = tid + it * 256;            // < 1280
        int t = i / 20, c4 = i % 20;
        *(float4*)&ts[t][c4 * 4] =
            *(const float4*)&M[((size_t)b * Tn + t0 + t) * INC + c4 * 4];
    }
    __syncthreads();
    #pragma unroll
    for (int it = 0; it < 20; ++it) {
        int i = tid + it * 256;            // < 5120
        int c = i >> 6, t = i & 63;
        MT[((size_t)b * INC + c) * Tn + t0 + t] = ts[t][c];
    }
}

// ---------------------------------------------------------------------------
// wt_transpose: Wt[(c*3+k)*Cout + o] = W[(o*Cin + c)*3 + k]
// grid (ceil(Cout/64), Cin/16), block 256
// ---------------------------------------------------------------------------
__global__ __launch_bounds__(256)
void wt_transpose(const float* __restrict__ W, float* __restrict__ Wt,
                  int Cin, int Cout) {
    const int o0 = blockIdx.x * 64;
    const int c0 = blockIdx.y * 16;
    __shared__ float ts[48][65];
    const int tid = threadIdx.x;
    for (int i = tid; i < 64 * 48; i += 256) {
        int o = i / 48, ck = i % 48;
        int oo = o0 + o;
        float v = 0.f;
        if (oo < Cout) v = W[(size_t)oo * Cin * 3 + c0 * 3 + ck];
        ts[ck][o] = v;
    }
    __syncthreads();
    for (int i = tid; i < 48 * 64; i += 256) {
        int o = i & 63, ck = i >> 6;
        int oo = o0 + o;
        if (oo < Cout) Wt[(size_t)(c0 * 3 + ck) * Cout + oo] = ts[ck][o];
    }
}

// ---------------------------------------------------------------------------
// wsplit: enc_w2 [o][c][k] fp32 -> Whi/Wlo [k][o][c] bf16 (hi + residual-lo).
// grid (Hc, 3), block 256.
// ---------------------------------------------------------------------------
__global__ __launch_bounds__(256)
void wsplit(const float* __restrict__ W, unsigned short* __restrict__ Whi,
            unsigned short* __restrict__ Wlo) {
    int o = blockIdx.x, k = blockIdx.y;
    #pragma unroll
    for (int it = 0; it < 2; ++it) {
        int c = threadIdx.x + it * 256;
        float v = W[((size_t)o * Hc + c) * 3 + k];
        unsigned short h = f2bf(v);
        Whi[((size_t)k * Hc + o) * Hc + c] = h;
        Wlo[((size_t)k * Hc + o) * Hc + c] = f2bf(v - bf2f(h));
    }
}

// ---------------------------------------------------------------------------
// conv_enc1 (r6 known-good): melsT [B,80,T] -> Y [B,512,T], K=3, ReLU.
// ---------------------------------------------------------------------------
__global__ __launch_bounds__(256)
void conv_enc1(const float* __restrict__ X, const float* __restrict__ Wt,
               const float* __restrict__ bias, float* __restrict__ Y) {
    const int t0 = blockIdx.x * 64;
    const int o0 = blockIdx.y * 128;
    const int b  = blockIdx.z;
    __shared__ __align__(16) float Xs[16][72];
    __shared__ __align__(16) float Ws[48][132];
    const int tid = threadIdx.x;
    const int tx = tid & 15, ty = tid >> 4;
    float acc[8][4] = {};   // [o8: og*4+oi][t4]
    const float* Xb = X + (size_t)b * INC * Tn;

    for (int c0 = 0; c0 < INC; c0 += 16) {
        for (int i = tid; i < 16 * 66; i += 256) {
            int cc = i / 66, tt = i % 66;
            int t = t0 + tt - 1;
            float v = 0.f;
            if (t >= 0 && t < Tn) v = Xb[(size_t)(c0 + cc) * Tn + t];
            Xs[cc][tt] = v;
        }
        for (int i = tid; i < 48 * 128; i += 256) {
            int o = i & 127, ck = i >> 7;
            Ws[ck][o] = Wt[(size_t)(c0 * 3 + ck) * Hc + o0 + o];
        }
        __syncthreads();
        #pragma unroll
        for (int cc = 0; cc < 16; ++cc) {
            float4 xa = *(const float4*)&Xs[cc][tx * 4];
            float2 xb2 = *(const float2*)&Xs[cc][tx * 4 + 4];
            float xv[6] = {xa.x, xa.y, xa.z, xa.w, xb2.x, xb2.y};
            #pragma unroll
            for (int k = 0; k < 3; ++k) {
                float4 wa = *(const float4*)&Ws[cc * 3 + k][ty * 4];
                float4 wb = *(const float4*)&Ws[cc * 3 + k][64 + ty * 4];
                float wv[8] = {wa.x, wa.y, wa.z, wa.w, wb.x, wb.y, wb.z, wb.w};
                #pragma unroll
                for (int i8 = 0; i8 < 8; ++i8)
                    #pragma unroll
                    for (int j = 0; j < 4; ++j)
                        acc[i8][j] = fmaf(wv[i8], xv[k + j], acc[i8][j]);
            }
        }
        __syncthreads();
    }
    float* Yb = Y + (size_t)b * Hc * Tn;
    #pragma unroll
    for (int og = 0; og < 2; ++og)
        #pragma unroll
        for (int oi = 0; oi < 4; ++oi) {
            int o = o0 + og * 64 + ty * 4 + oi;
            float bv = bias[o];
            const int i8 = og * 4 + oi;
            float4 r;
            r.x = fmaxf(acc[i8][0] + bv, 0.f);
            r.y = fmaxf(acc[i8][1] + bv, 0.f);
            r.z = fmaxf(acc[i8][2] + bv, 0.f);
            r.w = fmaxf(acc[i8][3] + bv, 0.f);
            *(float4*)&Yb[(size_t)o * Tn + t0 + tx * 4] = r;
        }
}

// ---------------------------------------------------------------------------
// conv_mid_mfma v2: same math as r9 (3xbf16 emulated implicit GEMM, z
// bit-identical to r9 which idx survived), restructured as a ONE-barrier-
// per-chunk software pipeline with double-buffered LDS:
//   per chunk: convert regs -> ds_write buf[k&1]; barrier (vmcnt already
//   drained: xr consumed by convert); issue chunk k+1 global loads (fly
//   during compute); compute(k).
// Safety: write(k+2) happens after barrier(k+1) which post-dates all waves'
// compute(k) -> one barrier suffices. r9's stall was the serial
// [stage | barrier | compute] alternation (MfmaUtil 10.6%, VALU 7.4%).
// grid (Tn/128, Hc/128, B) = 1024 blocks, block 256.
// ---------------------------------------------------------------------------
__global__ __launch_bounds__(256)
void conv_mid_mfma(const float* __restrict__ X,
                   const unsigned short* __restrict__ Whi,
                   const unsigned short* __restrict__ Wlo,
                   const float* __restrict__ bias, float* __restrict__ Y) {
    const int t0 = blockIdx.x * 128;
    const int o0 = blockIdx.y * 128;
    const int b  = blockIdx.z;
    __shared__ unsigned short XhL[2][130 * 36];
    __shared__ unsigned short XlL[2][130 * 36];
    const int tid = threadIdx.x;
    const int lane = tid & 63;
    const int wave = tid >> 6;
    const int wm = wave >> 1, wn = wave & 1;
    const int m16 = lane & 15;
    const int q = lane >> 4;
    const float* Xb = X + (size_t)b * Hc * Tn;

    f32x4 acc[4][4];
    #pragma unroll
    for (int mt = 0; mt < 4; ++mt)
        #pragma unroll
        for (int nt = 0; nt < 4; ++nt)
            acc[mt][nt] = (f32x4){0.f, 0.f, 0.f, 0.f};

    // per-thread staging map (constant): f = tid + it*256 -> (cc, tt)
    // xr holds the raw fp32 X values of the current chunk.
    float xr[17];
    #pragma unroll
    for (int it = 0; it < 17; ++it) {
        int f = tid + it * 256;
        if (it < 16 || tid < 64) {
            int cc = f / 130, tt = f - cc * 130;
            int t = t0 + tt - 1;
            xr[it] = (t >= 0 && t < Tn) ? Xb[(size_t)cc * Tn + t] : 0.f;
        }
    }

    for (int c0 = 0; c0 < Hc; c0 += 32) {
        const int buf = (c0 >> 5) & 1;
        // convert + write current chunk into buf
        #pragma unroll
        for (int it = 0; it < 17; ++it) {
            int f = tid + it * 256;
            if (it < 16 || tid < 64) {
                int cc = f / 130, tt = f - cc * 130;
                float v = xr[it];
                unsigned short h = f2bf(v);
                XhL[buf][tt * 36 + cc] = h;
                XlL[buf][tt * 36 + cc] = f2bf(v - bf2f(h));
            }
        }
        __syncthreads();
        // issue next chunk's loads AFTER the barrier so they overlap compute
        if (c0 + 32 < Hc) {
            const float* Xc = Xb + (size_t)(c0 + 32) * Tn;
            #pragma unroll
            for (int it = 0; it < 17; ++it) {
                int f = tid + it * 256;
                if (it < 16 || tid < 64) {
                    int cc = f / 130, tt = f - cc * 130;
                    int t = t0 + tt - 1;
                    xr[it] = (t >= 0 && t < Tn) ? Xc[(size_t)cc * Tn + t] : 0.f;
                }
            }
        }
        // compute chunk c0 from buf
        #pragma unroll
        for (int k = 0; k < 3; ++k) {
            bf16x8 Ah[4], Al[4];
            #pragma unroll
            for (int mt = 0; mt < 4; ++mt) {
                int o = o0 + wm * 64 + mt * 16 + m16;
                size_t base = (size_t)(k * Hc + o) * Hc + c0 + q * 8;
                Ah[mt] = *(const bf16x8*)(Whi + base);
                Al[mt] = *(const bf16x8*)(Wlo + base);
            }
            #pragma unroll
            for (int nt = 0; nt < 4; ++nt) {
                int tt = wn * 64 + nt * 16 + m16 + k;
                union { bf16x8 v; uint2 h[2]; } bh, bl;
                const unsigned short* ph = XhL[buf] + tt * 36 + q * 8;
                const unsigned short* pl = XlL[buf] + tt * 36 + q * 8;
                bh.h[0] = *(const uint2*)ph; bh.h[1] = *(const uint2*)(ph + 4);
                bl.h[0] = *(const uint2*)pl; bl.h[1] = *(const uint2*)(pl + 4);
                #pragma unroll
                for (int mt = 0; mt < 4; ++mt)
                    acc[mt][nt] = __builtin_amdgcn_mfma_f32_16x16x32_bf16(
                        Ah[mt], bh.v, acc[mt][nt], 0, 0, 0);
                #pragma unroll
                for (int mt = 0; mt < 4; ++mt)
                    acc[mt][nt] = __builtin_amdgcn_mfma_f32_16x16x32_bf16(
                        Al[mt], bh.v, acc[mt][nt], 0, 0, 0);
                #pragma unroll
                for (int mt = 0; mt < 4; ++mt)
                    acc[mt][nt] = __builtin_amdgcn_mfma_f32_16x16x32_bf16(
                        Ah[mt], bl.v, acc[mt][nt], 0, 0, 0);
            }
        }
    }
    float* Yb = Y + (size_t)b * Hc * Tn;
    #pragma unroll
    for (int mt = 0; mt < 4; ++mt) {
        int ob = o0 + wm * 64 + mt * 16 + q * 4;
        float4 bq = *(const float4*)&bias[ob];
        float bqa[4] = {bq.x, bq.y, bq.z, bq.w};
        #pragma unroll
        for (int nt = 0; nt < 4; ++nt) {
            int t = t0 + wn * 64 + nt * 16 + m16;
            #pragma unroll
            for (int r = 0; r < 4; ++r)
                Yb[(size_t)(ob + r) * Tn + t] = acc[mt][nt][r] + bqa[r];
        }
    }
}

// ---------------------------------------------------------------------------
// conv_dec2p (r6 known-good): X [B,512,T] -> partial recon, K-split over c.
// ---------------------------------------------------------------------------
__global__ __launch_bounds__(256)
void conv_dec2p(const float* __restrict__ X, const float* __restrict__ Wt,
                float* __restrict__ P) {
    const int t0 = blockIdx.x * 64;
    const int half = blockIdx.y;
    const int b  = blockIdx.z;
    __shared__ __align__(16) float Xs[16][72];
    __shared__ __align__(16) float Ws[48][132];
    const int tid = threadIdx.x;
    const int tx = tid & 15, ty = tid >> 4;
    float acc[8][4] = {};   // [o8: og*4+oi][t4]
    const float* Xb = X + (size_t)b * Hc * Tn;
    const int cbase = half * 256;

    for (int c0 = cbase; c0 < cbase + 256; c0 += 16) {
        for (int i = tid; i < 16 * 66; i += 256) {
            int cc = i / 66, tt = i % 66;
            int t = t0 + tt - 1;
            float v = 0.f;
            if (t >= 0 && t < Tn) v = Xb[(size_t)(c0 + cc) * Tn + t];
            Xs[cc][tt] = v;
        }
        for (int i = tid; i < 48 * 128; i += 256) {
            int o = i & 127, ck = i >> 7;
            Ws[ck][o] = (o < INC) ? Wt[(size_t)(c0 * 3 + ck) * INC + o] : 0.f;
        }
        __syncthreads();
        #pragma unroll
        for (int cc = 0; cc < 16; ++cc) {
            float4 xa = *(const float4*)&Xs[cc][tx * 4];
            float2 xb2 = *(const float2*)&Xs[cc][tx * 4 + 4];
            float xv[6] = {xa.x, xa.y, xa.z, xa.w, xb2.x, xb2.y};
            #pragma unroll
            for (int k = 0; k < 3; ++k) {
                float4 wa = *(const float4*)&Ws[cc * 3 + k][ty * 4];
                float4 wb = *(const float4*)&Ws[cc * 3 + k][64 + ty * 4];
                float wv[8] = {wa.x, wa.y, wa.z, wa.w, wb.x, wb.y, wb.z, wb.w};
                #pragma unroll
                for (int i8 = 0; i8 < 8; ++i8)
                    #pragma unroll
                    for (int j = 0; j < 4; ++j)
                        acc[i8][j] = fmaf(wv[i8], xv[k + j], acc[i8][j]);
            }
        }
        __syncthreads();
    }
    float* Ph = P + (size_t)half * RECON_N;
    {
        #pragma unroll
        for (int j = 0; j < 4; ++j) {
            int t = t0 + tx * 4 + j;
            float4 s;
            s.x = acc[0][j]; s.y = acc[1][j]; s.z = acc[2][j]; s.w = acc[3][j];
            *(float4*)(Ph + ((size_t)b * Tn + t) * INC + ty * 4) = s;
        }
    }
    if (ty < 4) {
        #pragma unroll
        for (int j = 0; j < 4; ++j) {
            int t = t0 + tx * 4 + j;
            float4 s;
            s.x = acc[4][j]; s.y = acc[5][j]; s.z = acc[6][j]; s.w = acc[7][j];
            *(float4*)(Ph + ((size_t)b * Tn + t) * INC + 64 + ty * 4) = s;
        }
    }
}

// ---------------------------------------------------------------------------
// dec_combine: recon = P0 + P1 + bias. grid (RECON_N/1024), block 256, f4.
// ---------------------------------------------------------------------------
__global__ __launch_bounds__(256)
void dec_combine(const float* __restrict__ P, const float* __restrict__ bias,
                 float* __restrict__ OUT) {
    int i4 = blockIdx.x * 256 + threadIdx.x;
    float4 a = ((const float4*)P)[i4];
    float4 b = ((const float4*)(P + RECON_N))[i4];
    int o = (i4 * 4) % INC;
    float4 r;
    r.x = a.x + b.x + bias[o];
    r.y = a.y + b.y + bias[o + 1];
    r.z = a.z + b.z + bias[o + 2];
    r.w = a.w + b.w + bias[o + 3];
    ((float4*)OUT)[i4] = r;
}

// ---------------------------------------------------------------------------
// vq_partial (r6 known-good): per code-quarter partial argmin.
// ---------------------------------------------------------------------------
__global__ __launch_bounds__(256)
void vq_partial(const float* __restrict__ Z, const float* __restrict__ CBt,
                const float* __restrict__ CN, float* __restrict__ candv,
                int* __restrict__ candi) {
    const int t0 = blockIdx.x * 64;
    const int b  = blockIdx.y;
    const int jbase = blockIdx.z * 256;
    const int tid = threadIdx.x;
    const int tx = tid & 15, ty = tid >> 4;
    __shared__ __align__(16) float Zs[16][68];
    __shared__ __align__(16) float Cs[16][260];
    __shared__ float rv[64][17];
    __shared__ int   ri[64][17];

    float acc[16][4] = {};   // [code16][pos]
    const float* Zb = Z + (size_t)b * Dc * Tn + t0;

    for (int d0 = 0; d0 < Dc; d0 += 16) {
        for (int i = tid; i < 1024; i += 256) {
            int dd = i >> 6, tt = i & 63;
            Zs[dd][tt] = Zb[(size_t)(d0 + dd) * Tn + tt];
        }
        for (int i = tid; i < 1024; i += 256) {
            int dd = i >> 6, j4 = i & 63;
            *(float4*)&Cs[dd][j4 * 4] =
                *(const float4*)&CBt[(size_t)(d0 + dd) * NCODE + jbase + j4 * 4];
        }
        __syncthreads();
        #pragma unroll
        for (int dd = 0; dd < 16; ++dd) {
            float4 z = *(const float4*)&Zs[dd][tx * 4];
            float zp[4] = {z.x, z.y, z.z, z.w};
            #pragma unroll
            for (int s = 0; s < 4; ++s) {
                float4 c = *(const float4*)&Cs[dd][s * 64 + ty * 4];
                float cp[4] = {c.x, c.y, c.z, c.w};
                #pragma unroll
                for (int qq = 0; qq < 4; ++qq)
                    #pragma unroll
                    for (int p = 0; p < 4; ++p)
                        acc[s * 4 + qq][p] = fmaf(cp[qq], zp[p], acc[s * 4 + qq][p]);
            }
        }
        __syncthreads();
    }
    float bestv[4];
    int   besti[4];
    #pragma unroll
    for (int p = 0; p < 4; ++p) { bestv[p] = 1e30f; besti[p] = 0; }
    #pragma unroll
    for (int s = 0; s < 4; ++s)
        #pragma unroll
        for (int qq = 0; qq < 4; ++qq) {
            int j = jbase + s * 64 + ty * 4 + qq;
            float cnv = CN[j];
            #pragma unroll
            for (int p = 0; p < 4; ++p) {
                float dist = fmaf(-2.f, acc[s * 4 + qq][p], cnv);
                if (dist < bestv[p] || (dist == bestv[p] && j < besti[p])) {
                    bestv[p] = dist; besti[p] = j;
                }
            }
        }
    #pragma unroll
    for (int p = 0; p < 4; ++p) {
        rv[tx * 4 + p][ty] = bestv[p];
        ri[tx * 4 + p][ty] = besti[p];
    }
    __syncthreads();
    if (tid < 64) {
        float bv = rv[tid][0];
        int   bi = ri[tid][0];
        #pragma unroll
        for (int y = 1; y < 16; ++y) {
            float v = rv[tid][y];
            int   i2 = ri[tid][y];
            if (v < bv || (v == bv && i2 < bi)) { bv = v; bi = i2; }
        }
        int n = b * Tn + t0 + tid;
        candv[(size_t)blockIdx.z * BT + n] = bv;
        candi[(size_t)blockIdx.z * BT + n] = bi;
    }
}

// ---------------------------------------------------------------------------
// vq_reduce: merge 4 candidates per position. grid (BT/256), block 256
// ---------------------------------------------------------------------------
__global__ __launch_bounds__(256)
void vq_reduce(const float* __restrict__ candv, const int* __restrict__ candi,
               int* __restrict__ idxI, float* __restrict__ idxf) {
    int n = blockIdx.x * 256 + threadIdx.x;
    float bv = candv[n];
    int   bi = candi[n];
    #pragma unroll
    for (int jq = 1; jq < 4; ++jq) {
        float v = candv[(size_t)jq * BT + n];
        int   i2 = candi[(size_t)jq * BT + n];
        if (v < bv || (v == bv && i2 < bi)) { bv = v; bi = i2; }
    }
    idxI[n] = bi;
    idxf[n] = (float)bi;
}

// ---------------------------------------------------------------------------
// gemm_g: G[j][kk*512+o] = sum_c CB[j][c] * dec_w1[o][c][kk].
// ---------------------------------------------------------------------------
__global__ __launch_bounds__(256)
void gemm_g(const float* __restrict__ CBt, const float* __restrict__ Wt,
            float* __restrict__ G) {
    const int j0 = blockIdx.x * 64;
    const int kk = blockIdx.y >> 2;
    const int o0 = (blockIdx.y & 3) * 128;
    __shared__ __align__(16) float As[16][68];    // [c][j]
    __shared__ __align__(16) float Bs[16][132];   // [c][o]
    const int tid = threadIdx.x;
    const int tx = tid & 15, ty = tid >> 4;
    float acc[4][8] = {};   // [j][o]

    for (int c0 = 0; c0 < Dc; c0 += 16) {
        {
            int cc = tid >> 4, j4 = tid & 15;
            *(float4*)&As[cc][j4 * 4] =
                *(const float4*)&CBt[(size_t)(c0 + cc) * NCODE + j0 + j4 * 4];
        }
        #pragma unroll
        for (int it = 0; it < 2; ++it) {
            int i = tid + it * 256;
            int cc = i >> 5, o4 = i & 31;
            *(float4*)&Bs[cc][o4 * 4] =
                *(const float4*)&Wt[(size_t)((c0 + cc) * 3 + kk) * Hc + o0 + o4 * 4];
        }
        __syncthreads();
        #pragma unroll
        for (int cc = 0; cc < 16; ++cc) {
            float4 a = *(const float4*)&As[cc][tx * 4];
            float av[4] = {a.x, a.y, a.z, a.w};
            float4 b0 = *(const float4*)&Bs[cc][ty * 4];
            float4 b1 = *(const float4*)&Bs[cc][64 + ty * 4];
            float bv[8] = {b0.x, b0.y, b0.z, b0.w, b1.x, b1.y, b1.z, b1.w};
            #pragma unroll
            for (int jj = 0; jj < 4; ++jj)
                #pragma unroll
                for (int oo = 0; oo < 8; ++oo)
                    acc[jj][oo] = fmaf(av[jj], bv[oo], acc[jj][oo]);
        }
        __syncthreads();
    }
    #pragma unroll
    for (int jj = 0; jj < 4; ++jj) {
        int j = j0 + tx * 4 + jj;
        float* gp = G + (size_t)j * 1536 + kk * 512 + o0;
        *(float4*)(gp + ty * 4) = *(float4*)&acc[jj][0];
        *(float4*)(gp + 64 + ty * 4) = *(float4*)&acc[jj][4];
    }
}

// ---------------------------------------------------------------------------
// dec_y3: y3[b][o][t] = relu(b1[o] + sum_kk G[idx[b][t+kk-1]][kk*512+o]).
// ---------------------------------------------------------------------------
__global__ __launch_bounds__(256)
void dec_y3(const int* __restrict__ idx, const float* __restrict__ G,
            const float* __restrict__ bias, float* __restrict__ Y) {
    const int t0 = blockIdx.x * 64;
    const int o0 = blockIdx.y * 128;
    const int b  = blockIdx.z;
    const int tid = threadIdx.x;
    __shared__ int sidx[66];
    __shared__ __align__(16) float Ys[128][68];

    if (tid < 66) {
        int t = t0 + tid - 1;
        sidx[tid] = (t >= 0 && t < Tn) ? idx[b * Tn + t] : -1;
    }
    __syncthreads();

    const int o = tid & 127;
    const int half = tid >> 7;
    float acc[32] = {};
    #pragma unroll
    for (int kk = 0; kk < 3; ++kk) {
        const float* Gk = G + (size_t)kk * 512 + o0 + o;
        #pragma unroll
        for (int k = 0; k < 32; ++k) {
            int j = sidx[half + 2 * k + kk];
            if (j >= 0) acc[k] += Gk[(size_t)j * 1536];
        }
    }
    float bv = bias[o0 + o];
    #pragma unroll
    for (int k = 0; k < 32; ++k)
        Ys[o][half + 2 * k] = fmaxf(acc[k] + bv, 0.f);
    __syncthreads();

    float* Yb = Y + (size_t)b * Hc * Tn + t0;
    #pragma unroll
    for (int it = 0; it < 8; ++it) {
        int i = tid + it * 256;
        int t4 = i & 15, oo = i >> 4;
        *(float4*)&Yb[(size_t)(o0 + oo) * Tn + t4 * 4] =
            *(const float4*)&Ys[oo][t4 * 4];
    }
}

// ---------------------------------------------------------------------------
extern "C" void kernel_launch(void* const* d_in, const int* in_sizes, int n_in,
                              void* d_out, int out_size, void* d_ws, size_t ws_size,
                              hipStream_t stream) {
    const float* mels    = (const float*)d_in[0];
    const float* enc_w1  = (const float*)d_in[1];
    const float* enc_b1  = (const float*)d_in[2];
    const float* enc_w2  = (const float*)d_in[3];
    const float* enc_b2  = (const float*)d_in[4];
    const float* codebook= (const float*)d_in[5];
    const float* dec_w1  = (const float*)d_in[6];
    const float* dec_b1  = (const float*)d_in[7];
    const float* dec_w2  = (const float*)d_in[8];
    const float* dec_b2  = (const float*)d_in[9];

    float* out = (float*)d_out;
    float* recon = out;                 // [B,T,80]
    float* idxf  = out + RECON_N;       // [B,T] as float

    const size_t ACT = (size_t)Bsz * Hc * Tn;   // 16,777,216 floats (64 MB)
    float* bufA = (float*)d_ws;                 // y1, later y3
    float* bufB = bufA + ACT;                   // melsT, then z, then dec partials
    int*   idxI = (int*)(bufB + ACT);           // [B*T]
    float* cn   = (float*)(idxI + BT);          // [NCODE]
    float* cbt  = cn + NCODE;                   // [512*1024]
    float* wt1  = cbt + (size_t)Dc * NCODE;     // enc_w1t: 80*3*512
    float* wt2  = wt1 + (size_t)INC * 3 * Hc;   // (slot kept; unused now)
    float* wt3  = wt2 + (size_t)Hc * 3 * Dc;    // dec_w1t: 512*3*512
    float* wt4  = wt3 + (size_t)Dc * 3 * Hc;    // dec_w2t: 512*3*80
    float* candv = wt4 + (size_t)Hc * 3 * INC;  // [4*BT]
    int*   candi = (int*)(candv + 4 * BT);      // [4*BT]
    float* G    = (float*)(candi + 4 * BT);     // [1024*1536]
    unsigned short* whi = (unsigned short*)(G + (size_t)NCODE * 1536); // [3*512*512]
    unsigned short* wlo = whi + (size_t)3 * Hc * Dc;                   // [3*512*512]
    float* melsT = bufB;                        // [B,80,T] (dead after enc1)
    float* Pdec  = bufB;                        // 2 partials (z dead by then)

    dim3 blk(256);
    // prep: norms + transposes + bf16 weight split (cheap, graph-capture safe)
    code_norms<<<dim3(NCODE), dim3(64), 0, stream>>>(codebook, cn);
    cb_transpose<<<dim3(NCODE / 64, Dc / 64), blk, 0, stream>>>(codebook, cbt);
    mels_transpose<<<dim3(Tn / 64, Bsz), blk, 0, stream>>>(mels, melsT);
    wt_transpose<<<dim3(Hc / 64, INC / 16), blk, 0, stream>>>(enc_w1, wt1, INC, Hc);
    wsplit<<<dim3(Hc, 3), blk, 0, stream>>>(enc_w2, whi, wlo);
    wt_transpose<<<dim3(Hc / 64, Dc / 16), blk, 0, stream>>>(dec_w1, wt3, Dc, Hc);
    wt_transpose<<<dim3(2, Hc / 16), blk, 0, stream>>>(dec_w2, wt4, Hc, INC);
    // decoder conv1 folded matrix (independent of activations)
    gemm_g<<<dim3(NCODE / 64, 12), blk, 0, stream>>>(cbt, wt3, G);
    // encoder
    conv_enc1<<<dim3(Tn / 64, Hc / 128, Bsz), blk, 0, stream>>>(melsT, wt1, enc_b1, bufA);
    conv_mid_mfma<<<dim3(Tn / 128, Hc / 128, Bsz), blk, 0, stream>>>(bufA, whi, wlo, enc_b2, bufB);
    // vector quantization
    vq_partial<<<dim3(Tn / 64, Bsz, 4), blk, 0, stream>>>(bufB, cbt, cn, candv, candi);
    vq_reduce<<<dim3(BT / 256), blk, 0, stream>>>(candv, candi, idxI, idxf);
    // decoder: conv1 via gather of G rows, then conv2 (K-split) + combine
    dec_y3<<<dim3(Tn / 64, 4, Bsz), blk, 0, stream>>>(idxI, G, dec_b1, bufA);
    conv_dec2p<<<dim3(Tn / 64, 2, Bsz), blk, 0, stream>>>(bufA, wt4, Pdec);
    dec_combine<<<dim3(RECON_N / 1024), blk, 0, stream>>>(Pdec, dec_b2, recon);
}

// Round 11
// 1042.398 us; speedup vs baseline: 3.0847x; 1.1905x over previous
//
#include <hip/hip_runtime.h>
#include <hip/hip_bf16.h>

// Problem constants
#define Bsz   16
#define Tn    2048
#define INC   80
#define Hc    512
#define Dc    512
#define NCODE 1024
#define BT    (Bsz * Tn)           // 32768
#define RECON_N (Bsz * Tn * INC)   // 2,621,440
#define MARGIN 0.03f               // approx-distance safety margin (>>40 sigma of bf16x3 err)

typedef __attribute__((ext_vector_type(8))) short bf16x8;
typedef __attribute__((ext_vector_type(4))) float f32x4;

// float -> bf16 (round-to-nearest-even), and back
static __device__ __forceinline__ unsigned short f2bf(float x) {
    unsigned u = __float_as_uint(x);
    u += 0x7FFF + ((u >> 16) & 1);
    return (unsigned short)(u >> 16);
}
static __device__ __forceinline__ float bf2f(unsigned short h) {
    return __uint_as_float((unsigned)h << 16);
}

// ---------------------------------------------------------------------------
// code_norms: CN[j] = sum_d CB[j][d]^2
// ---------------------------------------------------------------------------
__global__ __launch_bounds__(64)
void code_norms(const float* __restrict__ CB, float* __restrict__ CN) {
    int j = blockIdx.x;
    int lane = threadIdx.x;
    const float4* row = (const float4*)(CB + (size_t)j * Dc);
    float s = 0.f;
    #pragma unroll
    for (int i = 0; i < 2; ++i) {
        float4 v = row[lane + i * 64];
        s = fmaf(v.x, v.x, s);
        s = fmaf(v.y, v.y, s);
        s = fmaf(v.z, v.z, s);
        s = fmaf(v.w, v.w, s);
    }
    #pragma unroll
    for (int off = 32; off > 0; off >>= 1) s += __shfl_down(s, off, 64);
    if (lane == 0) CN[j] = s;
}

// ---------------------------------------------------------------------------
// cb_transpose: CBt[d][j] = CB[j][d].  grid (NCODE/64, Dc/64), block 256
// ---------------------------------------------------------------------------
__global__ __launch_bounds__(256)
void cb_transpose(const float* __restrict__ CB, float* __restrict__ CBt) {
    const int j0 = blockIdx.x * 64;
    const int d0 = blockIdx.y * 64;
    __shared__ float ts[64][65];
    const int tid = threadIdx.x;
    for (int i = tid; i < 4096; i += 256) {
        int r = i >> 6, c = i & 63;
        ts[r][c] = CB[(size_t)(j0 + r) * Dc + d0 + c];
    }
    __syncthreads();
    for (int i = tid; i < 4096; i += 256) {
        int r = i >> 6, c = i & 63;
        CBt[(size_t)(d0 + r) * NCODE + j0 + c] = ts[c][r];
    }
}

// ---------------------------------------------------------------------------
// mels_transpose: MT[b][c][t] = M[b][t][c].  grid (Tn/64, Bsz), block 256
// ---------------------------------------------------------------------------
__global__ __launch_bounds__(256)
void mels_transpose(const float* __restrict__ M, float* __restrict__ MT) {
    const int t0 = blockIdx.x * 64;
    const int b  = blockIdx.y;
    __shared__ float ts[64][84];
    const int tid = threadIdx.x;
    #pragma unroll
    for (int it = 0; it < 5; ++it) {
        int i = tid + it * 256;            // < 1280
        int t = i / 20, c4 = i % 20;
        *(float4*)&ts[t][c4 * 4] =
            *(const float4*)&M[((size_t)b * Tn + t0 + t) * INC + c4 * 4];
    }
    __syncthreads();
    #pragma unroll
    for (int it = 0; it < 20; ++it) {
        int i = tid + it * 256;            // < 5120
        int c = i >> 6, t = i & 63;
        MT[((size_t)b * INC + c) * Tn + t0 + t] = ts[t][c];
    }
}

// ---------------------------------------------------------------------------
// wt_transpose: Wt[(c*3+k)*Cout + o] = W[(o*Cin + c)*3 + k]
// ---------------------------------------------------------------------------
__global__ __launch_bounds__(256)
void wt_transpose(const float* __restrict__ W, float* __restrict__ Wt,
                  int Cin, int Cout) {
    const int o0 = blockIdx.x * 64;
    const int c0 = blockIdx.y * 16;
    __shared__ float ts[48][65];
    const int tid = threadIdx.x;
    for (int i = tid; i < 64 * 48; i += 256) {
        int o = i / 48, ck = i % 48;
        int oo = o0 + o;
        float v = 0.f;
        if (oo < Cout) v = W[(size_t)oo * Cin * 3 + c0 * 3 + ck];
        ts[ck][o] = v;
    }
    __syncthreads();
    for (int i = tid; i < 48 * 64; i += 256) {
        int o = i & 63, ck = i >> 6;
        int oo = o0 + o;
        if (oo < Cout) Wt[(size_t)(c0 * 3 + ck) * Cout + oo] = ts[ck][o];
    }
}

// ---------------------------------------------------------------------------
// wsplit: enc_w2 [o][c][k] fp32 -> Whi/Wlo [k][o][c] bf16 (hi + residual-lo).
// ---------------------------------------------------------------------------
__global__ __launch_bounds__(256)
void wsplit(const float* __restrict__ W, unsigned short* __restrict__ Whi,
            unsigned short* __restrict__ Wlo) {
    int o = blockIdx.x, k = blockIdx.y;
    #pragma unroll
    for (int it = 0; it < 2; ++it) {
        int c = threadIdx.x + it * 256;
        float v = W[((size_t)o * Hc + c) * 3 + k];
        unsigned short h = f2bf(v);
        Whi[((size_t)k * Hc + o) * Hc + c] = h;
        Wlo[((size_t)k * Hc + o) * Hc + c] = f2bf(v - bf2f(h));
    }
}

// ---------------------------------------------------------------------------
// cbsplit: codebook [j][d] fp32 -> CBh/CBl [j][d] bf16. grid (NCODE), blk 256
// ---------------------------------------------------------------------------
__global__ __launch_bounds__(256)
void cbsplit(const float* __restrict__ CB, unsigned short* __restrict__ CBh,
             unsigned short* __restrict__ CBl) {
    int j = blockIdx.x;
    #pragma unroll
    for (int it = 0; it < 2; ++it) {
        int d = threadIdx.x + it * 256;
        float v = CB[(size_t)j * Dc + d];
        unsigned short h = f2bf(v);
        CBh[(size_t)j * Dc + d] = h;
        CBl[(size_t)j * Dc + d] = f2bf(v - bf2f(h));
    }
}

// ---------------------------------------------------------------------------
// conv_enc1 (known-good): melsT [B,80,T] -> Y [B,512,T], K=3, ReLU.
// ---------------------------------------------------------------------------
__global__ __launch_bounds__(256)
void conv_enc1(const float* __restrict__ X, const float* __restrict__ Wt,
               const float* __restrict__ bias, float* __restrict__ Y) {
    const int t0 = blockIdx.x * 64;
    const int o0 = blockIdx.y * 128;
    const int b  = blockIdx.z;
    __shared__ __align__(16) float Xs[16][72];
    __shared__ __align__(16) float Ws[48][132];
    const int tid = threadIdx.x;
    const int tx = tid & 15, ty = tid >> 4;
    float acc[8][4] = {};
    const float* Xb = X + (size_t)b * INC * Tn;

    for (int c0 = 0; c0 < INC; c0 += 16) {
        for (int i = tid; i < 16 * 66; i += 256) {
            int cc = i / 66, tt = i % 66;
            int t = t0 + tt - 1;
            float v = 0.f;
            if (t >= 0 && t < Tn) v = Xb[(size_t)(c0 + cc) * Tn + t];
            Xs[cc][tt] = v;
        }
        for (int i = tid; i < 48 * 128; i += 256) {
            int o = i & 127, ck = i >> 7;
            Ws[ck][o] = Wt[(size_t)(c0 * 3 + ck) * Hc + o0 + o];
        }
        __syncthreads();
        #pragma unroll
        for (int cc = 0; cc < 16; ++cc) {
            float4 xa = *(const float4*)&Xs[cc][tx * 4];
            float2 xb2 = *(const float2*)&Xs[cc][tx * 4 + 4];
            float xv[6] = {xa.x, xa.y, xa.z, xa.w, xb2.x, xb2.y};
            #pragma unroll
            for (int k = 0; k < 3; ++k) {
                float4 wa = *(const float4*)&Ws[cc * 3 + k][ty * 4];
                float4 wb = *(const float4*)&Ws[cc * 3 + k][64 + ty * 4];
                float wv[8] = {wa.x, wa.y, wa.z, wa.w, wb.x, wb.y, wb.z, wb.w};
                #pragma unroll
                for (int i8 = 0; i8 < 8; ++i8)
                    #pragma unroll
                    for (int j = 0; j < 4; ++j)
                        acc[i8][j] = fmaf(wv[i8], xv[k + j], acc[i8][j]);
            }
        }
        __syncthreads();
    }
    float* Yb = Y + (size_t)b * Hc * Tn;
    #pragma unroll
    for (int og = 0; og < 2; ++og)
        #pragma unroll
        for (int oi = 0; oi < 4; ++oi) {
            int o = o0 + og * 64 + ty * 4 + oi;
            float bv = bias[o];
            const int i8 = og * 4 + oi;
            float4 r;
            r.x = fmaxf(acc[i8][0] + bv, 0.f);
            r.y = fmaxf(acc[i8][1] + bv, 0.f);
            r.z = fmaxf(acc[i8][2] + bv, 0.f);
            r.w = fmaxf(acc[i8][3] + bv, 0.f);
            *(float4*)&Yb[(size_t)o * Tn + t0 + tx * 4] = r;
        }
}

// ---------------------------------------------------------------------------
// conv_mid_mfma (r10 known-good): 3xbf16 emulated implicit GEMM, one-barrier
// pipelined double-buffered LDS.
// ---------------------------------------------------------------------------
__global__ __launch_bounds__(256)
void conv_mid_mfma(const float* __restrict__ X,
                   const unsigned short* __restrict__ Whi,
                   const unsigned short* __restrict__ Wlo,
                   const float* __restrict__ bias, float* __restrict__ Y) {
    const int t0 = blockIdx.x * 128;
    const int o0 = blockIdx.y * 128;
    const int b  = blockIdx.z;
    __shared__ unsigned short XhL[2][130 * 36];
    __shared__ unsigned short XlL[2][130 * 36];
    const int tid = threadIdx.x;
    const int lane = tid & 63;
    const int wave = tid >> 6;
    const int wm = wave >> 1, wn = wave & 1;
    const int m16 = lane & 15;
    const int q = lane >> 4;
    const float* Xb = X + (size_t)b * Hc * Tn;

    f32x4 acc[4][4];
    #pragma unroll
    for (int mt = 0; mt < 4; ++mt)
        #pragma unroll
        for (int nt = 0; nt < 4; ++nt)
            acc[mt][nt] = (f32x4){0.f, 0.f, 0.f, 0.f};

    float xr[17];
    #pragma unroll
    for (int it = 0; it < 17; ++it) {
        int f = tid + it * 256;
        if (it < 16 || tid < 64) {
            int cc = f / 130, tt = f - cc * 130;
            int t = t0 + tt - 1;
            xr[it] = (t >= 0 && t < Tn) ? Xb[(size_t)cc * Tn + t] : 0.f;
        }
    }

    for (int c0 = 0; c0 < Hc; c0 += 32) {
        const int buf = (c0 >> 5) & 1;
        #pragma unroll
        for (int it = 0; it < 17; ++it) {
            int f = tid + it * 256;
            if (it < 16 || tid < 64) {
                int cc = f / 130, tt = f - cc * 130;
                float v = xr[it];
                unsigned short h = f2bf(v);
                XhL[buf][tt * 36 + cc] = h;
                XlL[buf][tt * 36 + cc] = f2bf(v - bf2f(h));
            }
        }
        __syncthreads();
        if (c0 + 32 < Hc) {
            const float* Xc = Xb + (size_t)(c0 + 32) * Tn;
            #pragma unroll
            for (int it = 0; it < 17; ++it) {
                int f = tid + it * 256;
                if (it < 16 || tid < 64) {
                    int cc = f / 130, tt = f - cc * 130;
                    int t = t0 + tt - 1;
                    xr[it] = (t >= 0 && t < Tn) ? Xc[(size_t)cc * Tn + t] : 0.f;
                }
            }
        }
        #pragma unroll
        for (int k = 0; k < 3; ++k) {
            bf16x8 Ah[4], Al[4];
            #pragma unroll
            for (int mt = 0; mt < 4; ++mt) {
                int o = o0 + wm * 64 + mt * 16 + m16;
                size_t base = (size_t)(k * Hc + o) * Hc + c0 + q * 8;
                Ah[mt] = *(const bf16x8*)(Whi + base);
                Al[mt] = *(const bf16x8*)(Wlo + base);
            }
            #pragma unroll
            for (int nt = 0; nt < 4; ++nt) {
                int tt = wn * 64 + nt * 16 + m16 + k;
                union { bf16x8 v; uint2 h[2]; } bh, bl;
                const unsigned short* ph = XhL[buf] + tt * 36 + q * 8;
                const unsigned short* pl = XlL[buf] + tt * 36 + q * 8;
                bh.h[0] = *(const uint2*)ph; bh.h[1] = *(const uint2*)(ph + 4);
                bl.h[0] = *(const uint2*)pl; bl.h[1] = *(const uint2*)(pl + 4);
                #pragma unroll
                for (int mt = 0; mt < 4; ++mt)
                    acc[mt][nt] = __builtin_amdgcn_mfma_f32_16x16x32_bf16(
                        Ah[mt], bh.v, acc[mt][nt], 0, 0, 0);
                #pragma unroll
                for (int mt = 0; mt < 4; ++mt)
                    acc[mt][nt] = __builtin_amdgcn_mfma_f32_16x16x32_bf16(
                        Al[mt], bh.v, acc[mt][nt], 0, 0, 0);
                #pragma unroll
                for (int mt = 0; mt < 4; ++mt)
                    acc[mt][nt] = __builtin_amdgcn_mfma_f32_16x16x32_bf16(
                        Ah[mt], bl.v, acc[mt][nt], 0, 0, 0);
            }
        }
    }
    float* Yb = Y + (size_t)b * Hc * Tn;
    #pragma unroll
    for (int mt = 0; mt < 4; ++mt) {
        int ob = o0 + wm * 64 + mt * 16 + q * 4;
        float4 bq = *(const float4*)&bias[ob];
        float bqa[4] = {bq.x, bq.y, bq.z, bq.w};
        #pragma unroll
        for (int nt = 0; nt < 4; ++nt) {
            int t = t0 + wn * 64 + nt * 16 + m16;
            #pragma unroll
            for (int r = 0; r < 4; ++r)
                Yb[(size_t)(ob + r) * Tn + t] = acc[mt][nt][r] + bqa[r];
        }
    }
}

// ---------------------------------------------------------------------------
// vq_mfma: approx distances via 3xbf16 MFMA GEMM D[j][t] = CN[j] - 2*z.c.
// Per block: 128 codes (jb) x 128 positions; per-position best1/best2 over
// the block's codes -> candidates [8][BT]. Same staging pipeline as conv_mid.
// grid (BT/128, NCODE/128) = (256, 8), block 256.
// ---------------------------------------------------------------------------
__global__ __launch_bounds__(256)
void vq_mfma(const float* __restrict__ Z,
             const unsigned short* __restrict__ CBh,
             const unsigned short* __restrict__ CBl,
             const float* __restrict__ CN,
             float* __restrict__ candv, int* __restrict__ candi,
             float* __restrict__ cand2v) {
    const int nb = blockIdx.x;
    const int jb = blockIdx.y;
    const int b  = nb >> 4;
    const int t0 = (nb & 15) * 128;
    const int jbase = jb * 128;
    __shared__ __align__(16) unsigned char pool[4 * 128 * 36 * 2]; // 36864 B
    unsigned short* XhP = (unsigned short*)pool;            // [2][128*36]
    unsigned short* XlP = XhP + 2 * 128 * 36;               // [2][128*36]
    float* RV = (float*)pool;                               // [128][8] (reuse)
    int*   RI = (int*)(pool + 128 * 8 * 4);
    float* R2 = (float*)(pool + 2 * 128 * 8 * 4);

    const int tid = threadIdx.x;
    const int lane = tid & 63;
    const int wave = tid >> 6;
    const int wm = wave >> 1, wn = wave & 1;
    const int m16 = lane & 15;
    const int q = lane >> 4;
    const float* Zb = Z + (size_t)b * Dc * Tn + t0;

    f32x4 acc[4][4];
    #pragma unroll
    for (int mt = 0; mt < 4; ++mt)
        #pragma unroll
        for (int nt = 0; nt < 4; ++nt)
            acc[mt][nt] = (f32x4){0.f, 0.f, 0.f, 0.f};

    // prefetch chunk 0: 32 d x 128 t, coalesced over t
    float xr[16];
    #pragma unroll
    for (int it = 0; it < 16; ++it) {
        int f = tid + it * 256;
        xr[it] = Zb[(size_t)(f >> 7) * Tn + (f & 127)];
    }

    for (int d0 = 0; d0 < Dc; d0 += 32) {
        const int buf = (d0 >> 5) & 1;
        unsigned short* Xh = XhP + buf * (128 * 36);
        unsigned short* Xl = XlP + buf * (128 * 36);
        #pragma unroll
        for (int it = 0; it < 16; ++it) {
            int f = tid + it * 256;
            int dd = f >> 7, tt = f & 127;
            float v = xr[it];
            unsigned short h = f2bf(v);
            Xh[tt * 36 + dd] = h;
            Xl[tt * 36 + dd] = f2bf(v - bf2f(h));
        }
        __syncthreads();
        if (d0 + 32 < Dc) {
            const float* Zc = Zb + (size_t)(d0 + 32) * Tn;
            #pragma unroll
            for (int it = 0; it < 16; ++it) {
                int f = tid + it * 256;
                xr[it] = Zc[(size_t)(f >> 7) * Tn + (f & 127)];
            }
        }
        bf16x8 Ah[4], Al[4];
        #pragma unroll
        for (int mt = 0; mt < 4; ++mt) {
            int j = jbase + wm * 64 + mt * 16 + m16;
            size_t base = (size_t)j * Dc + d0 + q * 8;
            Ah[mt] = *(const bf16x8*)(CBh + base);
            Al[mt] = *(const bf16x8*)(CBl + base);
        }
        #pragma unroll
        for (int nt = 0; nt < 4; ++nt) {
            int tt = wn * 64 + nt * 16 + m16;
            union { bf16x8 v; uint2 h[2]; } bh, bl;
            const unsigned short* ph = Xh + tt * 36 + q * 8;
            const unsigned short* pl = Xl + tt * 36 + q * 8;
            bh.h[0] = *(const uint2*)ph; bh.h[1] = *(const uint2*)(ph + 4);
            bl.h[0] = *(const uint2*)pl; bl.h[1] = *(const uint2*)(pl + 4);
            #pragma unroll
            for (int mt = 0; mt < 4; ++mt)
                acc[mt][nt] = __builtin_amdgcn_mfma_f32_16x16x32_bf16(
                    Ah[mt], bh.v, acc[mt][nt], 0, 0, 0);
            #pragma unroll
            for (int mt = 0; mt < 4; ++mt)
                acc[mt][nt] = __builtin_amdgcn_mfma_f32_16x16x32_bf16(
                    Al[mt], bh.v, acc[mt][nt], 0, 0, 0);
            #pragma unroll
            for (int mt = 0; mt < 4; ++mt)
                acc[mt][nt] = __builtin_amdgcn_mfma_f32_16x16x32_bf16(
                    Ah[mt], bl.v, acc[mt][nt], 0, 0, 0);
        }
    }
    __syncthreads();   // all waves done with staging pool; reuse as reduce buf

    float cn4[4][4];
    #pragma unroll
    for (int mt = 0; mt < 4; ++mt) {
        float4 c = *(const float4*)&CN[jbase + wm * 64 + mt * 16 + q * 4];
        cn4[mt][0] = c.x; cn4[mt][1] = c.y; cn4[mt][2] = c.z; cn4[mt][3] = c.w;
    }
    #pragma unroll
    for (int nt = 0; nt < 4; ++nt) {
        int t = wn * 64 + nt * 16 + m16;
        float v1 = 1e30f, v2 = 1e30f;
        int i1 = 0;
        #pragma unroll
        for (int mt = 0; mt < 4; ++mt)
            #pragma unroll
            for (int r = 0; r < 4; ++r) {
                float d = fmaf(-2.f, acc[mt][nt][r], cn4[mt][r]);
                int j = jbase + wm * 64 + mt * 16 + q * 4 + r;
                if (d < v1 || (d == v1 && j < i1)) { v2 = v1; v1 = d; i1 = j; }
                else if (d < v2) v2 = d;
            }
        int slot = wm * 4 + q;
        RV[t * 8 + slot] = v1;
        RI[t * 8 + slot] = i1;
        R2[t * 8 + slot] = v2;
    }
    __syncthreads();
    if (tid < 128) {
        int t = tid;
        float v1 = RV[t * 8], v2 = R2[t * 8];
        int i1 = RI[t * 8];
        #pragma unroll
        for (int s = 1; s < 8; ++s) {
            float a1 = RV[t * 8 + s], a2 = R2[t * 8 + s];
            int ai = RI[t * 8 + s];
            if (a1 < v1 || (a1 == v1 && ai < i1)) {
                v2 = fminf(v1, a2); v1 = a1; i1 = ai;
            } else {
                v2 = fminf(v2, a1);
            }
        }
        int n = b * Tn + t0 + t;
        candv[(size_t)jb * BT + n] = v1;
        candi[(size_t)jb * BT + n] = i1;
        cand2v[(size_t)jb * BT + n] = v2;
    }
}

// ---------------------------------------------------------------------------
// vq_reduce2: merge 8 j-block candidates; flag near-ties for exact rescore.
// grid (BT/256), block 256.
// ---------------------------------------------------------------------------
__global__ __launch_bounds__(256)
void vq_reduce2(const float* __restrict__ candv, const int* __restrict__ candi,
                const float* __restrict__ cand2v, int* __restrict__ idxI,
                float* __restrict__ idxf, int* __restrict__ flagn,
                int* __restrict__ flaglist) {
    int n = blockIdx.x * 256 + threadIdx.x;
    float v1 = candv[n], v2 = cand2v[n];
    int i1 = candi[n];
    #pragma unroll
    for (int jq = 1; jq < 8; ++jq) {
        float a1 = candv[(size_t)jq * BT + n];
        float a2 = cand2v[(size_t)jq * BT + n];
        int ai = candi[(size_t)jq * BT + n];
        if (a1 < v1 || (a1 == v1 && ai < i1)) {
            v2 = fminf(v1, a2); v1 = a1; i1 = ai;
        } else {
            v2 = fminf(v2, a1);
        }
    }
    idxI[n] = i1;
    idxf[n] = (float)i1;
    if (v2 - v1 < MARGIN) {
        int s = atomicAdd(flagn, 1);
        flaglist[s] = n;
    }
}

// ---------------------------------------------------------------------------
// vq_rescue: exact fp32 re-score of flagged positions over all 1024 codes.
// grid (128), block 256; blocks stride over the flag list.
// ---------------------------------------------------------------------------
__global__ __launch_bounds__(256)
void vq_rescue(const int* __restrict__ flagn, const int* __restrict__ flaglist,
               const float* __restrict__ Z, const float* __restrict__ CB,
               const float* __restrict__ CN, int* __restrict__ idxI,
               float* __restrict__ idxf) {
    __shared__ float zs[512];
    __shared__ float rvv[256];
    __shared__ int   rii[256];
    const int nf = *flagn;
    for (int f = blockIdx.x; f < nf; f += gridDim.x) {
        int n = flaglist[f];
        int b = n / Tn, t = n - b * Tn;
        __syncthreads();
        #pragma unroll
        for (int it = 0; it < 2; ++it) {
            int d = threadIdx.x + it * 256;
            zs[d] = Z[((size_t)b * Dc + d) * Tn + t];
        }
        __syncthreads();
        float bv = 1e30f;
        int bi = 0;
        #pragma unroll
        for (int jj = 0; jj < 4; ++jj) {
            int j = threadIdx.x * 4 + jj;
            const float* cr = CB + (size_t)j * Dc;
            float dot = 0.f;
            for (int d = 0; d < Dc; ++d) dot = fmaf(zs[d], cr[d], dot);
            float dist = fmaf(-2.f, dot, CN[j]);
            if (dist < bv || (dist == bv && j < bi)) { bv = dist; bi = j; }
        }
        rvv[threadIdx.x] = bv;
        rii[threadIdx.x] = bi;
        __syncthreads();
        for (int off = 128; off > 0; off >>= 1) {
            if (threadIdx.x < off) {
                float ov = rvv[threadIdx.x + off];
                int oi = rii[threadIdx.x + off];
                if (ov < rvv[threadIdx.x] ||
                    (ov == rvv[threadIdx.x] && oi < rii[threadIdx.x])) {
                    rvv[threadIdx.x] = ov; rii[threadIdx.x] = oi;
                }
            }
            __syncthreads();
        }
        if (threadIdx.x == 0) {
            idxI[n] = rii[0];
            idxf[n] = (float)rii[0];
        }
    }
}

// ---------------------------------------------------------------------------
// conv_dec2p (known-good): X [B,512,T] -> partial recon, K-split over c.
// ---------------------------------------------------------------------------
__global__ __launch_bounds__(256)
void conv_dec2p(const float* __restrict__ X, const float* __restrict__ Wt,
                float* __restrict__ P) {
    const int t0 = blockIdx.x * 64;
    const int half = blockIdx.y;
    const int b  = blockIdx.z;
    __shared__ __align__(16) float Xs[16][72];
    __shared__ __align__(16) float Ws[48][132];
    const int tid = threadIdx.x;
    const int tx = tid & 15, ty = tid >> 4;
    float acc[8][4] = {};
    const float* Xb = X + (size_t)b * Hc * Tn;
    const int cbase = half * 256;

    for (int c0 = cbase; c0 < cbase + 256; c0 += 16) {
        for (int i = tid; i < 16 * 66; i += 256) {
            int cc = i / 66, tt = i % 66;
            int t = t0 + tt - 1;
            float v = 0.f;
            if (t >= 0 && t < Tn) v = Xb[(size_t)(c0 + cc) * Tn + t];
            Xs[cc][tt] = v;
        }
        for (int i = tid; i < 48 * 128; i += 256) {
            int o = i & 127, ck = i >> 7;
            Ws[ck][o] = (o < INC) ? Wt[(size_t)(c0 * 3 + ck) * INC + o] : 0.f;
        }
        __syncthreads();
        #pragma unroll
        for (int cc = 0; cc < 16; ++cc) {
            float4 xa = *(const float4*)&Xs[cc][tx * 4];
            float2 xb2 = *(const float2*)&Xs[cc][tx * 4 + 4];
            float xv[6] = {xa.x, xa.y, xa.z, xa.w, xb2.x, xb2.y};
            #pragma unroll
            for (int k = 0; k < 3; ++k) {
                float4 wa = *(const float4*)&Ws[cc * 3 + k][ty * 4];
                float4 wb = *(const float4*)&Ws[cc * 3 + k][64 + ty * 4];
                float wv[8] = {wa.x, wa.y, wa.z, wa.w, wb.x, wb.y, wb.z, wb.w};
                #pragma unroll
                for (int i8 = 0; i8 < 8; ++i8)
                    #pragma unroll
                    for (int j = 0; j < 4; ++j)
                        acc[i8][j] = fmaf(wv[i8], xv[k + j], acc[i8][j]);
            }
        }
        __syncthreads();
    }
    float* Ph = P + (size_t)half * RECON_N;
    {
        #pragma unroll
        for (int j = 0; j < 4; ++j) {
            int t = t0 + tx * 4 + j;
            float4 s;
            s.x = acc[0][j]; s.y = acc[1][j]; s.z = acc[2][j]; s.w = acc[3][j];
            *(float4*)(Ph + ((size_t)b * Tn + t) * INC + ty * 4) = s;
        }
    }
    if (ty < 4) {
        #pragma unroll
        for (int j = 0; j < 4; ++j) {
            int t = t0 + tx * 4 + j;
            float4 s;
            s.x = acc[4][j]; s.y = acc[5][j]; s.z = acc[6][j]; s.w = acc[7][j];
            *(float4*)(Ph + ((size_t)b * Tn + t) * INC + 64 + ty * 4) = s;
        }
    }
}

// ---------------------------------------------------------------------------
// dec_combine: recon = P0 + P1 + bias. grid (RECON_N/1024), block 256, f4.
// ---------------------------------------------------------------------------
__global__ __launch_bounds__(256)
void dec_combine(const float* __restrict__ P, const float* __restrict__ bias,
                 float* __restrict__ OUT) {
    int i4 = blockIdx.x * 256 + threadIdx.x;
    float4 a = ((const float4*)P)[i4];
    float4 b = ((const float4*)(P + RECON_N))[i4];
    int o = (i4 * 4) % INC;
    float4 r;
    r.x = a.x + b.x + bias[o];
    r.y = a.y + b.y + bias[o + 1];
    r.z = a.z + b.z + bias[o + 2];
    r.w = a.w + b.w + bias[o + 3];
    ((float4*)OUT)[i4] = r;
}

// ---------------------------------------------------------------------------
// gemm_g: G[j][kk*512+o] = sum_c CB[j][c] * dec_w1[o][c][kk].
// ---------------------------------------------------------------------------
__global__ __launch_bounds__(256)
void gemm_g(const float* __restrict__ CBt, const float* __restrict__ Wt,
            float* __restrict__ G) {
    const int j0 = blockIdx.x * 64;
    const int kk = blockIdx.y >> 2;
    const int o0 = (blockIdx.y & 3) * 128;
    __shared__ __align__(16) float As[16][68];
    __shared__ __align__(16) float Bs[16][132];
    const int tid = threadIdx.x;
    const int tx = tid & 15, ty = tid >> 4;
    float acc[4][8] = {};

    for (int c0 = 0; c0 < Dc; c0 += 16) {
        {
            int cc = tid >> 4, j4 = tid & 15;
            *(float4*)&As[cc][j4 * 4] =
                *(const float4*)&CBt[(size_t)(c0 + cc) * NCODE + j0 + j4 * 4];
        }
        #pragma unroll
        for (int it = 0; it < 2; ++it) {
            int i = tid + it * 256;
            int cc = i >> 5, o4 = i & 31;
            *(float4*)&Bs[cc][o4 * 4] =
                *(const float4*)&Wt[(size_t)((c0 + cc) * 3 + kk) * Hc + o0 + o4 * 4];
        }
        __syncthreads();
        #pragma unroll
        for (int cc = 0; cc < 16; ++cc) {
            float4 a = *(const float4*)&As[cc][tx * 4];
            float av[4] = {a.x, a.y, a.z, a.w};
            float4 b0 = *(const float4*)&Bs[cc][ty * 4];
            float4 b1 = *(const float4*)&Bs[cc][64 + ty * 4];
            float bv[8] = {b0.x, b0.y, b0.z, b0.w, b1.x, b1.y, b1.z, b1.w};
            #pragma unroll
            for (int jj = 0; jj < 4; ++jj)
                #pragma unroll
                for (int oo = 0; oo < 8; ++oo)
                    acc[jj][oo] = fmaf(av[jj], bv[oo], acc[jj][oo]);
        }
        __syncthreads();
    }
    #pragma unroll
    for (int jj = 0; jj < 4; ++jj) {
        int j = j0 + tx * 4 + jj;
        float* gp = G + (size_t)j * 1536 + kk * 512 + o0;
        *(float4*)(gp + ty * 4) = *(float4*)&acc[jj][0];
        *(float4*)(gp + 64 + ty * 4) = *(float4*)&acc[jj][4];
    }
}

// ---------------------------------------------------------------------------
// dec_y3: y3[b][o][t] = relu(b1[o] + sum_kk G[idx[b][t+kk-1]][kk*512+o]).
// ---------------------------------------------------------------------------
__global__ __launch_bounds__(256)
void dec_y3(const int* __restrict__ idx, const float* __restrict__ G,
            const float* __restrict__ bias, float* __restrict__ Y) {
    const int t0 = blockIdx.x * 64;
    const int o0 = blockIdx.y * 128;
    const int b  = blockIdx.z;
    const int tid = threadIdx.x;
    __shared__ int sidx[66];
    __shared__ __align__(16) float Ys[128][68];

    if (tid < 66) {
        int t = t0 + tid - 1;
        sidx[tid] = (t >= 0 && t < Tn) ? idx[b * Tn + t] : -1;
    }
    __syncthreads();

    const int o = tid & 127;
    const int half = tid >> 7;
    float acc[32] = {};
    #pragma unroll
    for (int kk = 0; kk < 3; ++kk) {
        const float* Gk = G + (size_t)kk * 512 + o0 + o;
        #pragma unroll
        for (int k = 0; k < 32; ++k) {
            int j = sidx[half + 2 * k + kk];
            if (j >= 0) acc[k] += Gk[(size_t)j * 1536];
        }
    }
    float bv = bias[o0 + o];
    #pragma unroll
    for (int k = 0; k < 32; ++k)
        Ys[o][half + 2 * k] = fmaxf(acc[k] + bv, 0.f);
    __syncthreads();

    float* Yb = Y + (size_t)b * Hc * Tn + t0;
    #pragma unroll
    for (int it = 0; it < 8; ++it) {
        int i = tid + it * 256;
        int t4 = i & 15, oo = i >> 4;
        *(float4*)&Yb[(size_t)(o0 + oo) * Tn + t4 * 4] =
            *(const float4*)&Ys[oo][t4 * 4];
    }
}

// ---------------------------------------------------------------------------
extern "C" void kernel_launch(void* const* d_in, const int* in_sizes, int n_in,
                              void* d_out, int out_size, void* d_ws, size_t ws_size,
                              hipStream_t stream) {
    const float* mels    = (const float*)d_in[0];
    const float* enc_w1  = (const float*)d_in[1];
    const float* enc_b1  = (const float*)d_in[2];
    const float* enc_w2  = (const float*)d_in[3];
    const float* enc_b2  = (const float*)d_in[4];
    const float* codebook= (const float*)d_in[5];
    const float* dec_w1  = (const float*)d_in[6];
    const float* dec_b1  = (const float*)d_in[7];
    const float* dec_w2  = (const float*)d_in[8];
    const float* dec_b2  = (const float*)d_in[9];

    float* out = (float*)d_out;
    float* recon = out;                 // [B,T,80]
    float* idxf  = out + RECON_N;       // [B,T] as float

    const size_t ACT = (size_t)Bsz * Hc * Tn;   // 16,777,216 floats (64 MB)
    float* bufA  = (float*)d_ws;                // y1, later y3
    float* bufB  = bufA + ACT;                  // melsT, then z, then dec partials
    int*   idxI  = (int*)(bufB + ACT);          // [BT]
    float* cn    = (float*)(idxI + BT);         // [NCODE]
    float* cbt   = cn + NCODE;                  // [Dc*NCODE]  (gemm_g)
    float* wt1   = cbt + (size_t)Dc * NCODE;    // enc_w1t: 80*3*512
    float* wt3   = wt1 + (size_t)INC * 3 * Hc;  // dec_w1t: 512*3*512
    float* wt4   = wt3 + (size_t)Dc * 3 * Hc;   // dec_w2t: 512*3*80
    float* candv = wt4 + (size_t)Hc * 3 * INC;  // [8*BT]
    float* cand2v= candv + (size_t)8 * BT;      // [8*BT]
    int*   candi = (int*)(cand2v + (size_t)8 * BT); // [8*BT]
    int*   flagn = candi + (size_t)8 * BT;      // [4] (padded for alignment)
    int*   flaglist = flagn + 4;                // [BT]
    float* G     = (float*)(flaglist + BT);     // [NCODE*1536]
    unsigned short* whi = (unsigned short*)(G + (size_t)NCODE * 1536); // [3*Hc*Dc]
    unsigned short* wlo = whi + (size_t)3 * Hc * Dc;                   // [3*Hc*Dc]
    unsigned short* cbh = wlo + (size_t)3 * Hc * Dc;                   // [NCODE*Dc]
    unsigned short* cbl = cbh + (size_t)NCODE * Dc;                    // [NCODE*Dc]
    float* melsT = bufB;                        // [B,80,T] (dead after enc1)
    float* Pdec  = bufB;                        // 2 partials (z dead by then)

    dim3 blk(256);
    hipMemsetAsync(flagn, 0, 16, stream);
    // prep: norms + transposes + bf16 splits (cheap, graph-capture safe)
    code_norms<<<dim3(NCODE), dim3(64), 0, stream>>>(codebook, cn);
    cb_transpose<<<dim3(NCODE / 64, Dc / 64), blk, 0, stream>>>(codebook, cbt);
    mels_transpose<<<dim3(Tn / 64, Bsz), blk, 0, stream>>>(mels, melsT);
    wt_transpose<<<dim3(Hc / 64, INC / 16), blk, 0, stream>>>(enc_w1, wt1, INC, Hc);
    wsplit<<<dim3(Hc, 3), blk, 0, stream>>>(enc_w2, whi, wlo);
    cbsplit<<<dim3(NCODE), blk, 0, stream>>>(codebook, cbh, cbl);
    wt_transpose<<<dim3(Hc / 64, Dc / 16), blk, 0, stream>>>(dec_w1, wt3, Dc, Hc);
    wt_transpose<<<dim3(2, Hc / 16), blk, 0, stream>>>(dec_w2, wt4, Hc, INC);
    // decoder conv1 folded matrix (independent of activations)
    gemm_g<<<dim3(NCODE / 64, 12), blk, 0, stream>>>(cbt, wt3, G);
    // encoder
    conv_enc1<<<dim3(Tn / 64, Hc / 128, Bsz), blk, 0, stream>>>(melsT, wt1, enc_b1, bufA);
    conv_mid_mfma<<<dim3(Tn / 128, Hc / 128, Bsz), blk, 0, stream>>>(bufA, whi, wlo, enc_b2, bufB);
    // vector quantization: MFMA approx + margin-guarded exact rescue
    vq_mfma<<<dim3(BT / 128, NCODE / 128), blk, 0, stream>>>(bufB, cbh, cbl, cn,
                                                             candv, candi, cand2v);
    vq_reduce2<<<dim3(BT / 256), blk, 0, stream>>>(candv, candi, cand2v, idxI,
                                                   idxf, flagn, flaglist);
    vq_rescue<<<dim3(128), blk, 0, stream>>>(flagn, flaglist, bufB, codebook, cn,
                                             idxI, idxf);
    // decoder: conv1 via gather of G rows, then conv2 (K-split) + combine
    dec_y3<<<dim3(Tn / 64, 4, Bsz), blk, 0, stream>>>(idxI, G, dec_b1, bufA);
    conv_dec2p<<<dim3(Tn / 64, 2, Bsz), blk, 0, stream>>>(bufA, wt4, Pdec);
    dec_combine<<<dim3(RECON_N / 1024), blk, 0, stream>>>(Pdec, dec_b2, recon);
}

// Round 12
// 896.416 us; speedup vs baseline: 3.5870x; 1.1629x over previous
//
#include <hip/hip_runtime.h>
#include <hip/hip_bf16.h>

// Problem constants
#define Bsz   16
#define Tn    2048
#define INC   80
#define Hc    512
#define Dc    512
#define NCODE 1024
#define BT    (Bsz * Tn)           // 32768
#define RECON_N (Bsz * Tn * INC)   // 2,621,440
#define MARGIN 0.03f               // approx-distance safety margin (>>40 sigma of bf16x3 err)

typedef __attribute__((ext_vector_type(8))) short bf16x8;
typedef __attribute__((ext_vector_type(4))) float f32x4;

// float -> bf16 (round-to-nearest-even), and back
static __device__ __forceinline__ unsigned short f2bf(float x) {
    unsigned u = __float_as_uint(x);
    u += 0x7FFF + ((u >> 16) & 1);
    return (unsigned short)(u >> 16);
}
static __device__ __forceinline__ float bf2f(unsigned short h) {
    return __uint_as_float((unsigned)h << 16);
}

// ---------------------------------------------------------------------------
// code_norms: CN[j] = sum_d CB[j][d]^2
// ---------------------------------------------------------------------------
__global__ __launch_bounds__(64)
void code_norms(const float* __restrict__ CB, float* __restrict__ CN) {
    int j = blockIdx.x;
    int lane = threadIdx.x;
    const float4* row = (const float4*)(CB + (size_t)j * Dc);
    float s = 0.f;
    #pragma unroll
    for (int i = 0; i < 2; ++i) {
        float4 v = row[lane + i * 64];
        s = fmaf(v.x, v.x, s);
        s = fmaf(v.y, v.y, s);
        s = fmaf(v.z, v.z, s);
        s = fmaf(v.w, v.w, s);
    }
    #pragma unroll
    for (int off = 32; off > 0; off >>= 1) s += __shfl_down(s, off, 64);
    if (lane == 0) CN[j] = s;
}

// ---------------------------------------------------------------------------
// cb_transpose: CBt[d][j] = CB[j][d].  grid (NCODE/64, Dc/64), block 256
// ---------------------------------------------------------------------------
__global__ __launch_bounds__(256)
void cb_transpose(const float* __restrict__ CB, float* __restrict__ CBt) {
    const int j0 = blockIdx.x * 64;
    const int d0 = blockIdx.y * 64;
    __shared__ float ts[64][65];
    const int tid = threadIdx.x;
    for (int i = tid; i < 4096; i += 256) {
        int r = i >> 6, c = i & 63;
        ts[r][c] = CB[(size_t)(j0 + r) * Dc + d0 + c];
    }
    __syncthreads();
    for (int i = tid; i < 4096; i += 256) {
        int r = i >> 6, c = i & 63;
        CBt[(size_t)(d0 + r) * NCODE + j0 + c] = ts[c][r];
    }
}

// ---------------------------------------------------------------------------
// mels_transpose: MT[b][c][t] = M[b][t][c].  grid (Tn/64, Bsz), block 256
// ---------------------------------------------------------------------------
__global__ __launch_bounds__(256)
void mels_transpose(const float* __restrict__ M, float* __restrict__ MT) {
    const int t0 = blockIdx.x * 64;
    const int b  = blockIdx.y;
    __shared__ float ts[64][84];
    const int tid = threadIdx.x;
    #pragma unroll
    for (int it = 0; it < 5; ++it) {
        int i = tid + it * 256;            // < 1280
        int t = i / 20, c4 = i % 20;
        *(float4*)&ts[t][c4 * 4] =
            *(const float4*)&M[((size_t)b * Tn + t0 + t) * INC + c4 * 4];
    }
    __syncthreads();
    #pragma unroll
    for (int it = 0; it < 20; ++it) {
        int i = tid + it * 256;            // < 5120
        int c = i >> 6, t = i & 63;
        MT[((size_t)b * INC + c) * Tn + t0 + t] = ts[t][c];
    }
}

// ---------------------------------------------------------------------------
// wt_transpose: Wt[(c*3+k)*Cout + o] = W[(o*Cin + c)*3 + k]
// ---------------------------------------------------------------------------
__global__ __launch_bounds__(256)
void wt_transpose(const float* __restrict__ W, float* __restrict__ Wt,
                  int Cin, int Cout) {
    const int o0 = blockIdx.x * 64;
    const int c0 = blockIdx.y * 16;
    __shared__ float ts[48][65];
    const int tid = threadIdx.x;
    for (int i = tid; i < 64 * 48; i += 256) {
        int o = i / 48, ck = i % 48;
        int oo = o0 + o;
        float v = 0.f;
        if (oo < Cout) v = W[(size_t)oo * Cin * 3 + c0 * 3 + ck];
        ts[ck][o] = v;
    }
    __syncthreads();
    for (int i = tid; i < 48 * 64; i += 256) {
        int o = i & 63, ck = i >> 6;
        int oo = o0 + o;
        if (oo < Cout) Wt[(size_t)(c0 * 3 + ck) * Cout + oo] = ts[ck][o];
    }
}

// ---------------------------------------------------------------------------
// wsplit: enc_w2 [o][c][k] fp32 -> Whi/Wlo [k][o][c] bf16 (hi + residual-lo).
// ---------------------------------------------------------------------------
__global__ __launch_bounds__(256)
void wsplit(const float* __restrict__ W, unsigned short* __restrict__ Whi,
            unsigned short* __restrict__ Wlo) {
    int o = blockIdx.x, k = blockIdx.y;
    #pragma unroll
    for (int it = 0; it < 2; ++it) {
        int c = threadIdx.x + it * 256;
        float v = W[((size_t)o * Hc + c) * 3 + k];
        unsigned short h = f2bf(v);
        Whi[((size_t)k * Hc + o) * Hc + c] = h;
        Wlo[((size_t)k * Hc + o) * Hc + c] = f2bf(v - bf2f(h));
    }
}

// ---------------------------------------------------------------------------
// wsplit80: dec_w2 [o][c][k] fp32 -> Wh2 [k][o][c] bf16 (hi only; recon
// tolerance 20.48 >> single-bf16 error ~1e-2). grid (INC, 3), block 256.
// ---------------------------------------------------------------------------
__global__ __launch_bounds__(256)
void wsplit80(const float* __restrict__ W, unsigned short* __restrict__ Wh) {
    int o = blockIdx.x, k = blockIdx.y;
    #pragma unroll
    for (int it = 0; it < 2; ++it) {
        int c = threadIdx.x + it * 256;
        Wh[((size_t)k * INC + o) * Hc + c] = f2bf(W[((size_t)o * Hc + c) * 3 + k]);
    }
}

// ---------------------------------------------------------------------------
// cbsplit: codebook [j][d] fp32 -> CBh/CBl [j][d] bf16. grid (NCODE), blk 256
// ---------------------------------------------------------------------------
__global__ __launch_bounds__(256)
void cbsplit(const float* __restrict__ CB, unsigned short* __restrict__ CBh,
             unsigned short* __restrict__ CBl) {
    int j = blockIdx.x;
    #pragma unroll
    for (int it = 0; it < 2; ++it) {
        int d = threadIdx.x + it * 256;
        float v = CB[(size_t)j * Dc + d];
        unsigned short h = f2bf(v);
        CBh[(size_t)j * Dc + d] = h;
        CBl[(size_t)j * Dc + d] = f2bf(v - bf2f(h));
    }
}

// ---------------------------------------------------------------------------
// conv_enc1 (known-good): melsT [B,80,T] -> Y [B,512,T], K=3, ReLU.
// ---------------------------------------------------------------------------
__global__ __launch_bounds__(256)
void conv_enc1(const float* __restrict__ X, const float* __restrict__ Wt,
               const float* __restrict__ bias, float* __restrict__ Y) {
    const int t0 = blockIdx.x * 64;
    const int o0 = blockIdx.y * 128;
    const int b  = blockIdx.z;
    __shared__ __align__(16) float Xs[16][72];
    __shared__ __align__(16) float Ws[48][132];
    const int tid = threadIdx.x;
    const int tx = tid & 15, ty = tid >> 4;
    float acc[8][4] = {};
    const float* Xb = X + (size_t)b * INC * Tn;

    for (int c0 = 0; c0 < INC; c0 += 16) {
        for (int i = tid; i < 16 * 66; i += 256) {
            int cc = i / 66, tt = i % 66;
            int t = t0 + tt - 1;
            float v = 0.f;
            if (t >= 0 && t < Tn) v = Xb[(size_t)(c0 + cc) * Tn + t];
            Xs[cc][tt] = v;
        }
        for (int i = tid; i < 48 * 128; i += 256) {
            int o = i & 127, ck = i >> 7;
            Ws[ck][o] = Wt[(size_t)(c0 * 3 + ck) * Hc + o0 + o];
        }
        __syncthreads();
        #pragma unroll
        for (int cc = 0; cc < 16; ++cc) {
            float4 xa = *(const float4*)&Xs[cc][tx * 4];
            float2 xb2 = *(const float2*)&Xs[cc][tx * 4 + 4];
            float xv[6] = {xa.x, xa.y, xa.z, xa.w, xb2.x, xb2.y};
            #pragma unroll
            for (int k = 0; k < 3; ++k) {
                float4 wa = *(const float4*)&Ws[cc * 3 + k][ty * 4];
                float4 wb = *(const float4*)&Ws[cc * 3 + k][64 + ty * 4];
                float wv[8] = {wa.x, wa.y, wa.z, wa.w, wb.x, wb.y, wb.z, wb.w};
                #pragma unroll
                for (int i8 = 0; i8 < 8; ++i8)
                    #pragma unroll
                    for (int j = 0; j < 4; ++j)
                        acc[i8][j] = fmaf(wv[i8], xv[k + j], acc[i8][j]);
            }
        }
        __syncthreads();
    }
    float* Yb = Y + (size_t)b * Hc * Tn;
    #pragma unroll
    for (int og = 0; og < 2; ++og)
        #pragma unroll
        for (int oi = 0; oi < 4; ++oi) {
            int o = o0 + og * 64 + ty * 4 + oi;
            float bv = bias[o];
            const int i8 = og * 4 + oi;
            float4 r;
            r.x = fmaxf(acc[i8][0] + bv, 0.f);
            r.y = fmaxf(acc[i8][1] + bv, 0.f);
            r.z = fmaxf(acc[i8][2] + bv, 0.f);
            r.w = fmaxf(acc[i8][3] + bv, 0.f);
            *(float4*)&Yb[(size_t)o * Tn + t0 + tx * 4] = r;
        }
}

// ---------------------------------------------------------------------------
// conv_mid_mfma (r10 known-good): 3xbf16 emulated implicit GEMM, one-barrier
// pipelined double-buffered LDS.
// ---------------------------------------------------------------------------
__global__ __launch_bounds__(256)
void conv_mid_mfma(const float* __restrict__ X,
                   const unsigned short* __restrict__ Whi,
                   const unsigned short* __restrict__ Wlo,
                   const float* __restrict__ bias, float* __restrict__ Y) {
    const int t0 = blockIdx.x * 128;
    const int o0 = blockIdx.y * 128;
    const int b  = blockIdx.z;
    __shared__ unsigned short XhL[2][130 * 36];
    __shared__ unsigned short XlL[2][130 * 36];
    const int tid = threadIdx.x;
    const int lane = tid & 63;
    const int wave = tid >> 6;
    const int wm = wave >> 1, wn = wave & 1;
    const int m16 = lane & 15;
    const int q = lane >> 4;
    const float* Xb = X + (size_t)b * Hc * Tn;

    f32x4 acc[4][4];
    #pragma unroll
    for (int mt = 0; mt < 4; ++mt)
        #pragma unroll
        for (int nt = 0; nt < 4; ++nt)
            acc[mt][nt] = (f32x4){0.f, 0.f, 0.f, 0.f};

    float xr[17];
    #pragma unroll
    for (int it = 0; it < 17; ++it) {
        int f = tid + it * 256;
        if (it < 16 || tid < 64) {
            int cc = f / 130, tt = f - cc * 130;
            int t = t0 + tt - 1;
            xr[it] = (t >= 0 && t < Tn) ? Xb[(size_t)cc * Tn + t] : 0.f;
        }
    }

    for (int c0 = 0; c0 < Hc; c0 += 32) {
        const int buf = (c0 >> 5) & 1;
        #pragma unroll
        for (int it = 0; it < 17; ++it) {
            int f = tid + it * 256;
            if (it < 16 || tid < 64) {
                int cc = f / 130, tt = f - cc * 130;
                float v = xr[it];
                unsigned short h = f2bf(v);
                XhL[buf][tt * 36 + cc] = h;
                XlL[buf][tt * 36 + cc] = f2bf(v - bf2f(h));
            }
        }
        __syncthreads();
        if (c0 + 32 < Hc) {
            const float* Xc = Xb + (size_t)(c0 + 32) * Tn;
            #pragma unroll
            for (int it = 0; it < 17; ++it) {
                int f = tid + it * 256;
                if (it < 16 || tid < 64) {
                    int cc = f / 130, tt = f - cc * 130;
                    int t = t0 + tt - 1;
                    xr[it] = (t >= 0 && t < Tn) ? Xc[(size_t)cc * Tn + t] : 0.f;
                }
            }
        }
        #pragma unroll
        for (int k = 0; k < 3; ++k) {
            bf16x8 Ah[4], Al[4];
            #pragma unroll
            for (int mt = 0; mt < 4; ++mt) {
                int o = o0 + wm * 64 + mt * 16 + m16;
                size_t base = (size_t)(k * Hc + o) * Hc + c0 + q * 8;
                Ah[mt] = *(const bf16x8*)(Whi + base);
                Al[mt] = *(const bf16x8*)(Wlo + base);
            }
            #pragma unroll
            for (int nt = 0; nt < 4; ++nt) {
                int tt = wn * 64 + nt * 16 + m16 + k;
                union { bf16x8 v; uint2 h[2]; } bh, bl;
                const unsigned short* ph = XhL[buf] + tt * 36 + q * 8;
                const unsigned short* pl = XlL[buf] + tt * 36 + q * 8;
                bh.h[0] = *(const uint2*)ph; bh.h[1] = *(const uint2*)(ph + 4);
                bl.h[0] = *(const uint2*)pl; bl.h[1] = *(const uint2*)(pl + 4);
                #pragma unroll
                for (int mt = 0; mt < 4; ++mt)
                    acc[mt][nt] = __builtin_amdgcn_mfma_f32_16x16x32_bf16(
                        Ah[mt], bh.v, acc[mt][nt], 0, 0, 0);
                #pragma unroll
                for (int mt = 0; mt < 4; ++mt)
                    acc[mt][nt] = __builtin_amdgcn_mfma_f32_16x16x32_bf16(
                        Al[mt], bh.v, acc[mt][nt], 0, 0, 0);
                #pragma unroll
                for (int mt = 0; mt < 4; ++mt)
                    acc[mt][nt] = __builtin_amdgcn_mfma_f32_16x16x32_bf16(
                        Ah[mt], bl.v, acc[mt][nt], 0, 0, 0);
            }
        }
    }
    float* Yb = Y + (size_t)b * Hc * Tn;
    #pragma unroll
    for (int mt = 0; mt < 4; ++mt) {
        int ob = o0 + wm * 64 + mt * 16 + q * 4;
        float4 bq = *(const float4*)&bias[ob];
        float bqa[4] = {bq.x, bq.y, bq.z, bq.w};
        #pragma unroll
        for (int nt = 0; nt < 4; ++nt) {
            int t = t0 + wn * 64 + nt * 16 + m16;
            #pragma unroll
            for (int r = 0; r < 4; ++r)
                Yb[(size_t)(ob + r) * Tn + t] = acc[mt][nt][r] + bqa[r];
        }
    }
}

// ---------------------------------------------------------------------------
// dec2_mfma: recon = conv(y3, dec_w2) + b, single-bf16 implicit GEMM.
// M=80 o (5 mt tiles), K=1536 (512 c x 3 taps), N=128 t per block.
// 4 waves = 4 t-quadrants of 32 (2 nt each). acc 5x2 f32x4 = 40 VGPR.
// Same pipelined staging as conv_mid (hi only). Writes [B,T,80] + bias.
// grid (Tn/128, 1, B) = 256 blocks, block 256.
// ---------------------------------------------------------------------------
__global__ __launch_bounds__(256)
void dec2_mfma(const float* __restrict__ X,
               const unsigned short* __restrict__ Wh2,
               const float* __restrict__ bias, float* __restrict__ OUT) {
    const int t0 = blockIdx.x * 128;
    const int b  = blockIdx.z;
    __shared__ unsigned short Xs[2][130 * 36];
    const int tid = threadIdx.x;
    const int lane = tid & 63;
    const int wn = tid >> 6;           // wave = t-quadrant (32 t each)
    const int m16 = lane & 15;
    const int q = lane >> 4;
    const float* Xb = X + (size_t)b * Hc * Tn;

    f32x4 acc[5][2];
    #pragma unroll
    for (int mt = 0; mt < 5; ++mt)
        #pragma unroll
        for (int nt = 0; nt < 2; ++nt)
            acc[mt][nt] = (f32x4){0.f, 0.f, 0.f, 0.f};

    float xr[17];
    #pragma unroll
    for (int it = 0; it < 17; ++it) {
        int f = tid + it * 256;
        if (it < 16 || tid < 64) {
            int cc = f / 130, tt = f - cc * 130;
            int t = t0 + tt - 1;
            xr[it] = (t >= 0 && t < Tn) ? Xb[(size_t)cc * Tn + t] : 0.f;
        }
    }

    for (int c0 = 0; c0 < Hc; c0 += 32) {
        const int buf = (c0 >> 5) & 1;
        #pragma unroll
        for (int it = 0; it < 17; ++it) {
            int f = tid + it * 256;
            if (it < 16 || tid < 64) {
                int cc = f / 130, tt = f - cc * 130;
                Xs[buf][tt * 36 + cc] = f2bf(xr[it]);
            }
        }
        __syncthreads();
        if (c0 + 32 < Hc) {
            const float* Xc = Xb + (size_t)(c0 + 32) * Tn;
            #pragma unroll
            for (int it = 0; it < 17; ++it) {
                int f = tid + it * 256;
                if (it < 16 || tid < 64) {
                    int cc = f / 130, tt = f - cc * 130;
                    int t = t0 + tt - 1;
                    xr[it] = (t >= 0 && t < Tn) ? Xc[(size_t)cc * Tn + t] : 0.f;
                }
            }
        }
        #pragma unroll
        for (int k = 0; k < 3; ++k) {
            bf16x8 Ah[5];
            #pragma unroll
            for (int mt = 0; mt < 5; ++mt) {
                int o = mt * 16 + m16;
                Ah[mt] = *(const bf16x8*)(Wh2 + ((size_t)(k * INC + o)) * Hc + c0 + q * 8);
            }
            #pragma unroll
            for (int nt = 0; nt < 2; ++nt) {
                int tt = wn * 32 + nt * 16 + m16 + k;
                union { bf16x8 v; uint2 h[2]; } bh;
                const unsigned short* ph = Xs[buf] + tt * 36 + q * 8;
                bh.h[0] = *(const uint2*)ph; bh.h[1] = *(const uint2*)(ph + 4);
                #pragma unroll
                for (int mt = 0; mt < 5; ++mt)
                    acc[mt][nt] = __builtin_amdgcn_mfma_f32_16x16x32_bf16(
                        Ah[mt], bh.v, acc[mt][nt], 0, 0, 0);
            }
        }
    }
    #pragma unroll
    for (int mt = 0; mt < 5; ++mt) {
        float4 bq = *(const float4*)&bias[mt * 16 + q * 4];
        #pragma unroll
        for (int nt = 0; nt < 2; ++nt) {
            int t = t0 + wn * 32 + nt * 16 + m16;
            float4 r;
            r.x = acc[mt][nt][0] + bq.x;
            r.y = acc[mt][nt][1] + bq.y;
            r.z = acc[mt][nt][2] + bq.z;
            r.w = acc[mt][nt][3] + bq.w;
            *(float4*)(OUT + ((size_t)b * Tn + t) * INC + mt * 16 + q * 4) = r;
        }
    }
}

// ---------------------------------------------------------------------------
// vq_mfma (r11 known-good): approx distances via 3xbf16 MFMA GEMM.
// grid (BT/128, NCODE/128), block 256.
// ---------------------------------------------------------------------------
__global__ __launch_bounds__(256)
void vq_mfma(const float* __restrict__ Z,
             const unsigned short* __restrict__ CBh,
             const unsigned short* __restrict__ CBl,
             const float* __restrict__ CN,
             float* __restrict__ candv, int* __restrict__ candi,
             float* __restrict__ cand2v) {
    const int nb = blockIdx.x;
    const int jb = blockIdx.y;
    const int b  = nb >> 4;
    const int t0 = (nb & 15) * 128;
    const int jbase = jb * 128;
    __shared__ __align__(16) unsigned char pool[4 * 128 * 36 * 2]; // 36864 B
    unsigned short* XhP = (unsigned short*)pool;
    unsigned short* XlP = XhP + 2 * 128 * 36;
    float* RV = (float*)pool;
    int*   RI = (int*)(pool + 128 * 8 * 4);
    float* R2 = (float*)(pool + 2 * 128 * 8 * 4);

    const int tid = threadIdx.x;
    const int lane = tid & 63;
    const int wave = tid >> 6;
    const int wm = wave >> 1, wn = wave & 1;
    const int m16 = lane & 15;
    const int q = lane >> 4;
    const float* Zb = Z + (size_t)b * Dc * Tn + t0;

    f32x4 acc[4][4];
    #pragma unroll
    for (int mt = 0; mt < 4; ++mt)
        #pragma unroll
        for (int nt = 0; nt < 4; ++nt)
            acc[mt][nt] = (f32x4){0.f, 0.f, 0.f, 0.f};

    float xr[16];
    #pragma unroll
    for (int it = 0; it < 16; ++it) {
        int f = tid + it * 256;
        xr[it] = Zb[(size_t)(f >> 7) * Tn + (f & 127)];
    }

    for (int d0 = 0; d0 < Dc; d0 += 32) {
        const int buf = (d0 >> 5) & 1;
        unsigned short* Xh = XhP + buf * (128 * 36);
        unsigned short* Xl = XlP + buf * (128 * 36);
        #pragma unroll
        for (int it = 0; it < 16; ++it) {
            int f = tid + it * 256;
            int dd = f >> 7, tt = f & 127;
            float v = xr[it];
            unsigned short h = f2bf(v);
            Xh[tt * 36 + dd] = h;
            Xl[tt * 36 + dd] = f2bf(v - bf2f(h));
        }
        __syncthreads();
        if (d0 + 32 < Dc) {
            const float* Zc = Zb + (size_t)(d0 + 32) * Tn;
            #pragma unroll
            for (int it = 0; it < 16; ++it) {
                int f = tid + it * 256;
                xr[it] = Zc[(size_t)(f >> 7) * Tn + (f & 127)];
            }
        }
        bf16x8 Ah[4], Al[4];
        #pragma unroll
        for (int mt = 0; mt < 4; ++mt) {
            int j = jbase + wm * 64 + mt * 16 + m16;
            size_t base = (size_t)j * Dc + d0 + q * 8;
            Ah[mt] = *(const bf16x8*)(CBh + base);
            Al[mt] = *(const bf16x8*)(CBl + base);
        }
        #pragma unroll
        for (int nt = 0; nt < 4; ++nt) {
            int tt = wn * 64 + nt * 16 + m16;
            union { bf16x8 v; uint2 h[2]; } bh, bl;
            const unsigned short* ph = Xh + tt * 36 + q * 8;
            const unsigned short* pl = Xl + tt * 36 + q * 8;
            bh.h[0] = *(const uint2*)ph; bh.h[1] = *(const uint2*)(ph + 4);
            bl.h[0] = *(const uint2*)pl; bl.h[1] = *(const uint2*)(pl + 4);
            #pragma unroll
            for (int mt = 0; mt < 4; ++mt)
                acc[mt][nt] = __builtin_amdgcn_mfma_f32_16x16x32_bf16(
                    Ah[mt], bh.v, acc[mt][nt], 0, 0, 0);
            #pragma unroll
            for (int mt = 0; mt < 4; ++mt)
                acc[mt][nt] = __builtin_amdgcn_mfma_f32_16x16x32_bf16(
                    Al[mt], bh.v, acc[mt][nt], 0, 0, 0);
            #pragma unroll
            for (int mt = 0; mt < 4; ++mt)
                acc[mt][nt] = __builtin_amdgcn_mfma_f32_16x16x32_bf16(
                    Ah[mt], bl.v, acc[mt][nt], 0, 0, 0);
        }
    }
    __syncthreads();

    float cn4[4][4];
    #pragma unroll
    for (int mt = 0; mt < 4; ++mt) {
        float4 c = *(const float4*)&CN[jbase + wm * 64 + mt * 16 + q * 4];
        cn4[mt][0] = c.x; cn4[mt][1] = c.y; cn4[mt][2] = c.z; cn4[mt][3] = c.w;
    }
    #pragma unroll
    for (int nt = 0; nt < 4; ++nt) {
        int t = wn * 64 + nt * 16 + m16;
        float v1 = 1e30f, v2 = 1e30f;
        int i1 = 0;
        #pragma unroll
        for (int mt = 0; mt < 4; ++mt)
            #pragma unroll
            for (int r = 0; r < 4; ++r) {
                float d = fmaf(-2.f, acc[mt][nt][r], cn4[mt][r]);
                int j = jbase + wm * 64 + mt * 16 + q * 4 + r;
                if (d < v1 || (d == v1 && j < i1)) { v2 = v1; v1 = d; i1 = j; }
                else if (d < v2) v2 = d;
            }
        int slot = wm * 4 + q;
        RV[t * 8 + slot] = v1;
        RI[t * 8 + slot] = i1;
        R2[t * 8 + slot] = v2;
    }
    __syncthreads();
    if (tid < 128) {
        int t = tid;
        float v1 = RV[t * 8], v2 = R2[t * 8];
        int i1 = RI[t * 8];
        #pragma unroll
        for (int s = 1; s < 8; ++s) {
            float a1 = RV[t * 8 + s], a2 = R2[t * 8 + s];
            int ai = RI[t * 8 + s];
            if (a1 < v1 || (a1 == v1 && ai < i1)) {
                v2 = fminf(v1, a2); v1 = a1; i1 = ai;
            } else {
                v2 = fminf(v2, a1);
            }
        }
        int n = b * Tn + t0 + t;
        candv[(size_t)jb * BT + n] = v1;
        candi[(size_t)jb * BT + n] = i1;
        cand2v[(size_t)jb * BT + n] = v2;
    }
}

// ---------------------------------------------------------------------------
// vq_reduce2: merge 8 j-block candidates; flag near-ties for exact rescore.
// ---------------------------------------------------------------------------
__global__ __launch_bounds__(256)
void vq_reduce2(const float* __restrict__ candv, const int* __restrict__ candi,
                const float* __restrict__ cand2v, int* __restrict__ idxI,
                float* __restrict__ idxf, int* __restrict__ flagn,
                int* __restrict__ flaglist) {
    int n = blockIdx.x * 256 + threadIdx.x;
    float v1 = candv[n], v2 = cand2v[n];
    int i1 = candi[n];
    #pragma unroll
    for (int jq = 1; jq < 8; ++jq) {
        float a1 = candv[(size_t)jq * BT + n];
        float a2 = cand2v[(size_t)jq * BT + n];
        int ai = candi[(size_t)jq * BT + n];
        if (a1 < v1 || (a1 == v1 && ai < i1)) {
            v2 = fminf(v1, a2); v1 = a1; i1 = ai;
        } else {
            v2 = fminf(v2, a1);
        }
    }
    idxI[n] = i1;
    idxf[n] = (float)i1;
    if (v2 - v1 < MARGIN) {
        int s = atomicAdd(flagn, 1);
        flaglist[s] = n;
    }
}

// ---------------------------------------------------------------------------
// vq_rescue: exact fp32 re-score of flagged positions over all 1024 codes.
// ---------------------------------------------------------------------------
__global__ __launch_bounds__(256)
void vq_rescue(const int* __restrict__ flagn, const int* __restrict__ flaglist,
               const float* __restrict__ Z, const float* __restrict__ CB,
               const float* __restrict__ CN, int* __restrict__ idxI,
               float* __restrict__ idxf) {
    __shared__ float zs[512];
    __shared__ float rvv[256];
    __shared__ int   rii[256];
    const int nf = *flagn;
    for (int f = blockIdx.x; f < nf; f += gridDim.x) {
        int n = flaglist[f];
        int b = n / Tn, t = n - b * Tn;
        __syncthreads();
        #pragma unroll
        for (int it = 0; it < 2; ++it) {
            int d = threadIdx.x + it * 256;
            zs[d] = Z[((size_t)b * Dc + d) * Tn + t];
        }
        __syncthreads();
        float bv = 1e30f;
        int bi = 0;
        #pragma unroll
        for (int jj = 0; jj < 4; ++jj) {
            int j = threadIdx.x * 4 + jj;
            const float* cr = CB + (size_t)j * Dc;
            float dot = 0.f;
            for (int d = 0; d < Dc; ++d) dot = fmaf(zs[d], cr[d], dot);
            float dist = fmaf(-2.f, dot, CN[j]);
            if (dist < bv || (dist == bv && j < bi)) { bv = dist; bi = j; }
        }
        rvv[threadIdx.x] = bv;
        rii[threadIdx.x] = bi;
        __syncthreads();
        for (int off = 128; off > 0; off >>= 1) {
            if (threadIdx.x < off) {
                float ov = rvv[threadIdx.x + off];
                int oi = rii[threadIdx.x + off];
                if (ov < rvv[threadIdx.x] ||
                    (ov == rvv[threadIdx.x] && oi < rii[threadIdx.x])) {
                    rvv[threadIdx.x] = ov; rii[threadIdx.x] = oi;
                }
            }
            __syncthreads();
        }
        if (threadIdx.x == 0) {
            idxI[n] = rii[0];
            idxf[n] = (float)rii[0];
        }
    }
}

// ---------------------------------------------------------------------------
// gemm_g: G[j][kk*512+o] = sum_c CB[j][c] * dec_w1[o][c][kk].
// ---------------------------------------------------------------------------
__global__ __launch_bounds__(256)
void gemm_g(const float* __restrict__ CBt, const float* __restrict__ Wt,
            float* __restrict__ G) {
    const int j0 = blockIdx.x * 64;
    const int kk = blockIdx.y >> 2;
    const int o0 = (blockIdx.y & 3) * 128;
    __shared__ __align__(16) float As[16][68];
    __shared__ __align__(16) float Bs[16][132];
    const int tid = threadIdx.x;
    const int tx = tid & 15, ty = tid >> 4;
    float acc[4][8] = {};

    for (int c0 = 0; c0 < Dc; c0 += 16) {
        {
            int cc = tid >> 4, j4 = tid & 15;
            *(float4*)&As[cc][j4 * 4] =
                *(const float4*)&CBt[(size_t)(c0 + cc) * NCODE + j0 + j4 * 4];
        }
        #pragma unroll
        for (int it = 0; it < 2; ++it) {
            int i = tid + it * 256;
            int cc = i >> 5, o4 = i & 31;
            *(float4*)&Bs[cc][o4 * 4] =
                *(const float4*)&Wt[(size_t)((c0 + cc) * 3 + kk) * Hc + o0 + o4 * 4];
        }
        __syncthreads();
        #pragma unroll
        for (int cc = 0; cc < 16; ++cc) {
            float4 a = *(const float4*)&As[cc][tx * 4];
            float av[4] = {a.x, a.y, a.z, a.w};
            float4 b0 = *(const float4*)&Bs[cc][ty * 4];
            float4 b1 = *(const float4*)&Bs[cc][64 + ty * 4];
            float bv[8] = {b0.x, b0.y, b0.z, b0.w, b1.x, b1.y, b1.z, b1.w};
            #pragma unroll
            for (int jj = 0; jj < 4; ++jj)
                #pragma unroll
                for (int oo = 0; oo < 8; ++oo)
                    acc[jj][oo] = fmaf(av[jj], bv[oo], acc[jj][oo]);
        }
        __syncthreads();
    }
    #pragma unroll
    for (int jj = 0; jj < 4; ++jj) {
        int j = j0 + tx * 4 + jj;
        float* gp = G + (size_t)j * 1536 + kk * 512 + o0;
        *(float4*)(gp + ty * 4) = *(float4*)&acc[jj][0];
        *(float4*)(gp + 64 + ty * 4) = *(float4*)&acc[jj][4];
    }
}

// ---------------------------------------------------------------------------
// dec_y3: y3[b][o][t] = relu(b1[o] + sum_kk G[idx[b][t+kk-1]][kk*512+o]).
// ---------------------------------------------------------------------------
__global__ __launch_bounds__(256)
void dec_y3(const int* __restrict__ idx, const float* __restrict__ G,
            const float* __restrict__ bias, float* __restrict__ Y) {
    const int t0 = blockIdx.x * 64;
    const int o0 = blockIdx.y * 128;
    const int b  = blockIdx.z;
    const int tid = threadIdx.x;
    __shared__ int sidx[66];
    __shared__ __align__(16) float Ys[128][68];

    if (tid < 66) {
        int t = t0 + tid - 1;
        sidx[tid] = (t >= 0 && t < Tn) ? idx[b * Tn + t] : -1;
    }
    __syncthreads();

    const int o = tid & 127;
    const int half = tid >> 7;
    float acc[32] = {};
    #pragma unroll
    for (int kk = 0; kk < 3; ++kk) {
        const float* Gk = G + (size_t)kk * 512 + o0 + o;
        #pragma unroll
        for (int k = 0; k < 32; ++k) {
            int j = sidx[half + 2 * k + kk];
            if (j >= 0) acc[k] += Gk[(size_t)j * 1536];
        }
    }
    float bv = bias[o0 + o];
    #pragma unroll
    for (int k = 0; k < 32; ++k)
        Ys[o][half + 2 * k] = fmaxf(acc[k] + bv, 0.f);
    __syncthreads();

    float* Yb = Y + (size_t)b * Hc * Tn + t0;
    #pragma unroll
    for (int it = 0; it < 8; ++it) {
        int i = tid + it * 256;
        int t4 = i & 15, oo = i >> 4;
        *(float4*)&Yb[(size_t)(o0 + oo) * Tn + t4 * 4] =
            *(const float4*)&Ys[oo][t4 * 4];
    }
}

// ---------------------------------------------------------------------------
extern "C" void kernel_launch(void* const* d_in, const int* in_sizes, int n_in,
                              void* d_out, int out_size, void* d_ws, size_t ws_size,
                              hipStream_t stream) {
    const float* mels    = (const float*)d_in[0];
    const float* enc_w1  = (const float*)d_in[1];
    const float* enc_b1  = (const float*)d_in[2];
    const float* enc_w2  = (const float*)d_in[3];
    const float* enc_b2  = (const float*)d_in[4];
    const float* codebook= (const float*)d_in[5];
    const float* dec_w1  = (const float*)d_in[6];
    const float* dec_b1  = (const float*)d_in[7];
    const float* dec_w2  = (const float*)d_in[8];
    const float* dec_b2  = (const float*)d_in[9];

    float* out = (float*)d_out;
    float* recon = out;                 // [B,T,80]
    float* idxf  = out + RECON_N;       // [B,T] as float

    const size_t ACT = (size_t)Bsz * Hc * Tn;   // 16,777,216 floats (64 MB)
    float* bufA  = (float*)d_ws;                // y1, later y3
    float* bufB  = bufA + ACT;                  // melsT, then z
    int*   idxI  = (int*)(bufB + ACT);          // [BT]
    float* cn    = (float*)(idxI + BT);         // [NCODE]
    float* cbt   = cn + NCODE;                  // [Dc*NCODE]  (gemm_g)
    float* wt1   = cbt + (size_t)Dc * NCODE;    // enc_w1t: 80*3*512
    float* wt3   = wt1 + (size_t)INC * 3 * Hc;  // dec_w1t: 512*3*512
    float* candv = wt3 + (size_t)Dc * 3 * Hc;   // [8*BT]
    float* cand2v= candv + (size_t)8 * BT;      // [8*BT]
    int*   candi = (int*)(cand2v + (size_t)8 * BT); // [8*BT]
    int*   flagn = candi + (size_t)8 * BT;      // [4]
    int*   flaglist = flagn + 4;                // [BT]
    float* G     = (float*)(flaglist + BT);     // [NCODE*1536]
    unsigned short* whi = (unsigned short*)(G + (size_t)NCODE * 1536); // [3*Hc*Dc]
    unsigned short* wlo = whi + (size_t)3 * Hc * Dc;                   // [3*Hc*Dc]
    unsigned short* cbh = wlo + (size_t)3 * Hc * Dc;                   // [NCODE*Dc]
    unsigned short* cbl = cbh + (size_t)NCODE * Dc;                    // [NCODE*Dc]
    unsigned short* wh2 = cbl + (size_t)NCODE * Dc;                    // [3*INC*Hc]
    float* melsT = bufB;                        // [B,80,T] (dead after enc1)

    dim3 blk(256);
    hipMemsetAsync(flagn, 0, 16, stream);
    // prep: norms + transposes + bf16 splits (cheap, graph-capture safe)
    code_norms<<<dim3(NCODE), dim3(64), 0, stream>>>(codebook, cn);
    cb_transpose<<<dim3(NCODE / 64, Dc / 64), blk, 0, stream>>>(codebook, cbt);
    mels_transpose<<<dim3(Tn / 64, Bsz), blk, 0, stream>>>(mels, melsT);
    wt_transpose<<<dim3(Hc / 64, INC / 16), blk, 0, stream>>>(enc_w1, wt1, INC, Hc);
    wsplit<<<dim3(Hc, 3), blk, 0, stream>>>(enc_w2, whi, wlo);
    cbsplit<<<dim3(NCODE), blk, 0, stream>>>(codebook, cbh, cbl);
    wt_transpose<<<dim3(Hc / 64, Dc / 16), blk, 0, stream>>>(dec_w1, wt3, Dc, Hc);
    wsplit80<<<dim3(INC, 3), blk, 0, stream>>>(dec_w2, wh2);
    // decoder conv1 folded matrix (independent of activations)
    gemm_g<<<dim3(NCODE / 64, 12), blk, 0, stream>>>(cbt, wt3, G);
    // encoder
    conv_enc1<<<dim3(Tn / 64, Hc / 128, Bsz), blk, 0, stream>>>(melsT, wt1, enc_b1, bufA);
    conv_mid_mfma<<<dim3(Tn / 128, Hc / 128, Bsz), blk, 0, stream>>>(bufA, whi, wlo, enc_b2, bufB);
    // vector quantization: MFMA approx + margin-guarded exact rescue
    vq_mfma<<<dim3(BT / 128, NCODE / 128), blk, 0, stream>>>(bufB, cbh, cbl, cn,
                                                             candv, candi, cand2v);
    vq_reduce2<<<dim3(BT / 256), blk, 0, stream>>>(candv, candi, cand2v, idxI,
                                                   idxf, flagn, flaglist);
    vq_rescue<<<dim3(128), blk, 0, stream>>>(flagn, flaglist, bufB, codebook, cn,
                                             idxI, idxf);
    // decoder: conv1 via gather of G rows, then conv2 as single-bf16 MFMA
    dec_y3<<<dim3(Tn / 64, 4, Bsz), blk, 0, stream>>>(idxI, G, dec_b1, bufA);
    dec2_mfma<<<dim3(Tn / 128, 1, Bsz), blk, 0, stream>>>(bufA, wh2, dec_b2, recon);
}